// Round 9
// baseline (531.676 us; speedup 1.0000x reference)
//
#include <hip/hip_runtime.h>

// Problem constants (fixed by the reference file)
#define NND 50000   // nodes
#define NE  600000  // edges
#define TSEQ 50     // sequence length
#define NB  1000    // batch = NND/TSEQ
#define SB  4       // sequences per LSTM workgroup
#define AHS 136     // LDS h-row stride in shorts (128 + 8 pad, 16B-aligned)
#define NSCB 196    // scan blocks: ceil(NND/256)

typedef __attribute__((ext_vector_type(4))) float f32x4;
typedef __attribute__((ext_vector_type(8))) short s16x8;

// ---------------------------------------------------------------- helpers
__device__ __forceinline__ float sigf(float x) {
    return 1.0f / (1.0f + __expf(-x));
}
__device__ __forceinline__ float tanhfast(float x) {
    x = fminf(fmaxf(x, -15.f), 15.f);
    float e = __expf(2.f * x);
    return (e - 1.f) / (e + 1.f);
}
// bf16 bit helpers (round-to-nearest-even)
__device__ __forceinline__ unsigned short f2bf(float f) {
    unsigned int u = __float_as_uint(f);
    u = u + 0x7FFFu + ((u >> 16) & 1u);
    return (unsigned short)(u >> 16);
}
__device__ __forceinline__ float bf2f(unsigned short h) {
    return __uint_as_float(((unsigned int)h) << 16);
}

// ---------------------------------------------------------------- CSR build
__global__ void k_count(const int* __restrict__ ei, int* __restrict__ cnt) {
    int e = blockIdx.x * 256 + threadIdx.x;
    if (e < NE) atomicAdd(&cnt[ei[NE + e]], 1);
}

// ---- 3-stage multi-block exclusive scan of cnt -> rowstart (+ fused dinv)
__global__ __launch_bounds__(256) void k_bsum(const int* __restrict__ cnt,
                                              int* __restrict__ bsum) {
    __shared__ int red[256];
    int t = threadIdx.x;
    int idx = blockIdx.x * 256 + t;
    red[t] = (idx < NND) ? cnt[idx] : 0;
    __syncthreads();
    for (int off = 128; off > 0; off >>= 1) {
        if (t < off) red[t] += red[t + off];
        __syncthreads();
    }
    if (t == 0) bsum[blockIdx.x] = red[0];
}

__global__ __launch_bounds__(256) void k_bscan(int* __restrict__ bsum) {
    __shared__ int ps[256];
    int t = threadIdx.x;
    int v = (t < NSCB) ? bsum[t] : 0;
    ps[t] = v;
    __syncthreads();
    for (int off = 1; off < 256; off <<= 1) {
        int u = 0;
        if (t >= off) u = ps[t - off];
        __syncthreads();
        if (t >= off) ps[t] += u;
        __syncthreads();
    }
    if (t < NSCB) bsum[t] = ps[t] - v;   // exclusive
}

__global__ __launch_bounds__(256) void k_bout(const int* __restrict__ cnt,
                                              const int* __restrict__ bsum,
                                              int* __restrict__ rowstart,
                                              float* __restrict__ dinv) {
    __shared__ int ps[256];
    int t = threadIdx.x;
    int idx = blockIdx.x * 256 + t;
    int v = (idx < NND) ? cnt[idx] : 0;
    ps[t] = v;
    __syncthreads();
    for (int off = 1; off < 256; off <<= 1) {
        int u = 0;
        if (t >= off) u = ps[t - off];
        __syncthreads();
        if (t >= off) ps[t] += u;
        __syncthreads();
    }
    int boff = bsum[blockIdx.x];
    if (idx < NND) {
        rowstart[idx] = boff + ps[t] - v;   // exclusive
        dinv[idx] = 1.0f / sqrtf((float)v + 1.0f);   // fused (was k_dinv)
    }
    if (idx == NND - 1) rowstart[NND] = boff + ps[t];  // == NE
}

__global__ void k_fill(const int* __restrict__ ei, const int* __restrict__ rowstart,
                       int* __restrict__ cursor, int* __restrict__ adj) {
    int e = blockIdx.x * 256 + threadIdx.x;
    if (e >= NE) return;
    int s = ei[e], d = ei[NE + e];
    int pos = atomicAdd(&cursor[d], 1);
    adj[rowstart[d] + pos] = s;
}

// ---------------------------------------------------------------- MFMA GEMM
// GCN layers (Nc=128): 128x128 A panel staged once, NT col-tiles per block.
__global__ __launch_bounds__(256) void k_gemm_mfma(
    const unsigned short* __restrict__ Ahi, const unsigned short* __restrict__ Alo,
    const unsigned short* __restrict__ Bhi, const unsigned short* __restrict__ Blo,
    const float* __restrict__ bias, float* __restrict__ C,
    int M, int Nc, int NT)
{
    __shared__ unsigned short As_hi[128][136];
    __shared__ unsigned short As_lo[128][136];

    const int tid  = threadIdx.x;
    const int lane = tid & 63, wave = tid >> 6;
    const int mw = wave & 1, nw = wave >> 1;
    const int l15 = lane & 15, quad = lane >> 4;
    const int rowBase = blockIdx.y * 128;

    {
        int r0 = tid >> 4;            // 0..15
        int ko = (tid & 15) * 8;      // 0..120
        #pragma unroll
        for (int i = 0; i < 8; ++i) {
            int row = r0 + i * 16;
            int g = rowBase + row;
            uint4 vh = make_uint4(0, 0, 0, 0), vl = make_uint4(0, 0, 0, 0);
            if (g < M) {
                vh = *(const uint4*)&Ahi[(size_t)g * 128 + ko];
                vl = *(const uint4*)&Alo[(size_t)g * 128 + ko];
            }
            *(uint4*)&As_hi[row][ko] = vh;
            *(uint4*)&As_lo[row][ko] = vl;
        }
    }
    __syncthreads();

    for (int nt = 0; nt < NT; ++nt) {
        const int colBase = (blockIdx.x * NT + nt) * 64;

        s16x8 bh[2][4], bl[2][4];   // [ns][kq]
        #pragma unroll
        for (int ns = 0; ns < 2; ++ns) {
            int gn = colBase + nw * 32 + ns * 16 + l15;
            #pragma unroll
            for (int kq = 0; kq < 4; ++kq) {
                bh[ns][kq] = *(const s16x8*)&Bhi[(size_t)gn * 128 + kq * 32 + quad * 8];
                bl[ns][kq] = *(const s16x8*)&Blo[(size_t)gn * 128 + kq * 32 + quad * 8];
            }
        }

        f32x4 acc[4][2] = {};
        #pragma unroll
        for (int kq = 0; kq < 4; ++kq) {
            int kof = kq * 32 + quad * 8;
            s16x8 ah[4], al[4];
            #pragma unroll
            for (int ms = 0; ms < 4; ++ms) {
                int r = mw * 64 + ms * 16 + l15;
                ah[ms] = *(const s16x8*)&As_hi[r][kof];
                al[ms] = *(const s16x8*)&As_lo[r][kof];
            }
            #pragma unroll
            for (int ms = 0; ms < 4; ++ms)
                #pragma unroll
                for (int ns = 0; ns < 2; ++ns)
                    acc[ms][ns] = __builtin_amdgcn_mfma_f32_16x16x32_bf16(ah[ms], bh[ns][kq], acc[ms][ns], 0, 0, 0);
            #pragma unroll
            for (int ms = 0; ms < 4; ++ms)
                #pragma unroll
                for (int ns = 0; ns < 2; ++ns)
                    acc[ms][ns] = __builtin_amdgcn_mfma_f32_16x16x32_bf16(al[ms], bh[ns][kq], acc[ms][ns], 0, 0, 0);
            #pragma unroll
            for (int ms = 0; ms < 4; ++ms)
                #pragma unroll
                for (int ns = 0; ns < 2; ++ns)
                    acc[ms][ns] = __builtin_amdgcn_mfma_f32_16x16x32_bf16(ah[ms], bl[ns][kq], acc[ms][ns], 0, 0, 0);
        }

        #pragma unroll
        for (int ns = 0; ns < 2; ++ns) {
            int col = colBase + nw * 32 + ns * 16 + l15;
            float bv = bias ? bias[col] : 0.f;
            #pragma unroll
            for (int ms = 0; ms < 4; ++ms) {
                int row0 = rowBase + mw * 64 + ms * 16 + quad * 4;
                #pragma unroll
                for (int r = 0; r < 4; ++r) {
                    int row = row0 + r;
                    if (row < M) C[(size_t)row * Nc + col] = acc[ms][ns][r] + bv;
                }
            }
        }
    }
}

// Variant: A is raw fp32 (input x); split-bf16 conversion fused into staging.
__global__ __launch_bounds__(256) void k_gemm_mfma_xa(
    const float* __restrict__ X,
    const unsigned short* __restrict__ Bhi, const unsigned short* __restrict__ Blo,
    const float* __restrict__ bias, float* __restrict__ C,
    int M, int Nc, int NT)
{
    __shared__ unsigned short As_hi[128][136];
    __shared__ unsigned short As_lo[128][136];

    const int tid  = threadIdx.x;
    const int lane = tid & 63, wave = tid >> 6;
    const int mw = wave & 1, nw = wave >> 1;
    const int l15 = lane & 15, quad = lane >> 4;
    const int rowBase = blockIdx.y * 128;

    {
        int r0 = tid >> 4;
        int ko = (tid & 15) * 8;
        #pragma unroll
        for (int i = 0; i < 8; ++i) {
            int row = r0 + i * 16;
            int g = rowBase + row;
            unsigned short hx[8], lx[8];
            if (g < M) {
                float4 v0 = *(const float4*)&X[(size_t)g * 128 + ko];
                float4 v1 = *(const float4*)&X[(size_t)g * 128 + ko + 4];
                const float vv[8] = {v0.x, v0.y, v0.z, v0.w, v1.x, v1.y, v1.z, v1.w};
                #pragma unroll
                for (int e = 0; e < 8; ++e) {
                    hx[e] = f2bf(vv[e]);
                    lx[e] = f2bf(vv[e] - bf2f(hx[e]));
                }
            } else {
                #pragma unroll
                for (int e = 0; e < 8; ++e) { hx[e] = 0; lx[e] = 0; }
            }
            *(uint4*)&As_hi[row][ko] = *(const uint4*)hx;
            *(uint4*)&As_lo[row][ko] = *(const uint4*)lx;
        }
    }
    __syncthreads();

    for (int nt = 0; nt < NT; ++nt) {
        const int colBase = (blockIdx.x * NT + nt) * 64;

        s16x8 bh[2][4], bl[2][4];
        #pragma unroll
        for (int ns = 0; ns < 2; ++ns) {
            int gn = colBase + nw * 32 + ns * 16 + l15;
            #pragma unroll
            for (int kq = 0; kq < 4; ++kq) {
                bh[ns][kq] = *(const s16x8*)&Bhi[(size_t)gn * 128 + kq * 32 + quad * 8];
                bl[ns][kq] = *(const s16x8*)&Blo[(size_t)gn * 128 + kq * 32 + quad * 8];
            }
        }

        f32x4 acc[4][2] = {};
        #pragma unroll
        for (int kq = 0; kq < 4; ++kq) {
            int kof = kq * 32 + quad * 8;
            s16x8 ah[4], al[4];
            #pragma unroll
            for (int ms = 0; ms < 4; ++ms) {
                int r = mw * 64 + ms * 16 + l15;
                ah[ms] = *(const s16x8*)&As_hi[r][kof];
                al[ms] = *(const s16x8*)&As_lo[r][kof];
            }
            #pragma unroll
            for (int ms = 0; ms < 4; ++ms)
                #pragma unroll
                for (int ns = 0; ns < 2; ++ns)
                    acc[ms][ns] = __builtin_amdgcn_mfma_f32_16x16x32_bf16(ah[ms], bh[ns][kq], acc[ms][ns], 0, 0, 0);
            #pragma unroll
            for (int ms = 0; ms < 4; ++ms)
                #pragma unroll
                for (int ns = 0; ns < 2; ++ns)
                    acc[ms][ns] = __builtin_amdgcn_mfma_f32_16x16x32_bf16(al[ms], bh[ns][kq], acc[ms][ns], 0, 0, 0);
            #pragma unroll
            for (int ms = 0; ms < 4; ++ms)
                #pragma unroll
                for (int ns = 0; ns < 2; ++ns)
                    acc[ms][ns] = __builtin_amdgcn_mfma_f32_16x16x32_bf16(ah[ms], bl[ns][kq], acc[ms][ns], 0, 0, 0);
        }

        #pragma unroll
        for (int ns = 0; ns < 2; ++ns) {
            int col = colBase + nw * 32 + ns * 16 + l15;
            float bv = bias ? bias[col] : 0.f;
            #pragma unroll
            for (int ms = 0; ms < 4; ++ms) {
                int row0 = rowBase + mw * 64 + ms * 16 + quad * 4;
                #pragma unroll
                for (int r = 0; r < 4; ++r) {
                    int row = row0 + r;
                    if (row < M) C[(size_t)row * Nc + col] = acc[ms][ns][r] + bv;
                }
            }
        }
    }
}

// ---------------------------------------------------------------- gate GEMM v6
// SWAPPED-OPERAND layout (verified R7): W as MFMA A-operand, x as B-operand.
// Lane holds 4 consecutive gate cols of one G row => float4 stores.
__global__ __launch_bounds__(256) void k_gemm_gT(
    const unsigned short* __restrict__ Ahi, const unsigned short* __restrict__ Alo,
    const unsigned short* __restrict__ Whi, const unsigned short* __restrict__ Wlo,
    const float* __restrict__ bp, float* __restrict__ G,
    int M)
{
    __shared__ unsigned short As_hi[64][136];
    __shared__ unsigned short As_lo[64][136];

    const int tid  = threadIdx.x;
    const int lane = tid & 63, wave = tid >> 6;
    const int l15 = lane & 15, quad = lane >> 4;
    const int rowBase = blockIdx.x * 64;

    {
        int r0 = tid >> 4;            // 0..15
        int ko = (tid & 15) * 8;      // 0..120
        #pragma unroll
        for (int i = 0; i < 4; ++i) {
            int row = r0 + i * 16;
            int g = rowBase + row;
            uint4 vh = make_uint4(0, 0, 0, 0), vl = make_uint4(0, 0, 0, 0);
            if (g < M) {
                vh = *(const uint4*)&Ahi[(size_t)g * 128 + ko];
                vl = *(const uint4*)&Alo[(size_t)g * 128 + ko];
            }
            *(uint4*)&As_hi[row][ko] = vh;
            *(uint4*)&As_lo[row][ko] = vl;
        }
    }
    __syncthreads();

    const int pb = wave * 128;   // wave's 128 gate-cols

    #pragma unroll
    for (int tp = 0; tp < 4; ++tp) {
        const int p0 = pb + tp * 32;

        // W frags for 2 p-tiles (A-operand: lane l15 -> p row within tile)
        s16x8 wh[2][4], wl[2][4];   // [tile][kq]
        #pragma unroll
        for (int t = 0; t < 2; ++t)
            #pragma unroll
            for (int kq = 0; kq < 4; ++kq) {
                const size_t wrow = (size_t)(p0 + t * 16 + l15) * 128 + kq * 32 + quad * 8;
                wh[t][kq] = *(const s16x8*)&Whi[wrow];
                wl[t][kq] = *(const s16x8*)&Wlo[wrow];
            }
        float4 bv[2];
        #pragma unroll
        for (int t = 0; t < 2; ++t)
            bv[t] = *(const float4*)&bp[p0 + t * 16 + quad * 4];

        #pragma unroll
        for (int rg = 0; rg < 4; ++rg) {
            // x frags (B-operand: lane l15 -> x row within rowgroup)
            s16x8 xh[4], xl[4];
            #pragma unroll
            for (int kq = 0; kq < 4; ++kq) {
                xh[kq] = *(const s16x8*)&As_hi[rg * 16 + l15][kq * 32 + quad * 8];
                xl[kq] = *(const s16x8*)&As_lo[rg * 16 + l15][kq * 32 + quad * 8];
            }
            f32x4 acc[2] = {};
            #pragma unroll
            for (int kq = 0; kq < 4; ++kq)
                #pragma unroll
                for (int t = 0; t < 2; ++t) {
                    acc[t] = __builtin_amdgcn_mfma_f32_16x16x32_bf16(wh[t][kq], xh[kq], acc[t], 0, 0, 0);
                    acc[t] = __builtin_amdgcn_mfma_f32_16x16x32_bf16(wh[t][kq], xl[kq], acc[t], 0, 0, 0);
                    acc[t] = __builtin_amdgcn_mfma_f32_16x16x32_bf16(wl[t][kq], xh[kq], acc[t], 0, 0, 0);
                }
            const int row = rowBase + rg * 16 + l15;
            if (row < M) {
                #pragma unroll
                for (int t = 0; t < 2; ++t) {
                    float4 o;
                    o.x = acc[t][0] + bv[t].x;
                    o.y = acc[t][1] + bv[t].y;
                    o.z = acc[t][2] + bv[t].z;
                    o.w = acc[t][3] + bv[t].w;
                    *(float4*)&G[(size_t)row * 512 + p0 + t * 16 + quad * 4] = o;
                }
            }
        }
    }
}

// 2-term variant (A plain bf16): layer-1 gate GEMM. LDS 17.4 KB.
__global__ __launch_bounds__(256) void k_gemm_gT_h(
    const unsigned short* __restrict__ Ahi,
    const unsigned short* __restrict__ Whi, const unsigned short* __restrict__ Wlo,
    const float* __restrict__ bp, float* __restrict__ G,
    int M)
{
    __shared__ unsigned short As_hi[64][136];

    const int tid  = threadIdx.x;
    const int lane = tid & 63, wave = tid >> 6;
    const int l15 = lane & 15, quad = lane >> 4;
    const int rowBase = blockIdx.x * 64;

    {
        int r0 = tid >> 4;
        int ko = (tid & 15) * 8;
        #pragma unroll
        for (int i = 0; i < 4; ++i) {
            int row = r0 + i * 16;
            int g = rowBase + row;
            uint4 vh = make_uint4(0, 0, 0, 0);
            if (g < M) vh = *(const uint4*)&Ahi[(size_t)g * 128 + ko];
            *(uint4*)&As_hi[row][ko] = vh;
        }
    }
    __syncthreads();

    const int pb = wave * 128;

    #pragma unroll
    for (int tp = 0; tp < 4; ++tp) {
        const int p0 = pb + tp * 32;

        s16x8 wh[2][4], wl[2][4];
        #pragma unroll
        for (int t = 0; t < 2; ++t)
            #pragma unroll
            for (int kq = 0; kq < 4; ++kq) {
                const size_t wrow = (size_t)(p0 + t * 16 + l15) * 128 + kq * 32 + quad * 8;
                wh[t][kq] = *(const s16x8*)&Whi[wrow];
                wl[t][kq] = *(const s16x8*)&Wlo[wrow];
            }
        float4 bv[2];
        #pragma unroll
        for (int t = 0; t < 2; ++t)
            bv[t] = *(const float4*)&bp[p0 + t * 16 + quad * 4];

        #pragma unroll
        for (int rg = 0; rg < 4; ++rg) {
            s16x8 xh[4];
            #pragma unroll
            for (int kq = 0; kq < 4; ++kq)
                xh[kq] = *(const s16x8*)&As_hi[rg * 16 + l15][kq * 32 + quad * 8];
            f32x4 acc[2] = {};
            #pragma unroll
            for (int kq = 0; kq < 4; ++kq)
                #pragma unroll
                for (int t = 0; t < 2; ++t) {
                    acc[t] = __builtin_amdgcn_mfma_f32_16x16x32_bf16(wh[t][kq], xh[kq], acc[t], 0, 0, 0);
                    acc[t] = __builtin_amdgcn_mfma_f32_16x16x32_bf16(wl[t][kq], xh[kq], acc[t], 0, 0, 0);
                }
            const int row = rowBase + rg * 16 + l15;
            if (row < M) {
                #pragma unroll
                for (int t = 0; t < 2; ++t) {
                    float4 o;
                    o.x = acc[t][0] + bv[t].x;
                    o.y = acc[t][1] + bv[t].y;
                    o.z = acc[t][2] + bv[t].z;
                    o.w = acc[t][3] + bv[t].w;
                    *(float4*)&G[(size_t)row * 512 + p0 + t * 16 + quad * 4] = o;
                }
            }
        }
    }
}

// ---------------------------------------------------------------- GCN gather
// Edge loop unrolled x4 (4 h-rows in flight); accumulation order preserved.
__global__ __launch_bounds__(256) void k_gather(
    const int* __restrict__ rowstart, const int* __restrict__ adj,
    const float* __restrict__ h, const float* __restrict__ dinv,
    const float* __restrict__ bias,
    unsigned short* __restrict__ hi, unsigned short* __restrict__ lo)
{
    const int n    = blockIdx.x * 4 + (threadIdx.x >> 6);   // grid exactly NND/4
    const int lane = threadIdx.x & 63;
    const int r0 = rowstart[n], r1 = rowstart[n + 1];
    const float dn = dinv[n];

    float2 hv = *(const float2*)&h[(size_t)n * 128 + 2 * lane];
    float2 acc;
    acc.x = hv.x * dn;
    acc.y = hv.y * dn;

    int i = r0;
    for (; i + 4 <= r1; i += 4) {
        int s0 = adj[i], s1 = adj[i + 1], s2 = adj[i + 2], s3 = adj[i + 3];
        float d0 = dinv[s0], d1 = dinv[s1], d2 = dinv[s2], d3 = dinv[s3];
        float2 v0 = *(const float2*)&h[(size_t)s0 * 128 + 2 * lane];
        float2 v1 = *(const float2*)&h[(size_t)s1 * 128 + 2 * lane];
        float2 v2 = *(const float2*)&h[(size_t)s2 * 128 + 2 * lane];
        float2 v3 = *(const float2*)&h[(size_t)s3 * 128 + 2 * lane];
        acc.x += v0.x * d0; acc.y += v0.y * d0;
        acc.x += v1.x * d1; acc.y += v1.y * d1;
        acc.x += v2.x * d2; acc.y += v2.y * d2;
        acc.x += v3.x * d3; acc.y += v3.y * d3;
    }
    for (; i < r1; ++i) {
        int s = adj[i];
        float ds = dinv[s];
        float2 v = *(const float2*)&h[(size_t)s * 128 + 2 * lane];
        acc.x += v.x * ds;
        acc.y += v.y * ds;
    }

    float2 bb = *(const float2*)&bias[2 * lane];
    float vx = fmaxf(acc.x * dn + bb.x, 0.f);
    float vy = fmaxf(acc.y * dn + bb.y, 0.f);
    ushort2 ho, lo2;
    ho.x = f2bf(vx); lo2.x = f2bf(vx - bf2f(ho.x));
    ho.y = f2bf(vy); lo2.y = f2bf(vy - bf2f(ho.y));
    *(ushort2*)&hi[(size_t)n * 128 + 2 * lane] = ho;
    *(ushort2*)&lo[(size_t)n * 128 + 2 * lane] = lo2;
}

// ---------------------------------------------------------------- prep kernels
__global__ void k_prep_gcnw2(const float* __restrict__ W1, const float* __restrict__ W2,
                             unsigned short* __restrict__ hi1, unsigned short* __restrict__ lo1,
                             unsigned short* __restrict__ hi2, unsigned short* __restrict__ lo2) {
    int t = blockIdx.x * 256 + threadIdx.x;   // grid 128 -> 32768 threads
    const float* W = (t < 16384) ? W1 : W2;
    unsigned short* hi = (t < 16384) ? hi1 : hi2;
    unsigned short* lo = (t < 16384) ? lo1 : lo2;
    int tt = t & 16383;
    int k = tt >> 7, n = tt & 127;
    float v = W[tt];
    unsigned short h = f2bf(v);
    hi[n * 128 + k] = h;
    lo[n * 128 + k] = f2bf(v - bf2f(h));
}

// LSTM prep: w_ih and w_hh [512(r=g*128+j)][128(k)] -> packed-transposed
// split-bf16 wT[p=j*4+g][k]; bias -> bp[p] = b_ih + b_hh.
__global__ void k_prep_lstm(const float* __restrict__ w_ih, const float* __restrict__ w_hh,
                            const float* __restrict__ b_ih, const float* __restrict__ b_hh,
                            unsigned short* __restrict__ ih_hi, unsigned short* __restrict__ ih_lo,
                            unsigned short* __restrict__ hh_hi, unsigned short* __restrict__ hh_lo,
                            float* __restrict__ bp)
{
    int t = blockIdx.x * 256 + threadIdx.x;
    if (t < 65536) {
        int r = t >> 7, k = t & 127;
        int g = r >> 7, j = r & 127;
        int p = (j << 2) + g;
        float v = w_ih[t];
        unsigned short h = f2bf(v);
        ih_hi[p * 128 + k] = h;
        ih_lo[p * 128 + k] = f2bf(v - bf2f(h));
    } else if (t < 131072) {
        int t2 = t - 65536;
        int r = t2 >> 7, k = t2 & 127;
        int g = r >> 7, j = r & 127;
        int p = (j << 2) + g;
        float v = w_hh[t2];
        unsigned short h = f2bf(v);
        hh_hi[p * 128 + k] = h;
        hh_lo[p * 128 + k] = f2bf(v - bf2f(h));
    } else if (t < 131584) {
        int r = t - 131072;   // 0..511
        int g = r >> 7, j = r & 127;
        bp[(j << 2) + g] = b_ih[r] + b_hh[r];
    }
}

// ---------------------------------------------------------------- LSTM recurrence
// v11: v10 + REGISTER-RESIDENT WEIGHTS. R7 counters showed VGPR_Count=84 —
// below the 128 VGPRs the weight frags need — so the compiler was
// re-materializing 32 global weight loads per wave per STEP on the serial
// path (VALUBusy ~= MfmaUtil). Fix: __launch_bounds__(512,1) lifts the
// allocator cap (1 block/CU anyway; extra occupancy was useless), and an
// opaque asm keep-alive on each frag makes re-materialization illegal.
// Numerics bit-identical to v10.
__global__ __launch_bounds__(512, 1) void k_lstm(
    const float* __restrict__ G,            // (NB*TSEQ) x 512, gate-packed cols
    const unsigned short* __restrict__ Whi, // 512 x 128, packed-transposed hi
    const unsigned short* __restrict__ Wlo, // lo
    unsigned short* __restrict__ Hhi,       // (NB*TSEQ) x 128 bf16-hi, or nullptr
    const float* __restrict__ fcw,          // fused FC weight (layer 1) or nullptr
    const float* __restrict__ fcb,
    float* __restrict__ outp)               // NB x 1 output (layer 1) or nullptr
{
    const int tid  = threadIdx.x;
    const int lane = tid & 63, wave = tid >> 6;   // 8 waves
    const int l15  = lane & 15, quad = lane >> 4;
    const int b0   = blockIdx.x * SB;

    __shared__ __align__(16) unsigned short Ah[16 * AHS];  // h bf16 (rows SB..15 zero)
    __shared__ float partw[8][4][72];        // per-wave P patch [wave][b][col in wave]

    // weight fragments: wave owns n-tiles nt0..nt0+3 (n = p = j*4+gate)
    const int nt0 = wave * 4;
    s16x8 bh[4][4], bl[4][4];   // [nt][ks]
    #pragma unroll
    for (int nt = 0; nt < 4; ++nt) {
        int p = (nt0 + nt) * 16 + l15;
        #pragma unroll
        for (int ks = 0; ks < 4; ++ks) {
            bh[nt][ks] = *(const s16x8*)&Whi[(size_t)p * 128 + ks * 32 + quad * 8];
            bl[nt][ks] = *(const s16x8*)&Wlo[(size_t)p * 128 + ks * 32 + quad * 8];
            // pin in registers: opaque asm forbids re-materializing the load
            asm volatile("" : "+v"(bh[nt][ks]), "+v"(bl[nt][ks]));
        }
    }

    for (int i = tid; i < 16 * AHS; i += 512) Ah[i] = 0;

    // phase-2 mapping: lane l of wave w -> (b2, j) with j owned by wave w
    const int b2 = lane >> 4;              // 0..3
    const int jj = wave * 16 + l15;        // hidden unit this lane updates
    const int bg = b0 + b2;                // sequence index (NB % SB == 0)
    float c = 0.f;
    float hn_last = 0.f;
    __syncthreads();

    const float* gbase = &G[((size_t)bg * TSEQ) * 512 + (jj << 2)];

    for (int step = 0; step < TSEQ; ++step) {
        // gate input for phase 2 (issued early; covered by phase-1 MFMA time)
        const float4 gv = *(const float4*)&gbase[(size_t)step * 512];

        // phase 1: MFMA  P = bf16(h) @ (Whi + Wlo)
        f32x4 acc[4] = {};
        #pragma unroll
        for (int ks = 0; ks < 4; ++ks) {
            s16x8 ah = *(const s16x8*)&Ah[l15 * AHS + ks * 32 + quad * 8];
            #pragma unroll
            for (int nt = 0; nt < 4; ++nt) {
                acc[nt] = __builtin_amdgcn_mfma_f32_16x16x32_bf16(ah, bh[nt][ks], acc[nt], 0, 0, 0);
                acc[nt] = __builtin_amdgcn_mfma_f32_16x16x32_bf16(ah, bl[nt][ks], acc[nt], 0, 0, 0);
            }
        }

        // intra-wave exchange: quad-0 lanes hold rows 0..3 (the real seqs)
        if (quad == 0) {
            #pragma unroll
            for (int nt = 0; nt < 4; ++nt)
                #pragma unroll
                for (int r = 0; r < 4; ++r)
                    partw[wave][r][nt * 16 + l15] = acc[nt][r];
        }
        // same-wave producer/consumer: compiler inserts lgkmcnt wait, no barrier

        // phase 2: LSTM cell for (b2, jj); reads this wave's own patch
        {
            float4 pa = *(const float4*)&partw[wave][b2][l15 * 4];
            float xi = pa.x + gv.x;
            float xf = pa.y + gv.y;
            float xg = pa.z + gv.z;
            float xo = pa.w + gv.w;
            float ii = sigf(xi), ff = sigf(xf), gg = tanhfast(xg), oo = sigf(xo);
            float cn = ff * c + ii * gg;
            c = cn;
            float hn = oo * tanhfast(cn);
            hn_last = hn;
            unsigned short hh = f2bf(hn);
            Ah[b2 * AHS + jj] = hh;
            if (Hhi)
                Hhi[((size_t)bg * TSEQ + step) * 128 + jj] = hh;
        }
        // single barrier: Ah writes must be visible to all waves' phase-1
        __syncthreads();
    }

    // fused FC head (layer 1): out[bg] = dot(h_last[bg], fcw) + fcb
    if (outp) {
        float* red = (float*)Ah;   // 2 KiB scratch, Ah is dead now
        red[b2 * 128 + jj] = hn_last * fcw[jj];
        __syncthreads();
        if (wave < 4) {            // wave w reduces sequence b0+w
            float v = red[wave * 128 + lane] + red[wave * 128 + lane + 64];
            #pragma unroll
            for (int off = 32; off > 0; off >>= 1)
                v += __shfl_down(v, off);
            if (lane == 0) outp[b0 + wave] = v + fcb[0];
        }
    }
}

// ---------------------------------------------------------------- launch
extern "C" void kernel_launch(void* const* d_in, const int* in_sizes, int n_in,
                              void* d_out, int out_size, void* d_ws, size_t ws_size,
                              hipStream_t stream)
{
    const float* x    = (const float*)d_in[0];
    const int*   ei   = (const int*)d_in[1];
    const float* W1   = (const float*)d_in[3];
    const float* b1   = (const float*)d_in[4];
    const float* W2   = (const float*)d_in[5];
    const float* b2   = (const float*)d_in[6];
    const float* fcw  = (const float*)d_in[7];
    const float* fcb  = (const float*)d_in[8];
    const float* wih0 = (const float*)d_in[9];
    const float* whh0 = (const float*)d_in[10];
    const float* bih0 = (const float*)d_in[11];
    const float* bhh0 = (const float*)d_in[12];
    const float* wih1 = (const float*)d_in[13];
    const float* whh1 = (const float*)d_in[14];
    const float* bih1 = (const float*)d_in[15];
    const float* bhh1 = (const float*)d_in[16];
    float* out = (float*)d_out;

    char* ws = (char*)d_ws;
    // ---- persistent regions
    unsigned short* shi = (unsigned short*)(ws + 0);          // 12.8 MB
    unsigned short* slo = (unsigned short*)(ws + 12800000);   // 12.8 MB (ends 25.6M)
    float* bufG = (float*)(ws + 51200000);                    // 102.4 MB (ends 153.6M)

    // ---- GCN-phase regions (inside bufG, dead before gate GEMM writes bufG)
    unsigned short* xhi = (unsigned short*)(ws + 51200000);   // 12.8 MB
    unsigned short* xlo = (unsigned short*)(ws + 64000000);   // 12.8 MB
    float* bufHg  = (float*)(ws + 76800000);                  // 25.6 MB (ends 102.4M)
    int* cnt      = (int*)(ws + 102400000);                   // 200000 B (pad 204800)
    int* cursor   = (int*)(ws + 102604800);                   // contiguous with cnt
    int* rowstart = (int*)(ws + 102809600);
    int* adj      = (int*)(ws + 103014400);                   // 2.4 MB (ends 105.42M)
    int* bsum     = (int*)(ws + 105420800);                   // NSCB ints

    float* dinv = (float*)(ws + 153600000);
    float* bp0  = (float*)(ws + 153800192);
    float* bp1  = (float*)(ws + 153802240);
    unsigned short* w1t_hi   = (unsigned short*)(ws + 153804288);
    unsigned short* w1t_lo   = (unsigned short*)(ws + 153837056);
    unsigned short* w2t_hi   = (unsigned short*)(ws + 153869824);
    unsigned short* w2t_lo   = (unsigned short*)(ws + 153902592);
    unsigned short* wpih0_hi = (unsigned short*)(ws + 153935360);
    unsigned short* wpih0_lo = (unsigned short*)(ws + 154066432);
    unsigned short* wpih1_hi = (unsigned short*)(ws + 154197504);
    unsigned short* wpih1_lo = (unsigned short*)(ws + 154328576);
    unsigned short* wphh0_hi = (unsigned short*)(ws + 154459648);
    unsigned short* wphh0_lo = (unsigned short*)(ws + 154590720);
    unsigned short* wphh1_hi = (unsigned short*)(ws + 154721792);
    unsigned short* wphh1_lo = (unsigned short*)(ws + 154852864);

    // ---- CSR build + dinv (multi-block scan); cnt+cursor zeroed in ONE memset
    hipMemsetAsync(cnt, 0, 409600, stream);
    k_count<<<(NE + 255) / 256, 256, 0, stream>>>(ei, cnt);
    k_bsum<<<NSCB, 256, 0, stream>>>(cnt, bsum);
    k_bscan<<<1, 256, 0, stream>>>(bsum);
    k_bout<<<NSCB, 256, 0, stream>>>(cnt, bsum, rowstart, dinv);
    k_fill<<<(NE + 255) / 256, 256, 0, stream>>>(ei, rowstart, cursor, adj);

    // ---- weight prep
    k_prep_gcnw2<<<128, 256, 0, stream>>>(W1, W2, w1t_hi, w1t_lo, w2t_hi, w2t_lo);
    k_prep_lstm<<<514, 256, 0, stream>>>(wih0, whh0, bih0, bhh0,
                                         wpih0_hi, wpih0_lo, wphh0_hi, wphh0_lo, bp0);
    k_prep_lstm<<<514, 256, 0, stream>>>(wih1, whh1, bih1, bhh1,
                                         wpih1_hi, wpih1_lo, wphh1_hi, wphh1_lo, bp1);

    dim3 gH(1, 391);     // GCN GEMMs: 128-row panel, NT=2 (128 cols)

    // ---- GCN layer 1 (fp32 A, convert-on-stage)
    k_gemm_mfma_xa<<<gH, 256, 0, stream>>>(x, w1t_hi, w1t_lo, nullptr, bufHg, NND, 128, 2);
    k_gather<<<NND / 4, 256, 0, stream>>>(rowstart, adj, bufHg, dinv, b1, xhi, xlo);

    // ---- GCN layer 2
    k_gemm_mfma<<<gH, 256, 0, stream>>>(xhi, xlo, w2t_hi, w2t_lo, nullptr, bufHg, NND, 128, 2);
    k_gather<<<NND / 4, 256, 0, stream>>>(rowstart, adj, bufHg, dinv, b2, shi, slo);

    // ---- LSTM layer 0: swapped-operand gate GEMM (3-term) + recurrence
    k_gemm_gT<<<782, 256, 0, stream>>>(shi, slo, wpih0_hi, wpih0_lo, bp0, bufG, NND);
    k_lstm<<<NB / SB, 512, 0, stream>>>(bufG, wphh0_hi, wphh0_lo, shi,
                                        nullptr, nullptr, nullptr);

    // ---- LSTM layer 1: 2-term swapped gate GEMM (A = bf16 h) + recurrence + FC
    k_gemm_gT_h<<<782, 256, 0, stream>>>(shi, wpih1_hi, wpih1_lo, bp1, bufG, NND);
    k_lstm<<<NB / SB, 512, 0, stream>>>(bufG, wphh1_hi, wphh1_lo, nullptr,
                                        fcw, fcb, out);
}

// Round 10
// 518.606 us; speedup vs baseline: 1.0252x; 1.0252x over previous
//
#include <hip/hip_runtime.h>

// Problem constants (fixed by the reference file)
#define NND 50000   // nodes
#define NE  600000  // edges
#define TSEQ 50     // sequence length
#define NB  1000    // batch = NND/TSEQ
#define SB  4       // sequences per LSTM workgroup
#define AHS 136     // LDS h-row stride in shorts (128 + 8 pad, 16B-aligned)
#define NSCB 196    // scan blocks: ceil(NND/256)

typedef __attribute__((ext_vector_type(4))) float f32x4;
typedef __attribute__((ext_vector_type(8))) short s16x8;

// ---------------------------------------------------------------- helpers
__device__ __forceinline__ float sigf(float x) {
    return 1.0f / (1.0f + __expf(-x));
}
__device__ __forceinline__ float tanhfast(float x) {
    x = fminf(fmaxf(x, -15.f), 15.f);
    float e = __expf(2.f * x);
    return (e - 1.f) / (e + 1.f);
}
// bf16 bit helpers (round-to-nearest-even)
__device__ __forceinline__ unsigned short f2bf(float f) {
    unsigned int u = __float_as_uint(f);
    u = u + 0x7FFFu + ((u >> 16) & 1u);
    return (unsigned short)(u >> 16);
}
__device__ __forceinline__ float bf2f(unsigned short h) {
    return __uint_as_float(((unsigned int)h) << 16);
}
// G row permutation: node n -> block-local row (blk*200 + step*4 + seq_in_blk).
// Pure bijection on [0, NND): LSTM block b reads contiguous 8KB per step.
__device__ __forceinline__ int grow_perm(int n) {
    int grp = n / 200;
    int rem = n % 200;
    return grp * 200 + (n % 50) * 4 + rem / 50;
}

// ---------------------------------------------------------------- CSR build
__global__ void k_count(const int* __restrict__ ei, int* __restrict__ cnt) {
    int e = blockIdx.x * 256 + threadIdx.x;
    if (e < NE) atomicAdd(&cnt[ei[NE + e]], 1);
}

// ---- 3-stage multi-block exclusive scan of cnt -> rowstart (+ fused dinv)
__global__ __launch_bounds__(256) void k_bsum(const int* __restrict__ cnt,
                                              int* __restrict__ bsum) {
    __shared__ int red[256];
    int t = threadIdx.x;
    int idx = blockIdx.x * 256 + t;
    red[t] = (idx < NND) ? cnt[idx] : 0;
    __syncthreads();
    for (int off = 128; off > 0; off >>= 1) {
        if (t < off) red[t] += red[t + off];
        __syncthreads();
    }
    if (t == 0) bsum[blockIdx.x] = red[0];
}

__global__ __launch_bounds__(256) void k_bscan(int* __restrict__ bsum) {
    __shared__ int ps[256];
    int t = threadIdx.x;
    int v = (t < NSCB) ? bsum[t] : 0;
    ps[t] = v;
    __syncthreads();
    for (int off = 1; off < 256; off <<= 1) {
        int u = 0;
        if (t >= off) u = ps[t - off];
        __syncthreads();
        if (t >= off) ps[t] += u;
        __syncthreads();
    }
    if (t < NSCB) bsum[t] = ps[t] - v;   // exclusive
}

__global__ __launch_bounds__(256) void k_bout(const int* __restrict__ cnt,
                                              const int* __restrict__ bsum,
                                              int* __restrict__ rowstart,
                                              float* __restrict__ dinv) {
    __shared__ int ps[256];
    int t = threadIdx.x;
    int idx = blockIdx.x * 256 + t;
    int v = (idx < NND) ? cnt[idx] : 0;
    ps[t] = v;
    __syncthreads();
    for (int off = 1; off < 256; off <<= 1) {
        int u = 0;
        if (t >= off) u = ps[t - off];
        __syncthreads();
        if (t >= off) ps[t] += u;
        __syncthreads();
    }
    int boff = bsum[blockIdx.x];
    if (idx < NND) {
        rowstart[idx] = boff + ps[t] - v;   // exclusive
        dinv[idx] = 1.0f / sqrtf((float)v + 1.0f);   // fused (was k_dinv)
    }
    if (idx == NND - 1) rowstart[NND] = boff + ps[t];  // == NE
}

__global__ void k_fill(const int* __restrict__ ei, const int* __restrict__ rowstart,
                       int* __restrict__ cursor, int* __restrict__ adj) {
    int e = blockIdx.x * 256 + threadIdx.x;
    if (e >= NE) return;
    int s = ei[e], d = ei[NE + e];
    int pos = atomicAdd(&cursor[d], 1);
    adj[rowstart[d] + pos] = s;
}

// ---------------------------------------------------------------- MFMA GEMM
// GCN layers (Nc=128): 128x128 A panel staged once, NT col-tiles per block.
__global__ __launch_bounds__(256) void k_gemm_mfma(
    const unsigned short* __restrict__ Ahi, const unsigned short* __restrict__ Alo,
    const unsigned short* __restrict__ Bhi, const unsigned short* __restrict__ Blo,
    const float* __restrict__ bias, float* __restrict__ C,
    int M, int Nc, int NT)
{
    __shared__ unsigned short As_hi[128][136];
    __shared__ unsigned short As_lo[128][136];

    const int tid  = threadIdx.x;
    const int lane = tid & 63, wave = tid >> 6;
    const int mw = wave & 1, nw = wave >> 1;
    const int l15 = lane & 15, quad = lane >> 4;
    const int rowBase = blockIdx.y * 128;

    {
        int r0 = tid >> 4;            // 0..15
        int ko = (tid & 15) * 8;      // 0..120
        #pragma unroll
        for (int i = 0; i < 8; ++i) {
            int row = r0 + i * 16;
            int g = rowBase + row;
            uint4 vh = make_uint4(0, 0, 0, 0), vl = make_uint4(0, 0, 0, 0);
            if (g < M) {
                vh = *(const uint4*)&Ahi[(size_t)g * 128 + ko];
                vl = *(const uint4*)&Alo[(size_t)g * 128 + ko];
            }
            *(uint4*)&As_hi[row][ko] = vh;
            *(uint4*)&As_lo[row][ko] = vl;
        }
    }
    __syncthreads();

    for (int nt = 0; nt < NT; ++nt) {
        const int colBase = (blockIdx.x * NT + nt) * 64;

        s16x8 bh[2][4], bl[2][4];   // [ns][kq]
        #pragma unroll
        for (int ns = 0; ns < 2; ++ns) {
            int gn = colBase + nw * 32 + ns * 16 + l15;
            #pragma unroll
            for (int kq = 0; kq < 4; ++kq) {
                bh[ns][kq] = *(const s16x8*)&Bhi[(size_t)gn * 128 + kq * 32 + quad * 8];
                bl[ns][kq] = *(const s16x8*)&Blo[(size_t)gn * 128 + kq * 32 + quad * 8];
            }
        }

        f32x4 acc[4][2] = {};
        #pragma unroll
        for (int kq = 0; kq < 4; ++kq) {
            int kof = kq * 32 + quad * 8;
            s16x8 ah[4], al[4];
            #pragma unroll
            for (int ms = 0; ms < 4; ++ms) {
                int r = mw * 64 + ms * 16 + l15;
                ah[ms] = *(const s16x8*)&As_hi[r][kof];
                al[ms] = *(const s16x8*)&As_lo[r][kof];
            }
            #pragma unroll
            for (int ms = 0; ms < 4; ++ms)
                #pragma unroll
                for (int ns = 0; ns < 2; ++ns)
                    acc[ms][ns] = __builtin_amdgcn_mfma_f32_16x16x32_bf16(ah[ms], bh[ns][kq], acc[ms][ns], 0, 0, 0);
            #pragma unroll
            for (int ms = 0; ms < 4; ++ms)
                #pragma unroll
                for (int ns = 0; ns < 2; ++ns)
                    acc[ms][ns] = __builtin_amdgcn_mfma_f32_16x16x32_bf16(al[ms], bh[ns][kq], acc[ms][ns], 0, 0, 0);
            #pragma unroll
            for (int ms = 0; ms < 4; ++ms)
                #pragma unroll
                for (int ns = 0; ns < 2; ++ns)
                    acc[ms][ns] = __builtin_amdgcn_mfma_f32_16x16x32_bf16(ah[ms], bl[ns][kq], acc[ms][ns], 0, 0, 0);
        }

        #pragma unroll
        for (int ns = 0; ns < 2; ++ns) {
            int col = colBase + nw * 32 + ns * 16 + l15;
            float bv = bias ? bias[col] : 0.f;
            #pragma unroll
            for (int ms = 0; ms < 4; ++ms) {
                int row0 = rowBase + mw * 64 + ms * 16 + quad * 4;
                #pragma unroll
                for (int r = 0; r < 4; ++r) {
                    int row = row0 + r;
                    if (row < M) C[(size_t)row * Nc + col] = acc[ms][ns][r] + bv;
                }
            }
        }
    }
}

// Variant: A is raw fp32 (input x); split-bf16 conversion fused into staging.
__global__ __launch_bounds__(256) void k_gemm_mfma_xa(
    const float* __restrict__ X,
    const unsigned short* __restrict__ Bhi, const unsigned short* __restrict__ Blo,
    const float* __restrict__ bias, float* __restrict__ C,
    int M, int Nc, int NT)
{
    __shared__ unsigned short As_hi[128][136];
    __shared__ unsigned short As_lo[128][136];

    const int tid  = threadIdx.x;
    const int lane = tid & 63, wave = tid >> 6;
    const int mw = wave & 1, nw = wave >> 1;
    const int l15 = lane & 15, quad = lane >> 4;
    const int rowBase = blockIdx.y * 128;

    {
        int r0 = tid >> 4;
        int ko = (tid & 15) * 8;
        #pragma unroll
        for (int i = 0; i < 8; ++i) {
            int row = r0 + i * 16;
            int g = rowBase + row;
            unsigned short hx[8], lx[8];
            if (g < M) {
                float4 v0 = *(const float4*)&X[(size_t)g * 128 + ko];
                float4 v1 = *(const float4*)&X[(size_t)g * 128 + ko + 4];
                const float vv[8] = {v0.x, v0.y, v0.z, v0.w, v1.x, v1.y, v1.z, v1.w};
                #pragma unroll
                for (int e = 0; e < 8; ++e) {
                    hx[e] = f2bf(vv[e]);
                    lx[e] = f2bf(vv[e] - bf2f(hx[e]));
                }
            } else {
                #pragma unroll
                for (int e = 0; e < 8; ++e) { hx[e] = 0; lx[e] = 0; }
            }
            *(uint4*)&As_hi[row][ko] = *(const uint4*)hx;
            *(uint4*)&As_lo[row][ko] = *(const uint4*)lx;
        }
    }
    __syncthreads();

    for (int nt = 0; nt < NT; ++nt) {
        const int colBase = (blockIdx.x * NT + nt) * 64;

        s16x8 bh[2][4], bl[2][4];
        #pragma unroll
        for (int ns = 0; ns < 2; ++ns) {
            int gn = colBase + nw * 32 + ns * 16 + l15;
            #pragma unroll
            for (int kq = 0; kq < 4; ++kq) {
                bh[ns][kq] = *(const s16x8*)&Bhi[(size_t)gn * 128 + kq * 32 + quad * 8];
                bl[ns][kq] = *(const s16x8*)&Blo[(size_t)gn * 128 + kq * 32 + quad * 8];
            }
        }

        f32x4 acc[4][2] = {};
        #pragma unroll
        for (int kq = 0; kq < 4; ++kq) {
            int kof = kq * 32 + quad * 8;
            s16x8 ah[4], al[4];
            #pragma unroll
            for (int ms = 0; ms < 4; ++ms) {
                int r = mw * 64 + ms * 16 + l15;
                ah[ms] = *(const s16x8*)&As_hi[r][kof];
                al[ms] = *(const s16x8*)&As_lo[r][kof];
            }
            #pragma unroll
            for (int ms = 0; ms < 4; ++ms)
                #pragma unroll
                for (int ns = 0; ns < 2; ++ns)
                    acc[ms][ns] = __builtin_amdgcn_mfma_f32_16x16x32_bf16(ah[ms], bh[ns][kq], acc[ms][ns], 0, 0, 0);
            #pragma unroll
            for (int ms = 0; ms < 4; ++ms)
                #pragma unroll
                for (int ns = 0; ns < 2; ++ns)
                    acc[ms][ns] = __builtin_amdgcn_mfma_f32_16x16x32_bf16(al[ms], bh[ns][kq], acc[ms][ns], 0, 0, 0);
            #pragma unroll
            for (int ms = 0; ms < 4; ++ms)
                #pragma unroll
                for (int ns = 0; ns < 2; ++ns)
                    acc[ms][ns] = __builtin_amdgcn_mfma_f32_16x16x32_bf16(ah[ms], bl[ns][kq], acc[ms][ns], 0, 0, 0);
        }

        #pragma unroll
        for (int ns = 0; ns < 2; ++ns) {
            int col = colBase + nw * 32 + ns * 16 + l15;
            float bv = bias ? bias[col] : 0.f;
            #pragma unroll
            for (int ms = 0; ms < 4; ++ms) {
                int row0 = rowBase + mw * 64 + ms * 16 + quad * 4;
                #pragma unroll
                for (int r = 0; r < 4; ++r) {
                    int row = row0 + r;
                    if (row < M) C[(size_t)row * Nc + col] = acc[ms][ns][r] + bv;
                }
            }
        }
    }
}

// ---------------------------------------------------------------- gate GEMM v7
// SWAPPED-OPERAND layout (verified R7) + PERMUTED G rows: store at
// grow_perm(n) so each LSTM block's per-step gate input is one contiguous
// 8KB chunk (was 4 x 2KB at 100KB strides -> ~1.46 TB/s effective).
// Pure storage permutation: numerics bit-identical.
__global__ __launch_bounds__(256) void k_gemm_gT(
    const unsigned short* __restrict__ Ahi, const unsigned short* __restrict__ Alo,
    const unsigned short* __restrict__ Whi, const unsigned short* __restrict__ Wlo,
    const float* __restrict__ bp, float* __restrict__ G,
    int M)
{
    __shared__ unsigned short As_hi[64][136];
    __shared__ unsigned short As_lo[64][136];

    const int tid  = threadIdx.x;
    const int lane = tid & 63, wave = tid >> 6;
    const int l15 = lane & 15, quad = lane >> 4;
    const int rowBase = blockIdx.x * 64;

    {
        int r0 = tid >> 4;            // 0..15
        int ko = (tid & 15) * 8;      // 0..120
        #pragma unroll
        for (int i = 0; i < 4; ++i) {
            int row = r0 + i * 16;
            int g = rowBase + row;
            uint4 vh = make_uint4(0, 0, 0, 0), vl = make_uint4(0, 0, 0, 0);
            if (g < M) {
                vh = *(const uint4*)&Ahi[(size_t)g * 128 + ko];
                vl = *(const uint4*)&Alo[(size_t)g * 128 + ko];
            }
            *(uint4*)&As_hi[row][ko] = vh;
            *(uint4*)&As_lo[row][ko] = vl;
        }
    }
    __syncthreads();

    const int pb = wave * 128;   // wave's 128 gate-cols

    #pragma unroll
    for (int tp = 0; tp < 4; ++tp) {
        const int p0 = pb + tp * 32;

        // W frags for 2 p-tiles (A-operand: lane l15 -> p row within tile)
        s16x8 wh[2][4], wl[2][4];   // [tile][kq]
        #pragma unroll
        for (int t = 0; t < 2; ++t)
            #pragma unroll
            for (int kq = 0; kq < 4; ++kq) {
                const size_t wrow = (size_t)(p0 + t * 16 + l15) * 128 + kq * 32 + quad * 8;
                wh[t][kq] = *(const s16x8*)&Whi[wrow];
                wl[t][kq] = *(const s16x8*)&Wlo[wrow];
            }
        float4 bv[2];
        #pragma unroll
        for (int t = 0; t < 2; ++t)
            bv[t] = *(const float4*)&bp[p0 + t * 16 + quad * 4];

        #pragma unroll
        for (int rg = 0; rg < 4; ++rg) {
            // x frags (B-operand: lane l15 -> x row within rowgroup)
            s16x8 xh[4], xl[4];
            #pragma unroll
            for (int kq = 0; kq < 4; ++kq) {
                xh[kq] = *(const s16x8*)&As_hi[rg * 16 + l15][kq * 32 + quad * 8];
                xl[kq] = *(const s16x8*)&As_lo[rg * 16 + l15][kq * 32 + quad * 8];
            }
            f32x4 acc[2] = {};
            #pragma unroll
            for (int kq = 0; kq < 4; ++kq)
                #pragma unroll
                for (int t = 0; t < 2; ++t) {
                    acc[t] = __builtin_amdgcn_mfma_f32_16x16x32_bf16(wh[t][kq], xh[kq], acc[t], 0, 0, 0);
                    acc[t] = __builtin_amdgcn_mfma_f32_16x16x32_bf16(wh[t][kq], xl[kq], acc[t], 0, 0, 0);
                    acc[t] = __builtin_amdgcn_mfma_f32_16x16x32_bf16(wl[t][kq], xh[kq], acc[t], 0, 0, 0);
                }
            const int row = rowBase + rg * 16 + l15;
            if (row < M) {
                const size_t prow = (size_t)grow_perm(row);
                #pragma unroll
                for (int t = 0; t < 2; ++t) {
                    float4 o;
                    o.x = acc[t][0] + bv[t].x;
                    o.y = acc[t][1] + bv[t].y;
                    o.z = acc[t][2] + bv[t].z;
                    o.w = acc[t][3] + bv[t].w;
                    *(float4*)&G[prow * 512 + p0 + t * 16 + quad * 4] = o;
                }
            }
        }
    }
}

// 2-term variant (A plain bf16): layer-1 gate GEMM. LDS 17.4 KB.
__global__ __launch_bounds__(256) void k_gemm_gT_h(
    const unsigned short* __restrict__ Ahi,
    const unsigned short* __restrict__ Whi, const unsigned short* __restrict__ Wlo,
    const float* __restrict__ bp, float* __restrict__ G,
    int M)
{
    __shared__ unsigned short As_hi[64][136];

    const int tid  = threadIdx.x;
    const int lane = tid & 63, wave = tid >> 6;
    const int l15 = lane & 15, quad = lane >> 4;
    const int rowBase = blockIdx.x * 64;

    {
        int r0 = tid >> 4;
        int ko = (tid & 15) * 8;
        #pragma unroll
        for (int i = 0; i < 4; ++i) {
            int row = r0 + i * 16;
            int g = rowBase + row;
            uint4 vh = make_uint4(0, 0, 0, 0);
            if (g < M) vh = *(const uint4*)&Ahi[(size_t)g * 128 + ko];
            *(uint4*)&As_hi[row][ko] = vh;
        }
    }
    __syncthreads();

    const int pb = wave * 128;

    #pragma unroll
    for (int tp = 0; tp < 4; ++tp) {
        const int p0 = pb + tp * 32;

        s16x8 wh[2][4], wl[2][4];
        #pragma unroll
        for (int t = 0; t < 2; ++t)
            #pragma unroll
            for (int kq = 0; kq < 4; ++kq) {
                const size_t wrow = (size_t)(p0 + t * 16 + l15) * 128 + kq * 32 + quad * 8;
                wh[t][kq] = *(const s16x8*)&Whi[wrow];
                wl[t][kq] = *(const s16x8*)&Wlo[wrow];
            }
        float4 bv[2];
        #pragma unroll
        for (int t = 0; t < 2; ++t)
            bv[t] = *(const float4*)&bp[p0 + t * 16 + quad * 4];

        #pragma unroll
        for (int rg = 0; rg < 4; ++rg) {
            s16x8 xh[4];
            #pragma unroll
            for (int kq = 0; kq < 4; ++kq)
                xh[kq] = *(const s16x8*)&As_hi[rg * 16 + l15][kq * 32 + quad * 8];
            f32x4 acc[2] = {};
            #pragma unroll
            for (int kq = 0; kq < 4; ++kq)
                #pragma unroll
                for (int t = 0; t < 2; ++t) {
                    acc[t] = __builtin_amdgcn_mfma_f32_16x16x32_bf16(wh[t][kq], xh[kq], acc[t], 0, 0, 0);
                    acc[t] = __builtin_amdgcn_mfma_f32_16x16x32_bf16(wl[t][kq], xh[kq], acc[t], 0, 0, 0);
                }
            const int row = rowBase + rg * 16 + l15;
            if (row < M) {
                const size_t prow = (size_t)grow_perm(row);
                #pragma unroll
                for (int t = 0; t < 2; ++t) {
                    float4 o;
                    o.x = acc[t][0] + bv[t].x;
                    o.y = acc[t][1] + bv[t].y;
                    o.z = acc[t][2] + bv[t].z;
                    o.w = acc[t][3] + bv[t].w;
                    *(float4*)&G[prow * 512 + p0 + t * 16 + quad * 4] = o;
                }
            }
        }
    }
}

// ---------------------------------------------------------------- GCN gather
// Edge loop unrolled x4 (4 h-rows in flight); accumulation order preserved.
__global__ __launch_bounds__(256) void k_gather(
    const int* __restrict__ rowstart, const int* __restrict__ adj,
    const float* __restrict__ h, const float* __restrict__ dinv,
    const float* __restrict__ bias,
    unsigned short* __restrict__ hi, unsigned short* __restrict__ lo)
{
    const int n    = blockIdx.x * 4 + (threadIdx.x >> 6);   // grid exactly NND/4
    const int lane = threadIdx.x & 63;
    const int r0 = rowstart[n], r1 = rowstart[n + 1];
    const float dn = dinv[n];

    float2 hv = *(const float2*)&h[(size_t)n * 128 + 2 * lane];
    float2 acc;
    acc.x = hv.x * dn;
    acc.y = hv.y * dn;

    int i = r0;
    for (; i + 4 <= r1; i += 4) {
        int s0 = adj[i], s1 = adj[i + 1], s2 = adj[i + 2], s3 = adj[i + 3];
        float d0 = dinv[s0], d1 = dinv[s1], d2 = dinv[s2], d3 = dinv[s3];
        float2 v0 = *(const float2*)&h[(size_t)s0 * 128 + 2 * lane];
        float2 v1 = *(const float2*)&h[(size_t)s1 * 128 + 2 * lane];
        float2 v2 = *(const float2*)&h[(size_t)s2 * 128 + 2 * lane];
        float2 v3 = *(const float2*)&h[(size_t)s3 * 128 + 2 * lane];
        acc.x += v0.x * d0; acc.y += v0.y * d0;
        acc.x += v1.x * d1; acc.y += v1.y * d1;
        acc.x += v2.x * d2; acc.y += v2.y * d2;
        acc.x += v3.x * d3; acc.y += v3.y * d3;
    }
    for (; i < r1; ++i) {
        int s = adj[i];
        float ds = dinv[s];
        float2 v = *(const float2*)&h[(size_t)s * 128 + 2 * lane];
        acc.x += v.x * ds;
        acc.y += v.y * ds;
    }

    float2 bb = *(const float2*)&bias[2 * lane];
    float vx = fmaxf(acc.x * dn + bb.x, 0.f);
    float vy = fmaxf(acc.y * dn + bb.y, 0.f);
    ushort2 ho, lo2;
    ho.x = f2bf(vx); lo2.x = f2bf(vx - bf2f(ho.x));
    ho.y = f2bf(vy); lo2.y = f2bf(vy - bf2f(ho.y));
    *(ushort2*)&hi[(size_t)n * 128 + 2 * lane] = ho;
    *(ushort2*)&lo[(size_t)n * 128 + 2 * lane] = lo2;
}

// ---------------------------------------------------------------- prep kernels
__global__ void k_prep_gcnw2(const float* __restrict__ W1, const float* __restrict__ W2,
                             unsigned short* __restrict__ hi1, unsigned short* __restrict__ lo1,
                             unsigned short* __restrict__ hi2, unsigned short* __restrict__ lo2) {
    int t = blockIdx.x * 256 + threadIdx.x;   // grid 128 -> 32768 threads
    const float* W = (t < 16384) ? W1 : W2;
    unsigned short* hi = (t < 16384) ? hi1 : hi2;
    unsigned short* lo = (t < 16384) ? lo1 : lo2;
    int tt = t & 16383;
    int k = tt >> 7, n = tt & 127;
    float v = W[tt];
    unsigned short h = f2bf(v);
    hi[n * 128 + k] = h;
    lo[n * 128 + k] = f2bf(v - bf2f(h));
}

// LSTM prep: w_ih and w_hh [512(r=g*128+j)][128(k)] -> packed-transposed
// split-bf16 wT[p=j*4+g][k]; bias -> bp[p] = b_ih + b_hh.
__global__ void k_prep_lstm(const float* __restrict__ w_ih, const float* __restrict__ w_hh,
                            const float* __restrict__ b_ih, const float* __restrict__ b_hh,
                            unsigned short* __restrict__ ih_hi, unsigned short* __restrict__ ih_lo,
                            unsigned short* __restrict__ hh_hi, unsigned short* __restrict__ hh_lo,
                            float* __restrict__ bp)
{
    int t = blockIdx.x * 256 + threadIdx.x;
    if (t < 65536) {
        int r = t >> 7, k = t & 127;
        int g = r >> 7, j = r & 127;
        int p = (j << 2) + g;
        float v = w_ih[t];
        unsigned short h = f2bf(v);
        ih_hi[p * 128 + k] = h;
        ih_lo[p * 128 + k] = f2bf(v - bf2f(h));
    } else if (t < 131072) {
        int t2 = t - 65536;
        int r = t2 >> 7, k = t2 & 127;
        int g = r >> 7, j = r & 127;
        int p = (j << 2) + g;
        float v = w_hh[t2];
        unsigned short h = f2bf(v);
        hh_hi[p * 128 + k] = h;
        hh_lo[p * 128 + k] = f2bf(v - bf2f(h));
    } else if (t < 131584) {
        int r = t - 131072;   // 0..511
        int g = r >> 7, j = r & 127;
        bp[(j << 2) + g] = b_ih[r] + b_hh[r];
    }
}

// ---------------------------------------------------------------- LSTM recurrence
// v12: v10 + permuted-G streaming read (contiguous 8KB/block/step) + one-step
// register prefetch of the gate input (full step of latency cover, was half a
// phase). R9 falsified the register-rematerialization theory (VGPR count and
// dur identical with pins) — the binding constraint is the per-step G-read at
// ~1.46 TB/s effective. Numerics bit-identical (storage permutation only).
__global__ __launch_bounds__(512, 2) void k_lstm(
    const float* __restrict__ G,            // permuted: [blk][step][4 seq][512]
    const unsigned short* __restrict__ Whi, // 512 x 128, packed-transposed hi
    const unsigned short* __restrict__ Wlo, // lo
    unsigned short* __restrict__ Hhi,       // (NB*TSEQ) x 128 bf16-hi, or nullptr
    const float* __restrict__ fcw,          // fused FC weight (layer 1) or nullptr
    const float* __restrict__ fcb,
    float* __restrict__ outp)               // NB x 1 output (layer 1) or nullptr
{
    const int tid  = threadIdx.x;
    const int lane = tid & 63, wave = tid >> 6;   // 8 waves
    const int l15  = lane & 15, quad = lane >> 4;
    const int b0   = blockIdx.x * SB;

    __shared__ __align__(16) unsigned short Ah[16 * AHS];  // h bf16 (rows SB..15 zero)
    __shared__ float partw[8][4][72];        // per-wave P patch [wave][b][col in wave]

    // weight fragments: wave owns n-tiles nt0..nt0+3 (n = p = j*4+gate)
    const int nt0 = wave * 4;
    s16x8 bh[4][4], bl[4][4];   // [nt][ks]
    #pragma unroll
    for (int nt = 0; nt < 4; ++nt) {
        int p = (nt0 + nt) * 16 + l15;
        #pragma unroll
        for (int ks = 0; ks < 4; ++ks) {
            bh[nt][ks] = *(const s16x8*)&Whi[(size_t)p * 128 + ks * 32 + quad * 8];
            bl[nt][ks] = *(const s16x8*)&Wlo[(size_t)p * 128 + ks * 32 + quad * 8];
        }
    }

    for (int i = tid; i < 16 * AHS; i += 512) Ah[i] = 0;

    // phase-2 mapping: lane l of wave w -> (b2, j) with j owned by wave w
    const int b2 = lane >> 4;              // 0..3
    const int jj = wave * 16 + l15;        // hidden unit this lane updates
    const int bg = b0 + b2;                // sequence index (NB % SB == 0)
    float c = 0.f;
    float hn_last = 0.f;

    // permuted-G base: row' = blk*200 + step*4 + b2; step stride = 2048 floats
    const float* gb = &G[((size_t)blockIdx.x * 200 + b2) * 512 + (jj << 2)];
    float4 gv_cur = *(const float4*)&gb[0];

    __syncthreads();

    for (int step = 0; step < TSEQ; ++step) {
        // prefetch NEXT step's gate input (full step of latency cover)
        const int nstep = (step + 1 < TSEQ) ? step + 1 : step;
        const float4 gv_nxt = *(const float4*)&gb[(size_t)nstep * 2048];

        // phase 1: MFMA  P = bf16(h) @ (Whi + Wlo)
        f32x4 acc[4] = {};
        #pragma unroll
        for (int ks = 0; ks < 4; ++ks) {
            s16x8 ah = *(const s16x8*)&Ah[l15 * AHS + ks * 32 + quad * 8];
            #pragma unroll
            for (int nt = 0; nt < 4; ++nt) {
                acc[nt] = __builtin_amdgcn_mfma_f32_16x16x32_bf16(ah, bh[nt][ks], acc[nt], 0, 0, 0);
                acc[nt] = __builtin_amdgcn_mfma_f32_16x16x32_bf16(ah, bl[nt][ks], acc[nt], 0, 0, 0);
            }
        }

        // intra-wave exchange: quad-0 lanes hold rows 0..3 (the real seqs)
        if (quad == 0) {
            #pragma unroll
            for (int nt = 0; nt < 4; ++nt)
                #pragma unroll
                for (int r = 0; r < 4; ++r)
                    partw[wave][r][nt * 16 + l15] = acc[nt][r];
        }
        // same-wave producer/consumer: compiler inserts lgkmcnt wait, no barrier

        // phase 2: LSTM cell for (b2, jj); reads this wave's own patch
        {
            float4 pa = *(const float4*)&partw[wave][b2][l15 * 4];
            float xi = pa.x + gv_cur.x;
            float xf = pa.y + gv_cur.y;
            float xg = pa.z + gv_cur.z;
            float xo = pa.w + gv_cur.w;
            float ii = sigf(xi), ff = sigf(xf), gg = tanhfast(xg), oo = sigf(xo);
            float cn = ff * c + ii * gg;
            c = cn;
            float hn = oo * tanhfast(cn);
            hn_last = hn;
            unsigned short hh = f2bf(hn);
            Ah[b2 * AHS + jj] = hh;
            if (Hhi)
                Hhi[((size_t)bg * TSEQ + step) * 128 + jj] = hh;
        }
        gv_cur = gv_nxt;
        // single barrier: Ah writes must be visible to all waves' phase-1
        __syncthreads();
    }

    // fused FC head (layer 1): out[bg] = dot(h_last[bg], fcw) + fcb
    if (outp) {
        float* red = (float*)Ah;   // 2 KiB scratch, Ah is dead now
        red[b2 * 128 + jj] = hn_last * fcw[jj];
        __syncthreads();
        if (wave < 4) {            // wave w reduces sequence b0+w
            float v = red[wave * 128 + lane] + red[wave * 128 + lane + 64];
            #pragma unroll
            for (int off = 32; off > 0; off >>= 1)
                v += __shfl_down(v, off);
            if (lane == 0) outp[b0 + wave] = v + fcb[0];
        }
    }
}

// ---------------------------------------------------------------- launch
extern "C" void kernel_launch(void* const* d_in, const int* in_sizes, int n_in,
                              void* d_out, int out_size, void* d_ws, size_t ws_size,
                              hipStream_t stream)
{
    const float* x    = (const float*)d_in[0];
    const int*   ei   = (const int*)d_in[1];
    const float* W1   = (const float*)d_in[3];
    const float* b1   = (const float*)d_in[4];
    const float* W2   = (const float*)d_in[5];
    const float* b2   = (const float*)d_in[6];
    const float* fcw  = (const float*)d_in[7];
    const float* fcb  = (const float*)d_in[8];
    const float* wih0 = (const float*)d_in[9];
    const float* whh0 = (const float*)d_in[10];
    const float* bih0 = (const float*)d_in[11];
    const float* bhh0 = (const float*)d_in[12];
    const float* wih1 = (const float*)d_in[13];
    const float* whh1 = (const float*)d_in[14];
    const float* bih1 = (const float*)d_in[15];
    const float* bhh1 = (const float*)d_in[16];
    float* out = (float*)d_out;

    char* ws = (char*)d_ws;
    // ---- persistent regions
    unsigned short* shi = (unsigned short*)(ws + 0);          // 12.8 MB
    unsigned short* slo = (unsigned short*)(ws + 12800000);   // 12.8 MB (ends 25.6M)
    float* bufG = (float*)(ws + 51200000);                    // 102.4 MB (ends 153.6M)

    // ---- GCN-phase regions (inside bufG, dead before gate GEMM writes bufG)
    unsigned short* xhi = (unsigned short*)(ws + 51200000);   // 12.8 MB
    unsigned short* xlo = (unsigned short*)(ws + 64000000);   // 12.8 MB
    float* bufHg  = (float*)(ws + 76800000);                  // 25.6 MB (ends 102.4M)
    int* cnt      = (int*)(ws + 102400000);                   // 200000 B (pad 204800)
    int* cursor   = (int*)(ws + 102604800);                   // contiguous with cnt
    int* rowstart = (int*)(ws + 102809600);
    int* adj      = (int*)(ws + 103014400);                   // 2.4 MB (ends 105.42M)
    int* bsum     = (int*)(ws + 105420800);                   // NSCB ints

    float* dinv = (float*)(ws + 153600000);
    float* bp0  = (float*)(ws + 153800192);
    float* bp1  = (float*)(ws + 153802240);
    unsigned short* w1t_hi   = (unsigned short*)(ws + 153804288);
    unsigned short* w1t_lo   = (unsigned short*)(ws + 153837056);
    unsigned short* w2t_hi   = (unsigned short*)(ws + 153869824);
    unsigned short* w2t_lo   = (unsigned short*)(ws + 153902592);
    unsigned short* wpih0_hi = (unsigned short*)(ws + 153935360);
    unsigned short* wpih0_lo = (unsigned short*)(ws + 154066432);
    unsigned short* wpih1_hi = (unsigned short*)(ws + 154197504);
    unsigned short* wpih1_lo = (unsigned short*)(ws + 154328576);
    unsigned short* wphh0_hi = (unsigned short*)(ws + 154459648);
    unsigned short* wphh0_lo = (unsigned short*)(ws + 154590720);
    unsigned short* wphh1_hi = (unsigned short*)(ws + 154721792);
    unsigned short* wphh1_lo = (unsigned short*)(ws + 154852864);

    // ---- CSR build + dinv (multi-block scan); cnt+cursor zeroed in ONE memset
    hipMemsetAsync(cnt, 0, 409600, stream);
    k_count<<<(NE + 255) / 256, 256, 0, stream>>>(ei, cnt);
    k_bsum<<<NSCB, 256, 0, stream>>>(cnt, bsum);
    k_bscan<<<1, 256, 0, stream>>>(bsum);
    k_bout<<<NSCB, 256, 0, stream>>>(cnt, bsum, rowstart, dinv);
    k_fill<<<(NE + 255) / 256, 256, 0, stream>>>(ei, rowstart, cursor, adj);

    // ---- weight prep
    k_prep_gcnw2<<<128, 256, 0, stream>>>(W1, W2, w1t_hi, w1t_lo, w2t_hi, w2t_lo);
    k_prep_lstm<<<514, 256, 0, stream>>>(wih0, whh0, bih0, bhh0,
                                         wpih0_hi, wpih0_lo, wphh0_hi, wphh0_lo, bp0);
    k_prep_lstm<<<514, 256, 0, stream>>>(wih1, whh1, bih1, bhh1,
                                         wpih1_hi, wpih1_lo, wphh1_hi, wphh1_lo, bp1);

    dim3 gH(1, 391);     // GCN GEMMs: 128-row panel, NT=2 (128 cols)

    // ---- GCN layer 1 (fp32 A, convert-on-stage)
    k_gemm_mfma_xa<<<gH, 256, 0, stream>>>(x, w1t_hi, w1t_lo, nullptr, bufHg, NND, 128, 2);
    k_gather<<<NND / 4, 256, 0, stream>>>(rowstart, adj, bufHg, dinv, b1, xhi, xlo);

    // ---- GCN layer 2
    k_gemm_mfma<<<gH, 256, 0, stream>>>(xhi, xlo, w2t_hi, w2t_lo, nullptr, bufHg, NND, 128, 2);
    k_gather<<<NND / 4, 256, 0, stream>>>(rowstart, adj, bufHg, dinv, b2, shi, slo);

    // ---- LSTM layer 0: swapped-operand gate GEMM (3-term, permuted G) + recurrence
    k_gemm_gT<<<782, 256, 0, stream>>>(shi, slo, wpih0_hi, wpih0_lo, bp0, bufG, NND);
    k_lstm<<<NB / SB, 512, 0, stream>>>(bufG, wphh0_hi, wphh0_lo, shi,
                                        nullptr, nullptr, nullptr);

    // ---- LSTM layer 1: 2-term swapped gate GEMM (permuted G) + recurrence + FC
    k_gemm_gT_h<<<782, 256, 0, stream>>>(shi, wpih1_hi, wpih1_lo, bp1, bufG, NND);
    k_lstm<<<NB / SB, 512, 0, stream>>>(bufG, wphh1_hi, wphh1_lo, nullptr,
                                        fcw, fcb, out);
}

// Round 11
// 485.808 us; speedup vs baseline: 1.0944x; 1.0675x over previous
//
#include <hip/hip_runtime.h>

// Problem constants (fixed by the reference file)
#define NND 50000   // nodes
#define NE  600000  // edges
#define TSEQ 50     // sequence length
#define NB  1000    // batch = NND/TSEQ
#define SB  4       // sequences per LSTM workgroup
#define AHS 136     // LDS h-row stride in shorts (128 + 8 pad, 16B-aligned)
#define NSCB 196    // scan blocks: ceil(NND/256)

typedef __attribute__((ext_vector_type(4))) float f32x4;
typedef __attribute__((ext_vector_type(8))) short s16x8;

// ---------------------------------------------------------------- helpers
__device__ __forceinline__ float sigf(float x) {
    return 1.0f / (1.0f + __expf(-x));
}
__device__ __forceinline__ float tanhfast(float x) {
    x = fminf(fmaxf(x, -15.f), 15.f);
    float e = __expf(2.f * x);
    return (e - 1.f) / (e + 1.f);
}
// bf16 bit helpers (round-to-nearest-even)
__device__ __forceinline__ unsigned short f2bf(float f) {
    unsigned int u = __float_as_uint(f);
    u = u + 0x7FFFu + ((u >> 16) & 1u);
    return (unsigned short)(u >> 16);
}
__device__ __forceinline__ float bf2f(unsigned short h) {
    return __uint_as_float(((unsigned int)h) << 16);
}
// G row permutation: node n -> block-local row (blk*200 + step*4 + seq_in_blk).
// Pure bijection on [0, NND): LSTM block b reads contiguous 8KB per step.
__device__ __forceinline__ int grow_perm(int n) {
    int grp = n / 200;
    int rem = n % 200;
    return grp * 200 + (n % 50) * 4 + rem / 50;
}

// ---------------------------------------------------------------- CSR build
__global__ void k_count(const int* __restrict__ ei, int* __restrict__ cnt) {
    int e = blockIdx.x * 256 + threadIdx.x;
    if (e < NE) atomicAdd(&cnt[ei[NE + e]], 1);
}

// ---- 3-stage multi-block exclusive scan of cnt -> rowstart (+ fused dinv)
__global__ __launch_bounds__(256) void k_bsum(const int* __restrict__ cnt,
                                              int* __restrict__ bsum) {
    __shared__ int red[256];
    int t = threadIdx.x;
    int idx = blockIdx.x * 256 + t;
    red[t] = (idx < NND) ? cnt[idx] : 0;
    __syncthreads();
    for (int off = 128; off > 0; off >>= 1) {
        if (t < off) red[t] += red[t + off];
        __syncthreads();
    }
    if (t == 0) bsum[blockIdx.x] = red[0];
}

__global__ __launch_bounds__(256) void k_bscan(int* __restrict__ bsum) {
    __shared__ int ps[256];
    int t = threadIdx.x;
    int v = (t < NSCB) ? bsum[t] : 0;
    ps[t] = v;
    __syncthreads();
    for (int off = 1; off < 256; off <<= 1) {
        int u = 0;
        if (t >= off) u = ps[t - off];
        __syncthreads();
        if (t >= off) ps[t] += u;
        __syncthreads();
    }
    if (t < NSCB) bsum[t] = ps[t] - v;   // exclusive
}

__global__ __launch_bounds__(256) void k_bout(const int* __restrict__ cnt,
                                              const int* __restrict__ bsum,
                                              int* __restrict__ rowstart,
                                              float* __restrict__ dinv) {
    __shared__ int ps[256];
    int t = threadIdx.x;
    int idx = blockIdx.x * 256 + t;
    int v = (idx < NND) ? cnt[idx] : 0;
    ps[t] = v;
    __syncthreads();
    for (int off = 1; off < 256; off <<= 1) {
        int u = 0;
        if (t >= off) u = ps[t - off];
        __syncthreads();
        if (t >= off) ps[t] += u;
        __syncthreads();
    }
    int boff = bsum[blockIdx.x];
    if (idx < NND) {
        rowstart[idx] = boff + ps[t] - v;   // exclusive
        dinv[idx] = 1.0f / sqrtf((float)v + 1.0f);   // fused (was k_dinv)
    }
    if (idx == NND - 1) rowstart[NND] = boff + ps[t];  // == NE
}

__global__ void k_fill(const int* __restrict__ ei, const int* __restrict__ rowstart,
                       int* __restrict__ cursor, int* __restrict__ adj) {
    int e = blockIdx.x * 256 + threadIdx.x;
    if (e >= NE) return;
    int s = ei[e], d = ei[NE + e];
    int pos = atomicAdd(&cursor[d], 1);
    adj[rowstart[d] + pos] = s;
}

// ---------------------------------------------------------------- MFMA GEMM
// GCN layers (Nc=128): 128x128 A panel staged once, NT col-tiles per block.
__global__ __launch_bounds__(256) void k_gemm_mfma(
    const unsigned short* __restrict__ Ahi, const unsigned short* __restrict__ Alo,
    const unsigned short* __restrict__ Bhi, const unsigned short* __restrict__ Blo,
    const float* __restrict__ bias, float* __restrict__ C,
    int M, int Nc, int NT)
{
    __shared__ unsigned short As_hi[128][136];
    __shared__ unsigned short As_lo[128][136];

    const int tid  = threadIdx.x;
    const int lane = tid & 63, wave = tid >> 6;
    const int mw = wave & 1, nw = wave >> 1;
    const int l15 = lane & 15, quad = lane >> 4;
    const int rowBase = blockIdx.y * 128;

    {
        int r0 = tid >> 4;            // 0..15
        int ko = (tid & 15) * 8;      // 0..120
        #pragma unroll
        for (int i = 0; i < 8; ++i) {
            int row = r0 + i * 16;
            int g = rowBase + row;
            uint4 vh = make_uint4(0, 0, 0, 0), vl = make_uint4(0, 0, 0, 0);
            if (g < M) {
                vh = *(const uint4*)&Ahi[(size_t)g * 128 + ko];
                vl = *(const uint4*)&Alo[(size_t)g * 128 + ko];
            }
            *(uint4*)&As_hi[row][ko] = vh;
            *(uint4*)&As_lo[row][ko] = vl;
        }
    }
    __syncthreads();

    for (int nt = 0; nt < NT; ++nt) {
        const int colBase = (blockIdx.x * NT + nt) * 64;

        s16x8 bh[2][4], bl[2][4];   // [ns][kq]
        #pragma unroll
        for (int ns = 0; ns < 2; ++ns) {
            int gn = colBase + nw * 32 + ns * 16 + l15;
            #pragma unroll
            for (int kq = 0; kq < 4; ++kq) {
                bh[ns][kq] = *(const s16x8*)&Bhi[(size_t)gn * 128 + kq * 32 + quad * 8];
                bl[ns][kq] = *(const s16x8*)&Blo[(size_t)gn * 128 + kq * 32 + quad * 8];
            }
        }

        f32x4 acc[4][2] = {};
        #pragma unroll
        for (int kq = 0; kq < 4; ++kq) {
            int kof = kq * 32 + quad * 8;
            s16x8 ah[4], al[4];
            #pragma unroll
            for (int ms = 0; ms < 4; ++ms) {
                int r = mw * 64 + ms * 16 + l15;
                ah[ms] = *(const s16x8*)&As_hi[r][kof];
                al[ms] = *(const s16x8*)&As_lo[r][kof];
            }
            #pragma unroll
            for (int ms = 0; ms < 4; ++ms)
                #pragma unroll
                for (int ns = 0; ns < 2; ++ns)
                    acc[ms][ns] = __builtin_amdgcn_mfma_f32_16x16x32_bf16(ah[ms], bh[ns][kq], acc[ms][ns], 0, 0, 0);
            #pragma unroll
            for (int ms = 0; ms < 4; ++ms)
                #pragma unroll
                for (int ns = 0; ns < 2; ++ns)
                    acc[ms][ns] = __builtin_amdgcn_mfma_f32_16x16x32_bf16(al[ms], bh[ns][kq], acc[ms][ns], 0, 0, 0);
            #pragma unroll
            for (int ms = 0; ms < 4; ++ms)
                #pragma unroll
                for (int ns = 0; ns < 2; ++ns)
                    acc[ms][ns] = __builtin_amdgcn_mfma_f32_16x16x32_bf16(ah[ms], bl[ns][kq], acc[ms][ns], 0, 0, 0);
        }

        #pragma unroll
        for (int ns = 0; ns < 2; ++ns) {
            int col = colBase + nw * 32 + ns * 16 + l15;
            float bv = bias ? bias[col] : 0.f;
            #pragma unroll
            for (int ms = 0; ms < 4; ++ms) {
                int row0 = rowBase + mw * 64 + ms * 16 + quad * 4;
                #pragma unroll
                for (int r = 0; r < 4; ++r) {
                    int row = row0 + r;
                    if (row < M) C[(size_t)row * Nc + col] = acc[ms][ns][r] + bv;
                }
            }
        }
    }
}

// Variant: A is raw fp32 (input x); split-bf16 conversion fused into staging.
__global__ __launch_bounds__(256) void k_gemm_mfma_xa(
    const float* __restrict__ X,
    const unsigned short* __restrict__ Bhi, const unsigned short* __restrict__ Blo,
    const float* __restrict__ bias, float* __restrict__ C,
    int M, int Nc, int NT)
{
    __shared__ unsigned short As_hi[128][136];
    __shared__ unsigned short As_lo[128][136];

    const int tid  = threadIdx.x;
    const int lane = tid & 63, wave = tid >> 6;
    const int mw = wave & 1, nw = wave >> 1;
    const int l15 = lane & 15, quad = lane >> 4;
    const int rowBase = blockIdx.y * 128;

    {
        int r0 = tid >> 4;
        int ko = (tid & 15) * 8;
        #pragma unroll
        for (int i = 0; i < 8; ++i) {
            int row = r0 + i * 16;
            int g = rowBase + row;
            unsigned short hx[8], lx[8];
            if (g < M) {
                float4 v0 = *(const float4*)&X[(size_t)g * 128 + ko];
                float4 v1 = *(const float4*)&X[(size_t)g * 128 + ko + 4];
                const float vv[8] = {v0.x, v0.y, v0.z, v0.w, v1.x, v1.y, v1.z, v1.w};
                #pragma unroll
                for (int e = 0; e < 8; ++e) {
                    hx[e] = f2bf(vv[e]);
                    lx[e] = f2bf(vv[e] - bf2f(hx[e]));
                }
            } else {
                #pragma unroll
                for (int e = 0; e < 8; ++e) { hx[e] = 0; lx[e] = 0; }
            }
            *(uint4*)&As_hi[row][ko] = *(const uint4*)hx;
            *(uint4*)&As_lo[row][ko] = *(const uint4*)lx;
        }
    }
    __syncthreads();

    for (int nt = 0; nt < NT; ++nt) {
        const int colBase = (blockIdx.x * NT + nt) * 64;

        s16x8 bh[2][4], bl[2][4];
        #pragma unroll
        for (int ns = 0; ns < 2; ++ns) {
            int gn = colBase + nw * 32 + ns * 16 + l15;
            #pragma unroll
            for (int kq = 0; kq < 4; ++kq) {
                bh[ns][kq] = *(const s16x8*)&Bhi[(size_t)gn * 128 + kq * 32 + quad * 8];
                bl[ns][kq] = *(const s16x8*)&Blo[(size_t)gn * 128 + kq * 32 + quad * 8];
            }
        }

        f32x4 acc[4][2] = {};
        #pragma unroll
        for (int kq = 0; kq < 4; ++kq) {
            int kof = kq * 32 + quad * 8;
            s16x8 ah[4], al[4];
            #pragma unroll
            for (int ms = 0; ms < 4; ++ms) {
                int r = mw * 64 + ms * 16 + l15;
                ah[ms] = *(const s16x8*)&As_hi[r][kof];
                al[ms] = *(const s16x8*)&As_lo[r][kof];
            }
            #pragma unroll
            for (int ms = 0; ms < 4; ++ms)
                #pragma unroll
                for (int ns = 0; ns < 2; ++ns)
                    acc[ms][ns] = __builtin_amdgcn_mfma_f32_16x16x32_bf16(ah[ms], bh[ns][kq], acc[ms][ns], 0, 0, 0);
            #pragma unroll
            for (int ms = 0; ms < 4; ++ms)
                #pragma unroll
                for (int ns = 0; ns < 2; ++ns)
                    acc[ms][ns] = __builtin_amdgcn_mfma_f32_16x16x32_bf16(al[ms], bh[ns][kq], acc[ms][ns], 0, 0, 0);
            #pragma unroll
            for (int ms = 0; ms < 4; ++ms)
                #pragma unroll
                for (int ns = 0; ns < 2; ++ns)
                    acc[ms][ns] = __builtin_amdgcn_mfma_f32_16x16x32_bf16(ah[ms], bl[ns][kq], acc[ms][ns], 0, 0, 0);
        }

        #pragma unroll
        for (int ns = 0; ns < 2; ++ns) {
            int col = colBase + nw * 32 + ns * 16 + l15;
            float bv = bias ? bias[col] : 0.f;
            #pragma unroll
            for (int ms = 0; ms < 4; ++ms) {
                int row0 = rowBase + mw * 64 + ms * 16 + quad * 4;
                #pragma unroll
                for (int r = 0; r < 4; ++r) {
                    int row = row0 + r;
                    if (row < M) C[(size_t)row * Nc + col] = acc[ms][ns][r] + bv;
                }
            }
        }
    }
}

// ---------------------------------------------------------------- gate GEMM v7
// SWAPPED-OPERAND layout (verified R7) + PERMUTED G rows (verified R10).
__global__ __launch_bounds__(256) void k_gemm_gT(
    const unsigned short* __restrict__ Ahi, const unsigned short* __restrict__ Alo,
    const unsigned short* __restrict__ Whi, const unsigned short* __restrict__ Wlo,
    const float* __restrict__ bp, float* __restrict__ G,
    int M)
{
    __shared__ unsigned short As_hi[64][136];
    __shared__ unsigned short As_lo[64][136];

    const int tid  = threadIdx.x;
    const int lane = tid & 63, wave = tid >> 6;
    const int l15 = lane & 15, quad = lane >> 4;
    const int rowBase = blockIdx.x * 64;

    {
        int r0 = tid >> 4;            // 0..15
        int ko = (tid & 15) * 8;      // 0..120
        #pragma unroll
        for (int i = 0; i < 4; ++i) {
            int row = r0 + i * 16;
            int g = rowBase + row;
            uint4 vh = make_uint4(0, 0, 0, 0), vl = make_uint4(0, 0, 0, 0);
            if (g < M) {
                vh = *(const uint4*)&Ahi[(size_t)g * 128 + ko];
                vl = *(const uint4*)&Alo[(size_t)g * 128 + ko];
            }
            *(uint4*)&As_hi[row][ko] = vh;
            *(uint4*)&As_lo[row][ko] = vl;
        }
    }
    __syncthreads();

    const int pb = wave * 128;   // wave's 128 gate-cols

    #pragma unroll
    for (int tp = 0; tp < 4; ++tp) {
        const int p0 = pb + tp * 32;

        // W frags for 2 p-tiles (A-operand: lane l15 -> p row within tile)
        s16x8 wh[2][4], wl[2][4];   // [tile][kq]
        #pragma unroll
        for (int t = 0; t < 2; ++t)
            #pragma unroll
            for (int kq = 0; kq < 4; ++kq) {
                const size_t wrow = (size_t)(p0 + t * 16 + l15) * 128 + kq * 32 + quad * 8;
                wh[t][kq] = *(const s16x8*)&Whi[wrow];
                wl[t][kq] = *(const s16x8*)&Wlo[wrow];
            }
        float4 bv[2];
        #pragma unroll
        for (int t = 0; t < 2; ++t)
            bv[t] = *(const float4*)&bp[p0 + t * 16 + quad * 4];

        #pragma unroll
        for (int rg = 0; rg < 4; ++rg) {
            // x frags (B-operand: lane l15 -> x row within rowgroup)
            s16x8 xh[4], xl[4];
            #pragma unroll
            for (int kq = 0; kq < 4; ++kq) {
                xh[kq] = *(const s16x8*)&As_hi[rg * 16 + l15][kq * 32 + quad * 8];
                xl[kq] = *(const s16x8*)&As_lo[rg * 16 + l15][kq * 32 + quad * 8];
            }
            f32x4 acc[2] = {};
            #pragma unroll
            for (int kq = 0; kq < 4; ++kq)
                #pragma unroll
                for (int t = 0; t < 2; ++t) {
                    acc[t] = __builtin_amdgcn_mfma_f32_16x16x32_bf16(wh[t][kq], xh[kq], acc[t], 0, 0, 0);
                    acc[t] = __builtin_amdgcn_mfma_f32_16x16x32_bf16(wh[t][kq], xl[kq], acc[t], 0, 0, 0);
                    acc[t] = __builtin_amdgcn_mfma_f32_16x16x32_bf16(wl[t][kq], xh[kq], acc[t], 0, 0, 0);
                }
            const int row = rowBase + rg * 16 + l15;
            if (row < M) {
                const size_t prow = (size_t)grow_perm(row);
                #pragma unroll
                for (int t = 0; t < 2; ++t) {
                    float4 o;
                    o.x = acc[t][0] + bv[t].x;
                    o.y = acc[t][1] + bv[t].y;
                    o.z = acc[t][2] + bv[t].z;
                    o.w = acc[t][3] + bv[t].w;
                    *(float4*)&G[prow * 512 + p0 + t * 16 + quad * 4] = o;
                }
            }
        }
    }
}

// 2-term variant (A plain bf16): layer-1 gate GEMM. LDS 17.4 KB.
__global__ __launch_bounds__(256) void k_gemm_gT_h(
    const unsigned short* __restrict__ Ahi,
    const unsigned short* __restrict__ Whi, const unsigned short* __restrict__ Wlo,
    const float* __restrict__ bp, float* __restrict__ G,
    int M)
{
    __shared__ unsigned short As_hi[64][136];

    const int tid  = threadIdx.x;
    const int lane = tid & 63, wave = tid >> 6;
    const int l15 = lane & 15, quad = lane >> 4;
    const int rowBase = blockIdx.x * 64;

    {
        int r0 = tid >> 4;
        int ko = (tid & 15) * 8;
        #pragma unroll
        for (int i = 0; i < 4; ++i) {
            int row = r0 + i * 16;
            int g = rowBase + row;
            uint4 vh = make_uint4(0, 0, 0, 0);
            if (g < M) vh = *(const uint4*)&Ahi[(size_t)g * 128 + ko];
            *(uint4*)&As_hi[row][ko] = vh;
        }
    }
    __syncthreads();

    const int pb = wave * 128;

    #pragma unroll
    for (int tp = 0; tp < 4; ++tp) {
        const int p0 = pb + tp * 32;

        s16x8 wh[2][4], wl[2][4];
        #pragma unroll
        for (int t = 0; t < 2; ++t)
            #pragma unroll
            for (int kq = 0; kq < 4; ++kq) {
                const size_t wrow = (size_t)(p0 + t * 16 + l15) * 128 + kq * 32 + quad * 8;
                wh[t][kq] = *(const s16x8*)&Whi[wrow];
                wl[t][kq] = *(const s16x8*)&Wlo[wrow];
            }
        float4 bv[2];
        #pragma unroll
        for (int t = 0; t < 2; ++t)
            bv[t] = *(const float4*)&bp[p0 + t * 16 + quad * 4];

        #pragma unroll
        for (int rg = 0; rg < 4; ++rg) {
            s16x8 xh[4];
            #pragma unroll
            for (int kq = 0; kq < 4; ++kq)
                xh[kq] = *(const s16x8*)&As_hi[rg * 16 + l15][kq * 32 + quad * 8];
            f32x4 acc[2] = {};
            #pragma unroll
            for (int kq = 0; kq < 4; ++kq)
                #pragma unroll
                for (int t = 0; t < 2; ++t) {
                    acc[t] = __builtin_amdgcn_mfma_f32_16x16x32_bf16(wh[t][kq], xh[kq], acc[t], 0, 0, 0);
                    acc[t] = __builtin_amdgcn_mfma_f32_16x16x32_bf16(wl[t][kq], xh[kq], acc[t], 0, 0, 0);
                }
            const int row = rowBase + rg * 16 + l15;
            if (row < M) {
                const size_t prow = (size_t)grow_perm(row);
                #pragma unroll
                for (int t = 0; t < 2; ++t) {
                    float4 o;
                    o.x = acc[t][0] + bv[t].x;
                    o.y = acc[t][1] + bv[t].y;
                    o.z = acc[t][2] + bv[t].z;
                    o.w = acc[t][3] + bv[t].w;
                    *(float4*)&G[prow * 512 + p0 + t * 16 + quad * 4] = o;
                }
            }
        }
    }
}

// ---------------------------------------------------------------- GCN gather
// Edge loop unrolled x4 (4 h-rows in flight); accumulation order preserved.
__global__ __launch_bounds__(256) void k_gather(
    const int* __restrict__ rowstart, const int* __restrict__ adj,
    const float* __restrict__ h, const float* __restrict__ dinv,
    const float* __restrict__ bias,
    unsigned short* __restrict__ hi, unsigned short* __restrict__ lo)
{
    const int n    = blockIdx.x * 4 + (threadIdx.x >> 6);   // grid exactly NND/4
    const int lane = threadIdx.x & 63;
    const int r0 = rowstart[n], r1 = rowstart[n + 1];
    const float dn = dinv[n];

    float2 hv = *(const float2*)&h[(size_t)n * 128 + 2 * lane];
    float2 acc;
    acc.x = hv.x * dn;
    acc.y = hv.y * dn;

    int i = r0;
    for (; i + 4 <= r1; i += 4) {
        int s0 = adj[i], s1 = adj[i + 1], s2 = adj[i + 2], s3 = adj[i + 3];
        float d0 = dinv[s0], d1 = dinv[s1], d2 = dinv[s2], d3 = dinv[s3];
        float2 v0 = *(const float2*)&h[(size_t)s0 * 128 + 2 * lane];
        float2 v1 = *(const float2*)&h[(size_t)s1 * 128 + 2 * lane];
        float2 v2 = *(const float2*)&h[(size_t)s2 * 128 + 2 * lane];
        float2 v3 = *(const float2*)&h[(size_t)s3 * 128 + 2 * lane];
        acc.x += v0.x * d0; acc.y += v0.y * d0;
        acc.x += v1.x * d1; acc.y += v1.y * d1;
        acc.x += v2.x * d2; acc.y += v2.y * d2;
        acc.x += v3.x * d3; acc.y += v3.y * d3;
    }
    for (; i < r1; ++i) {
        int s = adj[i];
        float ds = dinv[s];
        float2 v = *(const float2*)&h[(size_t)s * 128 + 2 * lane];
        acc.x += v.x * ds;
        acc.y += v.y * ds;
    }

    float2 bb = *(const float2*)&bias[2 * lane];
    float vx = fmaxf(acc.x * dn + bb.x, 0.f);
    float vy = fmaxf(acc.y * dn + bb.y, 0.f);
    ushort2 ho, lo2;
    ho.x = f2bf(vx); lo2.x = f2bf(vx - bf2f(ho.x));
    ho.y = f2bf(vy); lo2.y = f2bf(vy - bf2f(ho.y));
    *(ushort2*)&hi[(size_t)n * 128 + 2 * lane] = ho;
    *(ushort2*)&lo[(size_t)n * 128 + 2 * lane] = lo2;
}

// ---------------------------------------------------------------- prep kernels
__global__ void k_prep_gcnw2(const float* __restrict__ W1, const float* __restrict__ W2,
                             unsigned short* __restrict__ hi1, unsigned short* __restrict__ lo1,
                             unsigned short* __restrict__ hi2, unsigned short* __restrict__ lo2) {
    int t = blockIdx.x * 256 + threadIdx.x;   // grid 128 -> 32768 threads
    const float* W = (t < 16384) ? W1 : W2;
    unsigned short* hi = (t < 16384) ? hi1 : hi2;
    unsigned short* lo = (t < 16384) ? lo1 : lo2;
    int tt = t & 16383;
    int k = tt >> 7, n = tt & 127;
    float v = W[tt];
    unsigned short h = f2bf(v);
    hi[n * 128 + k] = h;
    lo[n * 128 + k] = f2bf(v - bf2f(h));
}

// LSTM prep: w_ih and w_hh [512(r=g*128+j)][128(k)] -> packed-transposed
// split-bf16 wT[p=j*4+g][k]; bias -> bp[p] = b_ih + b_hh.
__global__ void k_prep_lstm(const float* __restrict__ w_ih, const float* __restrict__ w_hh,
                            const float* __restrict__ b_ih, const float* __restrict__ b_hh,
                            unsigned short* __restrict__ ih_hi, unsigned short* __restrict__ ih_lo,
                            unsigned short* __restrict__ hh_hi, unsigned short* __restrict__ hh_lo,
                            float* __restrict__ bp)
{
    int t = blockIdx.x * 256 + threadIdx.x;
    if (t < 65536) {
        int r = t >> 7, k = t & 127;
        int g = r >> 7, j = r & 127;
        int p = (j << 2) + g;
        float v = w_ih[t];
        unsigned short h = f2bf(v);
        ih_hi[p * 128 + k] = h;
        ih_lo[p * 128 + k] = f2bf(v - bf2f(h));
    } else if (t < 131072) {
        int t2 = t - 65536;
        int r = t2 >> 7, k = t2 & 127;
        int g = r >> 7, j = r & 127;
        int p = (j << 2) + g;
        float v = w_hh[t2];
        unsigned short h = f2bf(v);
        hh_hi[p * 128 + k] = h;
        hh_lo[p * 128 + k] = f2bf(v - bf2f(h));
    } else if (t < 131584) {
        int r = t - 131072;   // 0..511
        int g = r >> 7, j = r & 127;
        bp[(j << 2) + g] = b_ih[r] + b_hh[r];
    }
}

// ---------------------------------------------------------------- LSTM recurrence
// v13: 1-TERM recurrence weights. R10 showed the MFMA issue floor (1241 cyc of
// 3163/step) is the largest single remaining item. P = bf16(h) @ bf16(Whh):
// drops the weight-lo term from the RECURRENCE only (gate GEMMs keep split
// precision). Error model: W~N(0,1/128), bf16 rounding -> pre-activation
// err ~3e-4 -> h err ~1e-4/step -> ~7e-4 random walk over 50 steps, on top of
// the existing 4.88e-4. EXPLICIT NUMERICS EXPERIMENT: revert if absmax fails.
// Halves recurrence MFMA issue (16/step/wave) and weight registers.
__global__ __launch_bounds__(512, 2) void k_lstm(
    const float* __restrict__ G,            // permuted: [blk][step][4 seq][512]
    const unsigned short* __restrict__ Whi, // 512 x 128, packed-transposed hi
    unsigned short* __restrict__ Hhi,       // (NB*TSEQ) x 128 bf16-hi, or nullptr
    const float* __restrict__ fcw,          // fused FC weight (layer 1) or nullptr
    const float* __restrict__ fcb,
    float* __restrict__ outp)               // NB x 1 output (layer 1) or nullptr
{
    const int tid  = threadIdx.x;
    const int lane = tid & 63, wave = tid >> 6;   // 8 waves
    const int l15  = lane & 15, quad = lane >> 4;
    const int b0   = blockIdx.x * SB;

    __shared__ __align__(16) unsigned short Ah[16 * AHS];  // h bf16 (rows SB..15 zero)
    __shared__ float partw[8][4][72];        // per-wave P patch [wave][b][col in wave]

    // weight fragments: wave owns n-tiles nt0..nt0+3 (n = p = j*4+gate)
    const int nt0 = wave * 4;
    s16x8 bh[4][4];   // [nt][ks]
    #pragma unroll
    for (int nt = 0; nt < 4; ++nt) {
        int p = (nt0 + nt) * 16 + l15;
        #pragma unroll
        for (int ks = 0; ks < 4; ++ks)
            bh[nt][ks] = *(const s16x8*)&Whi[(size_t)p * 128 + ks * 32 + quad * 8];
    }

    for (int i = tid; i < 16 * AHS; i += 512) Ah[i] = 0;

    // phase-2 mapping: lane l of wave w -> (b2, j) with j owned by wave w
    const int b2 = lane >> 4;              // 0..3
    const int jj = wave * 16 + l15;        // hidden unit this lane updates
    const int bg = b0 + b2;                // sequence index (NB % SB == 0)
    float c = 0.f;
    float hn_last = 0.f;

    // permuted-G base: row' = blk*200 + step*4 + b2; step stride = 2048 floats
    const float* gb = &G[((size_t)blockIdx.x * 200 + b2) * 512 + (jj << 2)];
    float4 gv_cur = *(const float4*)&gb[0];

    __syncthreads();

    for (int step = 0; step < TSEQ; ++step) {
        // prefetch NEXT step's gate input (full step of latency cover)
        const int nstep = (step + 1 < TSEQ) ? step + 1 : step;
        const float4 gv_nxt = *(const float4*)&gb[(size_t)nstep * 2048];

        // phase 1: MFMA  P = bf16(h) @ bf16(Whh)  (1-term)
        f32x4 acc[4] = {};
        #pragma unroll
        for (int ks = 0; ks < 4; ++ks) {
            s16x8 ah = *(const s16x8*)&Ah[l15 * AHS + ks * 32 + quad * 8];
            #pragma unroll
            for (int nt = 0; nt < 4; ++nt)
                acc[nt] = __builtin_amdgcn_mfma_f32_16x16x32_bf16(ah, bh[nt][ks], acc[nt], 0, 0, 0);
        }

        // intra-wave exchange: quad-0 lanes hold rows 0..3 (the real seqs)
        if (quad == 0) {
            #pragma unroll
            for (int nt = 0; nt < 4; ++nt)
                #pragma unroll
                for (int r = 0; r < 4; ++r)
                    partw[wave][r][nt * 16 + l15] = acc[nt][r];
        }
        // same-wave producer/consumer: compiler inserts lgkmcnt wait, no barrier

        // phase 2: LSTM cell for (b2, jj); reads this wave's own patch
        {
            float4 pa = *(const float4*)&partw[wave][b2][l15 * 4];
            float xi = pa.x + gv_cur.x;
            float xf = pa.y + gv_cur.y;
            float xg = pa.z + gv_cur.z;
            float xo = pa.w + gv_cur.w;
            float ii = sigf(xi), ff = sigf(xf), gg = tanhfast(xg), oo = sigf(xo);
            float cn = ff * c + ii * gg;
            c = cn;
            float hn = oo * tanhfast(cn);
            hn_last = hn;
            unsigned short hh = f2bf(hn);
            Ah[b2 * AHS + jj] = hh;
            if (Hhi)
                Hhi[((size_t)bg * TSEQ + step) * 128 + jj] = hh;
        }
        gv_cur = gv_nxt;
        // single barrier: Ah writes must be visible to all waves' phase-1
        __syncthreads();
    }

    // fused FC head (layer 1): out[bg] = dot(h_last[bg], fcw) + fcb
    if (outp) {
        float* red = (float*)Ah;   // 2 KiB scratch, Ah is dead now
        red[b2 * 128 + jj] = hn_last * fcw[jj];
        __syncthreads();
        if (wave < 4) {            // wave w reduces sequence b0+w
            float v = red[wave * 128 + lane] + red[wave * 128 + lane + 64];
            #pragma unroll
            for (int off = 32; off > 0; off >>= 1)
                v += __shfl_down(v, off);
            if (lane == 0) outp[b0 + wave] = v + fcb[0];
        }
    }
}

// ---------------------------------------------------------------- launch
extern "C" void kernel_launch(void* const* d_in, const int* in_sizes, int n_in,
                              void* d_out, int out_size, void* d_ws, size_t ws_size,
                              hipStream_t stream)
{
    const float* x    = (const float*)d_in[0];
    const int*   ei   = (const int*)d_in[1];
    const float* W1   = (const float*)d_in[3];
    const float* b1   = (const float*)d_in[4];
    const float* W2   = (const float*)d_in[5];
    const float* b2   = (const float*)d_in[6];
    const float* fcw  = (const float*)d_in[7];
    const float* fcb  = (const float*)d_in[8];
    const float* wih0 = (const float*)d_in[9];
    const float* whh0 = (const float*)d_in[10];
    const float* bih0 = (const float*)d_in[11];
    const float* bhh0 = (const float*)d_in[12];
    const float* wih1 = (const float*)d_in[13];
    const float* whh1 = (const float*)d_in[14];
    const float* bih1 = (const float*)d_in[15];
    const float* bhh1 = (const float*)d_in[16];
    float* out = (float*)d_out;

    char* ws = (char*)d_ws;
    // ---- persistent regions
    unsigned short* shi = (unsigned short*)(ws + 0);          // 12.8 MB
    unsigned short* slo = (unsigned short*)(ws + 12800000);   // 12.8 MB (ends 25.6M)
    float* bufG = (float*)(ws + 51200000);                    // 102.4 MB (ends 153.6M)

    // ---- GCN-phase regions (inside bufG, dead before gate GEMM writes bufG)
    unsigned short* xhi = (unsigned short*)(ws + 51200000);   // 12.8 MB
    unsigned short* xlo = (unsigned short*)(ws + 64000000);   // 12.8 MB
    float* bufHg  = (float*)(ws + 76800000);                  // 25.6 MB (ends 102.4M)
    int* cnt      = (int*)(ws + 102400000);                   // 200000 B (pad 204800)
    int* cursor   = (int*)(ws + 102604800);                   // contiguous with cnt
    int* rowstart = (int*)(ws + 102809600);
    int* adj      = (int*)(ws + 103014400);                   // 2.4 MB (ends 105.42M)
    int* bsum     = (int*)(ws + 105420800);                   // NSCB ints

    float* dinv = (float*)(ws + 153600000);
    float* bp0  = (float*)(ws + 153800192);
    float* bp1  = (float*)(ws + 153802240);
    unsigned short* w1t_hi   = (unsigned short*)(ws + 153804288);
    unsigned short* w1t_lo   = (unsigned short*)(ws + 153837056);
    unsigned short* w2t_hi   = (unsigned short*)(ws + 153869824);
    unsigned short* w2t_lo   = (unsigned short*)(ws + 153902592);
    unsigned short* wpih0_hi = (unsigned short*)(ws + 153935360);
    unsigned short* wpih0_lo = (unsigned short*)(ws + 154066432);
    unsigned short* wpih1_hi = (unsigned short*)(ws + 154197504);
    unsigned short* wpih1_lo = (unsigned short*)(ws + 154328576);
    unsigned short* wphh0_hi = (unsigned short*)(ws + 154459648);
    unsigned short* wphh0_lo = (unsigned short*)(ws + 154590720);
    unsigned short* wphh1_hi = (unsigned short*)(ws + 154721792);
    unsigned short* wphh1_lo = (unsigned short*)(ws + 154852864);

    // ---- CSR build + dinv (multi-block scan); cnt+cursor zeroed in ONE memset
    hipMemsetAsync(cnt, 0, 409600, stream);
    k_count<<<(NE + 255) / 256, 256, 0, stream>>>(ei, cnt);
    k_bsum<<<NSCB, 256, 0, stream>>>(cnt, bsum);
    k_bscan<<<1, 256, 0, stream>>>(bsum);
    k_bout<<<NSCB, 256, 0, stream>>>(cnt, bsum, rowstart, dinv);
    k_fill<<<(NE + 255) / 256, 256, 0, stream>>>(ei, rowstart, cursor, adj);

    // ---- weight prep
    k_prep_gcnw2<<<128, 256, 0, stream>>>(W1, W2, w1t_hi, w1t_lo, w2t_hi, w2t_lo);
    k_prep_lstm<<<514, 256, 0, stream>>>(wih0, whh0, bih0, bhh0,
                                         wpih0_hi, wpih0_lo, wphh0_hi, wphh0_lo, bp0);
    k_prep_lstm<<<514, 256, 0, stream>>>(wih1, whh1, bih1, bhh1,
                                         wpih1_hi, wpih1_lo, wphh1_hi, wphh1_lo, bp1);

    dim3 gH(1, 391);     // GCN GEMMs: 128-row panel, NT=2 (128 cols)

    // ---- GCN layer 1 (fp32 A, convert-on-stage)
    k_gemm_mfma_xa<<<gH, 256, 0, stream>>>(x, w1t_hi, w1t_lo, nullptr, bufHg, NND, 128, 2);
    k_gather<<<NND / 4, 256, 0, stream>>>(rowstart, adj, bufHg, dinv, b1, xhi, xlo);

    // ---- GCN layer 2
    k_gemm_mfma<<<gH, 256, 0, stream>>>(xhi, xlo, w2t_hi, w2t_lo, nullptr, bufHg, NND, 128, 2);
    k_gather<<<NND / 4, 256, 0, stream>>>(rowstart, adj, bufHg, dinv, b2, shi, slo);

    // ---- LSTM layer 0: swapped-operand gate GEMM (3-term, permuted G) + recurrence
    k_gemm_gT<<<782, 256, 0, stream>>>(shi, slo, wpih0_hi, wpih0_lo, bp0, bufG, NND);
    k_lstm<<<NB / SB, 512, 0, stream>>>(bufG, wphh0_hi, shi,
                                        nullptr, nullptr, nullptr);

    // ---- LSTM layer 1: 2-term swapped gate GEMM (permuted G) + recurrence + FC
    k_gemm_gT_h<<<782, 256, 0, stream>>>(shi, wpih1_hi, wpih1_lo, bp1, bufG, NND);
    k_lstm<<<NB / SB, 512, 0, stream>>>(bufG, wphh1_hi, nullptr,
                                        fcw, fcb, out);
}

// Round 12
// 484.699 us; speedup vs baseline: 1.0969x; 1.0023x over previous
//
#include <hip/hip_runtime.h>

// Problem constants (fixed by the reference file)
#define NND 50000   // nodes
#define NE  600000  // edges
#define TSEQ 50     // sequence length
#define NB  1000    // batch = NND/TSEQ
#define SB  4       // sequences per LSTM workgroup
#define AHS 136     // LDS h-row stride in shorts (128 + 8 pad, 16B-aligned)
#define NSCB 196    // scan blocks: ceil(NND/256)

typedef __attribute__((ext_vector_type(4))) float f32x4;
typedef __attribute__((ext_vector_type(8))) short s16x8;

// ---------------------------------------------------------------- helpers
__device__ __forceinline__ float sigf(float x) {
    return 1.0f / (1.0f + __expf(-x));
}
__device__ __forceinline__ float tanhfast(float x) {
    x = fminf(fmaxf(x, -15.f), 15.f);
    float e = __expf(2.f * x);
    return (e - 1.f) / (e + 1.f);
}
// bf16 bit helpers (round-to-nearest-even)
__device__ __forceinline__ unsigned short f2bf(float f) {
    unsigned int u = __float_as_uint(f);
    u = u + 0x7FFFu + ((u >> 16) & 1u);
    return (unsigned short)(u >> 16);
}
__device__ __forceinline__ float bf2f(unsigned short h) {
    return __uint_as_float(((unsigned int)h) << 16);
}
// G row permutation: node n -> block-local row (blk*200 + step*4 + seq_in_blk).
// Pure bijection on [0, NND): LSTM block b reads contiguous 4KB per step.
__device__ __forceinline__ int grow_perm(int n) {
    int grp = n / 200;
    int rem = n % 200;
    return grp * 200 + (n % 50) * 4 + rem / 50;
}

// ---------------------------------------------------------------- CSR build
__global__ void k_count(const int* __restrict__ ei, int* __restrict__ cnt) {
    int e = blockIdx.x * 256 + threadIdx.x;
    if (e < NE) atomicAdd(&cnt[ei[NE + e]], 1);
}

// ---- 3-stage multi-block exclusive scan of cnt -> rowstart (+ fused dinv)
__global__ __launch_bounds__(256) void k_bsum(const int* __restrict__ cnt,
                                              int* __restrict__ bsum) {
    __shared__ int red[256];
    int t = threadIdx.x;
    int idx = blockIdx.x * 256 + t;
    red[t] = (idx < NND) ? cnt[idx] : 0;
    __syncthreads();
    for (int off = 128; off > 0; off >>= 1) {
        if (t < off) red[t] += red[t + off];
        __syncthreads();
    }
    if (t == 0) bsum[blockIdx.x] = red[0];
}

__global__ __launch_bounds__(256) void k_bscan(int* __restrict__ bsum) {
    __shared__ int ps[256];
    int t = threadIdx.x;
    int v = (t < NSCB) ? bsum[t] : 0;
    ps[t] = v;
    __syncthreads();
    for (int off = 1; off < 256; off <<= 1) {
        int u = 0;
        if (t >= off) u = ps[t - off];
        __syncthreads();
        if (t >= off) ps[t] += u;
        __syncthreads();
    }
    if (t < NSCB) bsum[t] = ps[t] - v;   // exclusive
}

__global__ __launch_bounds__(256) void k_bout(const int* __restrict__ cnt,
                                              const int* __restrict__ bsum,
                                              int* __restrict__ rowstart,
                                              float* __restrict__ dinv) {
    __shared__ int ps[256];
    int t = threadIdx.x;
    int idx = blockIdx.x * 256 + t;
    int v = (idx < NND) ? cnt[idx] : 0;
    ps[t] = v;
    __syncthreads();
    for (int off = 1; off < 256; off <<= 1) {
        int u = 0;
        if (t >= off) u = ps[t - off];
        __syncthreads();
        if (t >= off) ps[t] += u;
        __syncthreads();
    }
    int boff = bsum[blockIdx.x];
    if (idx < NND) {
        rowstart[idx] = boff + ps[t] - v;   // exclusive
        dinv[idx] = 1.0f / sqrtf((float)v + 1.0f);   // fused (was k_dinv)
    }
    if (idx == NND - 1) rowstart[NND] = boff + ps[t];  // == NE
}

__global__ void k_fill(const int* __restrict__ ei, const int* __restrict__ rowstart,
                       int* __restrict__ cursor, int* __restrict__ adj) {
    int e = blockIdx.x * 256 + threadIdx.x;
    if (e >= NE) return;
    int s = ei[e], d = ei[NE + e];
    int pos = atomicAdd(&cursor[d], 1);
    adj[rowstart[d] + pos] = s;
}

// ---------------------------------------------------------------- MFMA GEMM
// GCN layers (Nc=128): 128x128 A panel staged once, NT col-tiles per block.
__global__ __launch_bounds__(256) void k_gemm_mfma(
    const unsigned short* __restrict__ Ahi, const unsigned short* __restrict__ Alo,
    const unsigned short* __restrict__ Bhi, const unsigned short* __restrict__ Blo,
    const float* __restrict__ bias, float* __restrict__ C,
    int M, int Nc, int NT)
{
    __shared__ unsigned short As_hi[128][136];
    __shared__ unsigned short As_lo[128][136];

    const int tid  = threadIdx.x;
    const int lane = tid & 63, wave = tid >> 6;
    const int mw = wave & 1, nw = wave >> 1;
    const int l15 = lane & 15, quad = lane >> 4;
    const int rowBase = blockIdx.y * 128;

    {
        int r0 = tid >> 4;            // 0..15
        int ko = (tid & 15) * 8;      // 0..120
        #pragma unroll
        for (int i = 0; i < 8; ++i) {
            int row = r0 + i * 16;
            int g = rowBase + row;
            uint4 vh = make_uint4(0, 0, 0, 0), vl = make_uint4(0, 0, 0, 0);
            if (g < M) {
                vh = *(const uint4*)&Ahi[(size_t)g * 128 + ko];
                vl = *(const uint4*)&Alo[(size_t)g * 128 + ko];
            }
            *(uint4*)&As_hi[row][ko] = vh;
            *(uint4*)&As_lo[row][ko] = vl;
        }
    }
    __syncthreads();

    for (int nt = 0; nt < NT; ++nt) {
        const int colBase = (blockIdx.x * NT + nt) * 64;

        s16x8 bh[2][4], bl[2][4];   // [ns][kq]
        #pragma unroll
        for (int ns = 0; ns < 2; ++ns) {
            int gn = colBase + nw * 32 + ns * 16 + l15;
            #pragma unroll
            for (int kq = 0; kq < 4; ++kq) {
                bh[ns][kq] = *(const s16x8*)&Bhi[(size_t)gn * 128 + kq * 32 + quad * 8];
                bl[ns][kq] = *(const s16x8*)&Blo[(size_t)gn * 128 + kq * 32 + quad * 8];
            }
        }

        f32x4 acc[4][2] = {};
        #pragma unroll
        for (int kq = 0; kq < 4; ++kq) {
            int kof = kq * 32 + quad * 8;
            s16x8 ah[4], al[4];
            #pragma unroll
            for (int ms = 0; ms < 4; ++ms) {
                int r = mw * 64 + ms * 16 + l15;
                ah[ms] = *(const s16x8*)&As_hi[r][kof];
                al[ms] = *(const s16x8*)&As_lo[r][kof];
            }
            #pragma unroll
            for (int ms = 0; ms < 4; ++ms)
                #pragma unroll
                for (int ns = 0; ns < 2; ++ns)
                    acc[ms][ns] = __builtin_amdgcn_mfma_f32_16x16x32_bf16(ah[ms], bh[ns][kq], acc[ms][ns], 0, 0, 0);
            #pragma unroll
            for (int ms = 0; ms < 4; ++ms)
                #pragma unroll
                for (int ns = 0; ns < 2; ++ns)
                    acc[ms][ns] = __builtin_amdgcn_mfma_f32_16x16x32_bf16(al[ms], bh[ns][kq], acc[ms][ns], 0, 0, 0);
            #pragma unroll
            for (int ms = 0; ms < 4; ++ms)
                #pragma unroll
                for (int ns = 0; ns < 2; ++ns)
                    acc[ms][ns] = __builtin_amdgcn_mfma_f32_16x16x32_bf16(ah[ms], bl[ns][kq], acc[ms][ns], 0, 0, 0);
        }

        #pragma unroll
        for (int ns = 0; ns < 2; ++ns) {
            int col = colBase + nw * 32 + ns * 16 + l15;
            float bv = bias ? bias[col] : 0.f;
            #pragma unroll
            for (int ms = 0; ms < 4; ++ms) {
                int row0 = rowBase + mw * 64 + ms * 16 + quad * 4;
                #pragma unroll
                for (int r = 0; r < 4; ++r) {
                    int row = row0 + r;
                    if (row < M) C[(size_t)row * Nc + col] = acc[ms][ns][r] + bv;
                }
            }
        }
    }
}

// Variant: A is raw fp32 (input x); split-bf16 conversion fused into staging.
__global__ __launch_bounds__(256) void k_gemm_mfma_xa(
    const float* __restrict__ X,
    const unsigned short* __restrict__ Bhi, const unsigned short* __restrict__ Blo,
    const float* __restrict__ bias, float* __restrict__ C,
    int M, int Nc, int NT)
{
    __shared__ unsigned short As_hi[128][136];
    __shared__ unsigned short As_lo[128][136];

    const int tid  = threadIdx.x;
    const int lane = tid & 63, wave = tid >> 6;
    const int mw = wave & 1, nw = wave >> 1;
    const int l15 = lane & 15, quad = lane >> 4;
    const int rowBase = blockIdx.y * 128;

    {
        int r0 = tid >> 4;
        int ko = (tid & 15) * 8;
        #pragma unroll
        for (int i = 0; i < 8; ++i) {
            int row = r0 + i * 16;
            int g = rowBase + row;
            unsigned short hx[8], lx[8];
            if (g < M) {
                float4 v0 = *(const float4*)&X[(size_t)g * 128 + ko];
                float4 v1 = *(const float4*)&X[(size_t)g * 128 + ko + 4];
                const float vv[8] = {v0.x, v0.y, v0.z, v0.w, v1.x, v1.y, v1.z, v1.w};
                #pragma unroll
                for (int e = 0; e < 8; ++e) {
                    hx[e] = f2bf(vv[e]);
                    lx[e] = f2bf(vv[e] - bf2f(hx[e]));
                }
            } else {
                #pragma unroll
                for (int e = 0; e < 8; ++e) { hx[e] = 0; lx[e] = 0; }
            }
            *(uint4*)&As_hi[row][ko] = *(const uint4*)hx;
            *(uint4*)&As_lo[row][ko] = *(const uint4*)lx;
        }
    }
    __syncthreads();

    for (int nt = 0; nt < NT; ++nt) {
        const int colBase = (blockIdx.x * NT + nt) * 64;

        s16x8 bh[2][4], bl[2][4];
        #pragma unroll
        for (int ns = 0; ns < 2; ++ns) {
            int gn = colBase + nw * 32 + ns * 16 + l15;
            #pragma unroll
            for (int kq = 0; kq < 4; ++kq) {
                bh[ns][kq] = *(const s16x8*)&Bhi[(size_t)gn * 128 + kq * 32 + quad * 8];
                bl[ns][kq] = *(const s16x8*)&Blo[(size_t)gn * 128 + kq * 32 + quad * 8];
            }
        }

        f32x4 acc[4][2] = {};
        #pragma unroll
        for (int kq = 0; kq < 4; ++kq) {
            int kof = kq * 32 + quad * 8;
            s16x8 ah[4], al[4];
            #pragma unroll
            for (int ms = 0; ms < 4; ++ms) {
                int r = mw * 64 + ms * 16 + l15;
                ah[ms] = *(const s16x8*)&As_hi[r][kof];
                al[ms] = *(const s16x8*)&As_lo[r][kof];
            }
            #pragma unroll
            for (int ms = 0; ms < 4; ++ms)
                #pragma unroll
                for (int ns = 0; ns < 2; ++ns)
                    acc[ms][ns] = __builtin_amdgcn_mfma_f32_16x16x32_bf16(ah[ms], bh[ns][kq], acc[ms][ns], 0, 0, 0);
            #pragma unroll
            for (int ms = 0; ms < 4; ++ms)
                #pragma unroll
                for (int ns = 0; ns < 2; ++ns)
                    acc[ms][ns] = __builtin_amdgcn_mfma_f32_16x16x32_bf16(al[ms], bh[ns][kq], acc[ms][ns], 0, 0, 0);
            #pragma unroll
            for (int ms = 0; ms < 4; ++ms)
                #pragma unroll
                for (int ns = 0; ns < 2; ++ns)
                    acc[ms][ns] = __builtin_amdgcn_mfma_f32_16x16x32_bf16(ah[ms], bl[ns][kq], acc[ms][ns], 0, 0, 0);
        }

        #pragma unroll
        for (int ns = 0; ns < 2; ++ns) {
            int col = colBase + nw * 32 + ns * 16 + l15;
            float bv = bias ? bias[col] : 0.f;
            #pragma unroll
            for (int ms = 0; ms < 4; ++ms) {
                int row0 = rowBase + mw * 64 + ms * 16 + quad * 4;
                #pragma unroll
                for (int r = 0; r < 4; ++r) {
                    int row = row0 + r;
                    if (row < M) C[(size_t)row * Nc + col] = acc[ms][ns][r] + bv;
                }
            }
        }
    }
}

// ---------------------------------------------------------------- gate GEMM v8
// SWAPPED-OPERAND (R7) + PERMUTED G rows (R10) + BF16 G OUTPUT (this round).
// R11 counters: WRITE 100MB / 50us = 2.0 TB/s = the kernel duration exactly ->
// write-drain bound. Storing G as bf16 halves the G bytes for the GEMMs AND
// k_lstm's re-read. NUMERICS EXPERIMENT: gate pre-activation bf16 rounding
// ~4e-3 rel -> ~1e-3/step on h; expected absmax ~1-3e-3 (revert if fail).
__global__ __launch_bounds__(256) void k_gemm_gT(
    const unsigned short* __restrict__ Ahi, const unsigned short* __restrict__ Alo,
    const unsigned short* __restrict__ Whi, const unsigned short* __restrict__ Wlo,
    const float* __restrict__ bp, unsigned short* __restrict__ G,
    int M)
{
    __shared__ unsigned short As_hi[64][136];
    __shared__ unsigned short As_lo[64][136];

    const int tid  = threadIdx.x;
    const int lane = tid & 63, wave = tid >> 6;
    const int l15 = lane & 15, quad = lane >> 4;
    const int rowBase = blockIdx.x * 64;

    {
        int r0 = tid >> 4;            // 0..15
        int ko = (tid & 15) * 8;      // 0..120
        #pragma unroll
        for (int i = 0; i < 4; ++i) {
            int row = r0 + i * 16;
            int g = rowBase + row;
            uint4 vh = make_uint4(0, 0, 0, 0), vl = make_uint4(0, 0, 0, 0);
            if (g < M) {
                vh = *(const uint4*)&Ahi[(size_t)g * 128 + ko];
                vl = *(const uint4*)&Alo[(size_t)g * 128 + ko];
            }
            *(uint4*)&As_hi[row][ko] = vh;
            *(uint4*)&As_lo[row][ko] = vl;
        }
    }
    __syncthreads();

    const int pb = wave * 128;   // wave's 128 gate-cols

    #pragma unroll
    for (int tp = 0; tp < 4; ++tp) {
        const int p0 = pb + tp * 32;

        // W frags for 2 p-tiles (A-operand: lane l15 -> p row within tile)
        s16x8 wh[2][4], wl[2][4];   // [tile][kq]
        #pragma unroll
        for (int t = 0; t < 2; ++t)
            #pragma unroll
            for (int kq = 0; kq < 4; ++kq) {
                const size_t wrow = (size_t)(p0 + t * 16 + l15) * 128 + kq * 32 + quad * 8;
                wh[t][kq] = *(const s16x8*)&Whi[wrow];
                wl[t][kq] = *(const s16x8*)&Wlo[wrow];
            }
        float4 bv[2];
        #pragma unroll
        for (int t = 0; t < 2; ++t)
            bv[t] = *(const float4*)&bp[p0 + t * 16 + quad * 4];

        #pragma unroll
        for (int rg = 0; rg < 4; ++rg) {
            // x frags (B-operand: lane l15 -> x row within rowgroup)
            s16x8 xh[4], xl[4];
            #pragma unroll
            for (int kq = 0; kq < 4; ++kq) {
                xh[kq] = *(const s16x8*)&As_hi[rg * 16 + l15][kq * 32 + quad * 8];
                xl[kq] = *(const s16x8*)&As_lo[rg * 16 + l15][kq * 32 + quad * 8];
            }
            f32x4 acc[2] = {};
            #pragma unroll
            for (int kq = 0; kq < 4; ++kq)
                #pragma unroll
                for (int t = 0; t < 2; ++t) {
                    acc[t] = __builtin_amdgcn_mfma_f32_16x16x32_bf16(wh[t][kq], xh[kq], acc[t], 0, 0, 0);
                    acc[t] = __builtin_amdgcn_mfma_f32_16x16x32_bf16(wh[t][kq], xl[kq], acc[t], 0, 0, 0);
                    acc[t] = __builtin_amdgcn_mfma_f32_16x16x32_bf16(wl[t][kq], xh[kq], acc[t], 0, 0, 0);
                }
            const int row = rowBase + rg * 16 + l15;
            if (row < M) {
                const size_t prow = (size_t)grow_perm(row);
                #pragma unroll
                for (int t = 0; t < 2; ++t) {
                    ushort4 o;
                    o.x = f2bf(acc[t][0] + bv[t].x);
                    o.y = f2bf(acc[t][1] + bv[t].y);
                    o.z = f2bf(acc[t][2] + bv[t].z);
                    o.w = f2bf(acc[t][3] + bv[t].w);
                    *(ushort4*)&G[prow * 512 + p0 + t * 16 + quad * 4] = o;
                }
            }
        }
    }
}

// 2-term variant (A plain bf16): layer-1 gate GEMM. LDS 17.4 KB.
__global__ __launch_bounds__(256) void k_gemm_gT_h(
    const unsigned short* __restrict__ Ahi,
    const unsigned short* __restrict__ Whi, const unsigned short* __restrict__ Wlo,
    const float* __restrict__ bp, unsigned short* __restrict__ G,
    int M)
{
    __shared__ unsigned short As_hi[64][136];

    const int tid  = threadIdx.x;
    const int lane = tid & 63, wave = tid >> 6;
    const int l15 = lane & 15, quad = lane >> 4;
    const int rowBase = blockIdx.x * 64;

    {
        int r0 = tid >> 4;
        int ko = (tid & 15) * 8;
        #pragma unroll
        for (int i = 0; i < 4; ++i) {
            int row = r0 + i * 16;
            int g = rowBase + row;
            uint4 vh = make_uint4(0, 0, 0, 0);
            if (g < M) vh = *(const uint4*)&Ahi[(size_t)g * 128 + ko];
            *(uint4*)&As_hi[row][ko] = vh;
        }
    }
    __syncthreads();

    const int pb = wave * 128;

    #pragma unroll
    for (int tp = 0; tp < 4; ++tp) {
        const int p0 = pb + tp * 32;

        s16x8 wh[2][4], wl[2][4];
        #pragma unroll
        for (int t = 0; t < 2; ++t)
            #pragma unroll
            for (int kq = 0; kq < 4; ++kq) {
                const size_t wrow = (size_t)(p0 + t * 16 + l15) * 128 + kq * 32 + quad * 8;
                wh[t][kq] = *(const s16x8*)&Whi[wrow];
                wl[t][kq] = *(const s16x8*)&Wlo[wrow];
            }
        float4 bv[2];
        #pragma unroll
        for (int t = 0; t < 2; ++t)
            bv[t] = *(const float4*)&bp[p0 + t * 16 + quad * 4];

        #pragma unroll
        for (int rg = 0; rg < 4; ++rg) {
            s16x8 xh[4];
            #pragma unroll
            for (int kq = 0; kq < 4; ++kq)
                xh[kq] = *(const s16x8*)&As_hi[rg * 16 + l15][kq * 32 + quad * 8];
            f32x4 acc[2] = {};
            #pragma unroll
            for (int kq = 0; kq < 4; ++kq)
                #pragma unroll
                for (int t = 0; t < 2; ++t) {
                    acc[t] = __builtin_amdgcn_mfma_f32_16x16x32_bf16(wh[t][kq], xh[kq], acc[t], 0, 0, 0);
                    acc[t] = __builtin_amdgcn_mfma_f32_16x16x32_bf16(wl[t][kq], xh[kq], acc[t], 0, 0, 0);
                }
            const int row = rowBase + rg * 16 + l15;
            if (row < M) {
                const size_t prow = (size_t)grow_perm(row);
                #pragma unroll
                for (int t = 0; t < 2; ++t) {
                    ushort4 o;
                    o.x = f2bf(acc[t][0] + bv[t].x);
                    o.y = f2bf(acc[t][1] + bv[t].y);
                    o.z = f2bf(acc[t][2] + bv[t].z);
                    o.w = f2bf(acc[t][3] + bv[t].w);
                    *(ushort4*)&G[prow * 512 + p0 + t * 16 + quad * 4] = o;
                }
            }
        }
    }
}

// ---------------------------------------------------------------- GCN gather
// Edge loop unrolled x4 (4 h-rows in flight); accumulation order preserved.
__global__ __launch_bounds__(256) void k_gather(
    const int* __restrict__ rowstart, const int* __restrict__ adj,
    const float* __restrict__ h, const float* __restrict__ dinv,
    const float* __restrict__ bias,
    unsigned short* __restrict__ hi, unsigned short* __restrict__ lo)
{
    const int n    = blockIdx.x * 4 + (threadIdx.x >> 6);   // grid exactly NND/4
    const int lane = threadIdx.x & 63;
    const int r0 = rowstart[n], r1 = rowstart[n + 1];
    const float dn = dinv[n];

    float2 hv = *(const float2*)&h[(size_t)n * 128 + 2 * lane];
    float2 acc;
    acc.x = hv.x * dn;
    acc.y = hv.y * dn;

    int i = r0;
    for (; i + 4 <= r1; i += 4) {
        int s0 = adj[i], s1 = adj[i + 1], s2 = adj[i + 2], s3 = adj[i + 3];
        float d0 = dinv[s0], d1 = dinv[s1], d2 = dinv[s2], d3 = dinv[s3];
        float2 v0 = *(const float2*)&h[(size_t)s0 * 128 + 2 * lane];
        float2 v1 = *(const float2*)&h[(size_t)s1 * 128 + 2 * lane];
        float2 v2 = *(const float2*)&h[(size_t)s2 * 128 + 2 * lane];
        float2 v3 = *(const float2*)&h[(size_t)s3 * 128 + 2 * lane];
        acc.x += v0.x * d0; acc.y += v0.y * d0;
        acc.x += v1.x * d1; acc.y += v1.y * d1;
        acc.x += v2.x * d2; acc.y += v2.y * d2;
        acc.x += v3.x * d3; acc.y += v3.y * d3;
    }
    for (; i < r1; ++i) {
        int s = adj[i];
        float ds = dinv[s];
        float2 v = *(const float2*)&h[(size_t)s * 128 + 2 * lane];
        acc.x += v.x * ds;
        acc.y += v.y * ds;
    }

    float2 bb = *(const float2*)&bias[2 * lane];
    float vx = fmaxf(acc.x * dn + bb.x, 0.f);
    float vy = fmaxf(acc.y * dn + bb.y, 0.f);
    ushort2 ho, lo2;
    ho.x = f2bf(vx); lo2.x = f2bf(vx - bf2f(ho.x));
    ho.y = f2bf(vy); lo2.y = f2bf(vy - bf2f(ho.y));
    *(ushort2*)&hi[(size_t)n * 128 + 2 * lane] = ho;
    *(ushort2*)&lo[(size_t)n * 128 + 2 * lane] = lo2;
}

// ---------------------------------------------------------------- prep kernels
__global__ void k_prep_gcnw2(const float* __restrict__ W1, const float* __restrict__ W2,
                             unsigned short* __restrict__ hi1, unsigned short* __restrict__ lo1,
                             unsigned short* __restrict__ hi2, unsigned short* __restrict__ lo2) {
    int t = blockIdx.x * 256 + threadIdx.x;   // grid 128 -> 32768 threads
    const float* W = (t < 16384) ? W1 : W2;
    unsigned short* hi = (t < 16384) ? hi1 : hi2;
    unsigned short* lo = (t < 16384) ? lo1 : lo2;
    int tt = t & 16383;
    int k = tt >> 7, n = tt & 127;
    float v = W[tt];
    unsigned short h = f2bf(v);
    hi[n * 128 + k] = h;
    lo[n * 128 + k] = f2bf(v - bf2f(h));
}

// LSTM prep: w_ih and w_hh [512(r=g*128+j)][128(k)] -> packed-transposed
// split-bf16 wT[p=j*4+g][k]; bias -> bp[p] = b_ih + b_hh.
__global__ void k_prep_lstm(const float* __restrict__ w_ih, const float* __restrict__ w_hh,
                            const float* __restrict__ b_ih, const float* __restrict__ b_hh,
                            unsigned short* __restrict__ ih_hi, unsigned short* __restrict__ ih_lo,
                            unsigned short* __restrict__ hh_hi, unsigned short* __restrict__ hh_lo,
                            float* __restrict__ bp)
{
    int t = blockIdx.x * 256 + threadIdx.x;
    if (t < 65536) {
        int r = t >> 7, k = t & 127;
        int g = r >> 7, j = r & 127;
        int p = (j << 2) + g;
        float v = w_ih[t];
        unsigned short h = f2bf(v);
        ih_hi[p * 128 + k] = h;
        ih_lo[p * 128 + k] = f2bf(v - bf2f(h));
    } else if (t < 131072) {
        int t2 = t - 65536;
        int r = t2 >> 7, k = t2 & 127;
        int g = r >> 7, j = r & 127;
        int p = (j << 2) + g;
        float v = w_hh[t2];
        unsigned short h = f2bf(v);
        hh_hi[p * 128 + k] = h;
        hh_lo[p * 128 + k] = f2bf(v - bf2f(h));
    } else if (t < 131584) {
        int r = t - 131072;   // 0..511
        int g = r >> 7, j = r & 127;
        bp[(j << 2) + g] = b_ih[r] + b_hh[r];
    }
}

// ---------------------------------------------------------------- LSTM recurrence
// v14: 1-term recurrence (R11) + BF16 G input. Reads ushort4 (8B) per step,
// converts with 4 bf2f. G traffic halves (51.2 MB total).
__global__ __launch_bounds__(512, 2) void k_lstm(
    const unsigned short* __restrict__ G,   // bf16, permuted: [blk][step][4 seq][512]
    const unsigned short* __restrict__ Whi, // 512 x 128, packed-transposed hi
    unsigned short* __restrict__ Hhi,       // (NB*TSEQ) x 128 bf16-hi, or nullptr
    const float* __restrict__ fcw,          // fused FC weight (layer 1) or nullptr
    const float* __restrict__ fcb,
    float* __restrict__ outp)               // NB x 1 output (layer 1) or nullptr
{
    const int tid  = threadIdx.x;
    const int lane = tid & 63, wave = tid >> 6;   // 8 waves
    const int l15  = lane & 15, quad = lane >> 4;
    const int b0   = blockIdx.x * SB;

    __shared__ __align__(16) unsigned short Ah[16 * AHS];  // h bf16 (rows SB..15 zero)
    __shared__ float partw[8][4][72];        // per-wave P patch [wave][b][col in wave]

    // weight fragments: wave owns n-tiles nt0..nt0+3 (n = p = j*4+gate)
    const int nt0 = wave * 4;
    s16x8 bh[4][4];   // [nt][ks]
    #pragma unroll
    for (int nt = 0; nt < 4; ++nt) {
        int p = (nt0 + nt) * 16 + l15;
        #pragma unroll
        for (int ks = 0; ks < 4; ++ks)
            bh[nt][ks] = *(const s16x8*)&Whi[(size_t)p * 128 + ks * 32 + quad * 8];
    }

    for (int i = tid; i < 16 * AHS; i += 512) Ah[i] = 0;

    // phase-2 mapping: lane l of wave w -> (b2, j) with j owned by wave w
    const int b2 = lane >> 4;              // 0..3
    const int jj = wave * 16 + l15;        // hidden unit this lane updates
    const int bg = b0 + b2;                // sequence index (NB % SB == 0)
    float c = 0.f;
    float hn_last = 0.f;

    // permuted-G base: row' = blk*200 + step*4 + b2; step stride = 2048 ushorts
    const unsigned short* gb = &G[((size_t)blockIdx.x * 200 + b2) * 512 + (jj << 2)];
    ushort4 gr_cur = *(const ushort4*)&gb[0];

    __syncthreads();

    for (int step = 0; step < TSEQ; ++step) {
        // prefetch NEXT step's gate input (full step of latency cover)
        const int nstep = (step + 1 < TSEQ) ? step + 1 : step;
        const ushort4 gr_nxt = *(const ushort4*)&gb[(size_t)nstep * 2048];

        // phase 1: MFMA  P = bf16(h) @ bf16(Whh)  (1-term)
        f32x4 acc[4] = {};
        #pragma unroll
        for (int ks = 0; ks < 4; ++ks) {
            s16x8 ah = *(const s16x8*)&Ah[l15 * AHS + ks * 32 + quad * 8];
            #pragma unroll
            for (int nt = 0; nt < 4; ++nt)
                acc[nt] = __builtin_amdgcn_mfma_f32_16x16x32_bf16(ah, bh[nt][ks], acc[nt], 0, 0, 0);
        }

        // intra-wave exchange: quad-0 lanes hold rows 0..3 (the real seqs)
        if (quad == 0) {
            #pragma unroll
            for (int nt = 0; nt < 4; ++nt)
                #pragma unroll
                for (int r = 0; r < 4; ++r)
                    partw[wave][r][nt * 16 + l15] = acc[nt][r];
        }
        // same-wave producer/consumer: compiler inserts lgkmcnt wait, no barrier

        // phase 2: LSTM cell for (b2, jj); reads this wave's own patch
        {
            float4 pa = *(const float4*)&partw[wave][b2][l15 * 4];
            float xi = pa.x + bf2f(gr_cur.x);
            float xf = pa.y + bf2f(gr_cur.y);
            float xg = pa.z + bf2f(gr_cur.z);
            float xo = pa.w + bf2f(gr_cur.w);
            float ii = sigf(xi), ff = sigf(xf), gg = tanhfast(xg), oo = sigf(xo);
            float cn = ff * c + ii * gg;
            c = cn;
            float hn = oo * tanhfast(cn);
            hn_last = hn;
            unsigned short hh = f2bf(hn);
            Ah[b2 * AHS + jj] = hh;
            if (Hhi)
                Hhi[((size_t)bg * TSEQ + step) * 128 + jj] = hh;
        }
        gr_cur = gr_nxt;
        // single barrier: Ah writes must be visible to all waves' phase-1
        __syncthreads();
    }

    // fused FC head (layer 1): out[bg] = dot(h_last[bg], fcw) + fcb
    if (outp) {
        float* red = (float*)Ah;   // 2 KiB scratch, Ah is dead now
        red[b2 * 128 + jj] = hn_last * fcw[jj];
        __syncthreads();
        if (wave < 4) {            // wave w reduces sequence b0+w
            float v = red[wave * 128 + lane] + red[wave * 128 + lane + 64];
            #pragma unroll
            for (int off = 32; off > 0; off >>= 1)
                v += __shfl_down(v, off);
            if (lane == 0) outp[b0 + wave] = v + fcb[0];
        }
    }
}

// ---------------------------------------------------------------- launch
extern "C" void kernel_launch(void* const* d_in, const int* in_sizes, int n_in,
                              void* d_out, int out_size, void* d_ws, size_t ws_size,
                              hipStream_t stream)
{
    const float* x    = (const float*)d_in[0];
    const int*   ei   = (const int*)d_in[1];
    const float* W1   = (const float*)d_in[3];
    const float* b1   = (const float*)d_in[4];
    const float* W2   = (const float*)d_in[5];
    const float* b2   = (const float*)d_in[6];
    const float* fcw  = (const float*)d_in[7];
    const float* fcb  = (const float*)d_in[8];
    const float* wih0 = (const float*)d_in[9];
    const float* whh0 = (const float*)d_in[10];
    const float* bih0 = (const float*)d_in[11];
    const float* bhh0 = (const float*)d_in[12];
    const float* wih1 = (const float*)d_in[13];
    const float* whh1 = (const float*)d_in[14];
    const float* bih1 = (const float*)d_in[15];
    const float* bhh1 = (const float*)d_in[16];
    float* out = (float*)d_out;

    char* ws = (char*)d_ws;
    // ---- persistent regions
    unsigned short* shi = (unsigned short*)(ws + 0);          // 12.8 MB
    unsigned short* slo = (unsigned short*)(ws + 12800000);   // 12.8 MB (ends 25.6M)
    unsigned short* bufG = (unsigned short*)(ws + 51200000);  // 51.2 MB bf16 (ends 102.4M)

    // ---- GCN-phase regions (overlap bufG region; dead before gate GEMM writes)
    unsigned short* xhi = (unsigned short*)(ws + 51200000);   // 12.8 MB
    unsigned short* xlo = (unsigned short*)(ws + 64000000);   // 12.8 MB
    float* bufHg  = (float*)(ws + 76800000);                  // 25.6 MB (ends 102.4M)
    int* cnt      = (int*)(ws + 102400000);                   // 200000 B (pad 204800)
    int* cursor   = (int*)(ws + 102604800);                   // contiguous with cnt
    int* rowstart = (int*)(ws + 102809600);
    int* adj      = (int*)(ws + 103014400);                   // 2.4 MB (ends 105.42M)
    int* bsum     = (int*)(ws + 105420800);                   // NSCB ints

    float* dinv = (float*)(ws + 153600000);
    float* bp0  = (float*)(ws + 153800192);
    float* bp1  = (float*)(ws + 153802240);
    unsigned short* w1t_hi   = (unsigned short*)(ws + 153804288);
    unsigned short* w1t_lo   = (unsigned short*)(ws + 153837056);
    unsigned short* w2t_hi   = (unsigned short*)(ws + 153869824);
    unsigned short* w2t_lo   = (unsigned short*)(ws + 153902592);
    unsigned short* wpih0_hi = (unsigned short*)(ws + 153935360);
    unsigned short* wpih0_lo = (unsigned short*)(ws + 154066432);
    unsigned short* wpih1_hi = (unsigned short*)(ws + 154197504);
    unsigned short* wpih1_lo = (unsigned short*)(ws + 154328576);
    unsigned short* wphh0_hi = (unsigned short*)(ws + 154459648);
    unsigned short* wphh0_lo = (unsigned short*)(ws + 154590720);
    unsigned short* wphh1_hi = (unsigned short*)(ws + 154721792);
    unsigned short* wphh1_lo = (unsigned short*)(ws + 154852864);

    // ---- CSR build + dinv (multi-block scan); cnt+cursor zeroed in ONE memset
    hipMemsetAsync(cnt, 0, 409600, stream);
    k_count<<<(NE + 255) / 256, 256, 0, stream>>>(ei, cnt);
    k_bsum<<<NSCB, 256, 0, stream>>>(cnt, bsum);
    k_bscan<<<1, 256, 0, stream>>>(bsum);
    k_bout<<<NSCB, 256, 0, stream>>>(cnt, bsum, rowstart, dinv);
    k_fill<<<(NE + 255) / 256, 256, 0, stream>>>(ei, rowstart, cursor, adj);

    // ---- weight prep
    k_prep_gcnw2<<<128, 256, 0, stream>>>(W1, W2, w1t_hi, w1t_lo, w2t_hi, w2t_lo);
    k_prep_lstm<<<514, 256, 0, stream>>>(wih0, whh0, bih0, bhh0,
                                         wpih0_hi, wpih0_lo, wphh0_hi, wphh0_lo, bp0);
    k_prep_lstm<<<514, 256, 0, stream>>>(wih1, whh1, bih1, bhh1,
                                         wpih1_hi, wpih1_lo, wphh1_hi, wphh1_lo, bp1);

    dim3 gH(1, 391);     // GCN GEMMs: 128-row panel, NT=2 (128 cols)

    // ---- GCN layer 1 (fp32 A, convert-on-stage)
    k_gemm_mfma_xa<<<gH, 256, 0, stream>>>(x, w1t_hi, w1t_lo, nullptr, bufHg, NND, 128, 2);
    k_gather<<<NND / 4, 256, 0, stream>>>(rowstart, adj, bufHg, dinv, b1, xhi, xlo);

    // ---- GCN layer 2
    k_gemm_mfma<<<gH, 256, 0, stream>>>(xhi, xlo, w2t_hi, w2t_lo, nullptr, bufHg, NND, 128, 2);
    k_gather<<<NND / 4, 256, 0, stream>>>(rowstart, adj, bufHg, dinv, b2, shi, slo);

    // ---- LSTM layer 0: swapped-operand gate GEMM (3-term, bf16 G) + recurrence
    k_gemm_gT<<<782, 256, 0, stream>>>(shi, slo, wpih0_hi, wpih0_lo, bp0, bufG, NND);
    k_lstm<<<NB / SB, 512, 0, stream>>>(bufG, wphh0_hi, shi,
                                        nullptr, nullptr, nullptr);

    // ---- LSTM layer 1: 2-term swapped gate GEMM (bf16 G) + recurrence + FC
    k_gemm_gT_h<<<782, 256, 0, stream>>>(shi, wpih1_hi, wpih1_lo, bp1, bufG, NND);
    k_lstm<<<NB / SB, 512, 0, stream>>>(bufG, wphh1_hi, nullptr,
                                        fcw, fcb, out);
}

// Round 13
// 479.159 us; speedup vs baseline: 1.1096x; 1.0116x over previous
//
#include <hip/hip_runtime.h>

// Problem constants (fixed by the reference file)
#define NND 50000   // nodes
#define NE  600000  // edges
#define TSEQ 50     // sequence length
#define NB  1000    // batch = NND/TSEQ
#define SB  4       // sequences per LSTM workgroup
#define AHS 136     // LDS h-row stride in shorts (128 + 8 pad, 16B-aligned)
#define NSCB 196    // scan blocks: ceil(NND/256)

typedef __attribute__((ext_vector_type(4))) float f32x4;
typedef __attribute__((ext_vector_type(8))) short s16x8;

// ---------------------------------------------------------------- helpers
__device__ __forceinline__ float sigf(float x) {
    return 1.0f / (1.0f + __expf(-x));
}
__device__ __forceinline__ float tanhfast(float x) {
    x = fminf(fmaxf(x, -15.f), 15.f);
    float e = __expf(2.f * x);
    return (e - 1.f) / (e + 1.f);
}
// bf16 bit helpers (round-to-nearest-even)
__device__ __forceinline__ unsigned short f2bf(float f) {
    unsigned int u = __float_as_uint(f);
    u = u + 0x7FFFu + ((u >> 16) & 1u);
    return (unsigned short)(u >> 16);
}
__device__ __forceinline__ float bf2f(unsigned short h) {
    return __uint_as_float(((unsigned int)h) << 16);
}
// G row permutation: node n -> block-local row (blk*200 + step*4 + seq_in_blk).
// Pure bijection on [0, NND): LSTM block b reads contiguous 4KB per step.
__device__ __forceinline__ int grow_perm(int n) {
    int grp = n / 200;
    int rem = n % 200;
    return grp * 200 + (n % 50) * 4 + rem / 50;
}

// ---------------------------------------------------------------- CSR build
__global__ void k_count(const int* __restrict__ ei, int* __restrict__ cnt) {
    int e = blockIdx.x * 256 + threadIdx.x;
    if (e < NE) atomicAdd(&cnt[ei[NE + e]], 1);
}

// ---- 3-stage multi-block exclusive scan of cnt -> rowstart (+ fused dinv)
__global__ __launch_bounds__(256) void k_bsum(const int* __restrict__ cnt,
                                              int* __restrict__ bsum) {
    __shared__ int red[256];
    int t = threadIdx.x;
    int idx = blockIdx.x * 256 + t;
    red[t] = (idx < NND) ? cnt[idx] : 0;
    __syncthreads();
    for (int off = 128; off > 0; off >>= 1) {
        if (t < off) red[t] += red[t + off];
        __syncthreads();
    }
    if (t == 0) bsum[blockIdx.x] = red[0];
}

__global__ __launch_bounds__(256) void k_bscan(int* __restrict__ bsum) {
    __shared__ int ps[256];
    int t = threadIdx.x;
    int v = (t < NSCB) ? bsum[t] : 0;
    ps[t] = v;
    __syncthreads();
    for (int off = 1; off < 256; off <<= 1) {
        int u = 0;
        if (t >= off) u = ps[t - off];
        __syncthreads();
        if (t >= off) ps[t] += u;
        __syncthreads();
    }
    if (t < NSCB) bsum[t] = ps[t] - v;   // exclusive
}

__global__ __launch_bounds__(256) void k_bout(const int* __restrict__ cnt,
                                              const int* __restrict__ bsum,
                                              int* __restrict__ rowstart,
                                              float* __restrict__ dinv) {
    __shared__ int ps[256];
    int t = threadIdx.x;
    int idx = blockIdx.x * 256 + t;
    int v = (idx < NND) ? cnt[idx] : 0;
    ps[t] = v;
    __syncthreads();
    for (int off = 1; off < 256; off <<= 1) {
        int u = 0;
        if (t >= off) u = ps[t - off];
        __syncthreads();
        if (t >= off) ps[t] += u;
        __syncthreads();
    }
    int boff = bsum[blockIdx.x];
    if (idx < NND) {
        rowstart[idx] = boff + ps[t] - v;   // exclusive
        dinv[idx] = 1.0f / sqrtf((float)v + 1.0f);   // fused (was k_dinv)
    }
    if (idx == NND - 1) rowstart[NND] = boff + ps[t];  // == NE
}

__global__ void k_fill(const int* __restrict__ ei, const int* __restrict__ rowstart,
                       int* __restrict__ cursor, int* __restrict__ adj) {
    int e = blockIdx.x * 256 + threadIdx.x;
    if (e >= NE) return;
    int s = ei[e], d = ei[NE + e];
    int pos = atomicAdd(&cursor[d], 1);
    adj[rowstart[d] + pos] = s;
}

// ---------------------------------------------------------------- MFMA GEMM
// 2-term GCN GEMM: A plain bf16 (hi only), B split hi/lo. 128x128 A panel
// staged once (34.8 KB LDS -> 4 blocks/CU, was 69.6/2), NT col-tiles.
// R12 numerics evidence: bf16 quantization of gate pre-activations produced
// ZERO absmax change; the A-lo term here injects same-order noise.
__global__ __launch_bounds__(256) void k_gemm_mfma_h2(
    const unsigned short* __restrict__ Ahi,
    const unsigned short* __restrict__ Bhi, const unsigned short* __restrict__ Blo,
    const float* __restrict__ bias, float* __restrict__ C,
    int M, int Nc, int NT)
{
    __shared__ unsigned short As_hi[128][136];

    const int tid  = threadIdx.x;
    const int lane = tid & 63, wave = tid >> 6;
    const int mw = wave & 1, nw = wave >> 1;
    const int l15 = lane & 15, quad = lane >> 4;
    const int rowBase = blockIdx.y * 128;

    {
        int r0 = tid >> 4;            // 0..15
        int ko = (tid & 15) * 8;      // 0..120
        #pragma unroll
        for (int i = 0; i < 8; ++i) {
            int row = r0 + i * 16;
            int g = rowBase + row;
            uint4 vh = make_uint4(0, 0, 0, 0);
            if (g < M) vh = *(const uint4*)&Ahi[(size_t)g * 128 + ko];
            *(uint4*)&As_hi[row][ko] = vh;
        }
    }
    __syncthreads();

    for (int nt = 0; nt < NT; ++nt) {
        const int colBase = (blockIdx.x * NT + nt) * 64;

        s16x8 bh[2][4], bl[2][4];   // [ns][kq]
        #pragma unroll
        for (int ns = 0; ns < 2; ++ns) {
            int gn = colBase + nw * 32 + ns * 16 + l15;
            #pragma unroll
            for (int kq = 0; kq < 4; ++kq) {
                bh[ns][kq] = *(const s16x8*)&Bhi[(size_t)gn * 128 + kq * 32 + quad * 8];
                bl[ns][kq] = *(const s16x8*)&Blo[(size_t)gn * 128 + kq * 32 + quad * 8];
            }
        }

        f32x4 acc[4][2] = {};
        #pragma unroll
        for (int kq = 0; kq < 4; ++kq) {
            int kof = kq * 32 + quad * 8;
            s16x8 ah[4];
            #pragma unroll
            for (int ms = 0; ms < 4; ++ms) {
                int r = mw * 64 + ms * 16 + l15;
                ah[ms] = *(const s16x8*)&As_hi[r][kof];
            }
            #pragma unroll
            for (int ms = 0; ms < 4; ++ms)
                #pragma unroll
                for (int ns = 0; ns < 2; ++ns)
                    acc[ms][ns] = __builtin_amdgcn_mfma_f32_16x16x32_bf16(ah[ms], bh[ns][kq], acc[ms][ns], 0, 0, 0);
            #pragma unroll
            for (int ms = 0; ms < 4; ++ms)
                #pragma unroll
                for (int ns = 0; ns < 2; ++ns)
                    acc[ms][ns] = __builtin_amdgcn_mfma_f32_16x16x32_bf16(ah[ms], bl[ns][kq], acc[ms][ns], 0, 0, 0);
        }

        #pragma unroll
        for (int ns = 0; ns < 2; ++ns) {
            int col = colBase + nw * 32 + ns * 16 + l15;
            float bv = bias ? bias[col] : 0.f;
            #pragma unroll
            for (int ms = 0; ms < 4; ++ms) {
                int row0 = rowBase + mw * 64 + ms * 16 + quad * 4;
                #pragma unroll
                for (int r = 0; r < 4; ++r) {
                    int row = row0 + r;
                    if (row < M) C[(size_t)row * Nc + col] = acc[ms][ns][r] + bv;
                }
            }
        }
    }
}

// Variant: A is raw fp32 (input x); split-bf16 conversion fused into staging.
// (GCN layer 1 keeps full split precision — input is fp32.)
__global__ __launch_bounds__(256) void k_gemm_mfma_xa(
    const float* __restrict__ X,
    const unsigned short* __restrict__ Bhi, const unsigned short* __restrict__ Blo,
    const float* __restrict__ bias, float* __restrict__ C,
    int M, int Nc, int NT)
{
    __shared__ unsigned short As_hi[128][136];
    __shared__ unsigned short As_lo[128][136];

    const int tid  = threadIdx.x;
    const int lane = tid & 63, wave = tid >> 6;
    const int mw = wave & 1, nw = wave >> 1;
    const int l15 = lane & 15, quad = lane >> 4;
    const int rowBase = blockIdx.y * 128;

    {
        int r0 = tid >> 4;
        int ko = (tid & 15) * 8;
        #pragma unroll
        for (int i = 0; i < 8; ++i) {
            int row = r0 + i * 16;
            int g = rowBase + row;
            unsigned short hx[8], lx[8];
            if (g < M) {
                float4 v0 = *(const float4*)&X[(size_t)g * 128 + ko];
                float4 v1 = *(const float4*)&X[(size_t)g * 128 + ko + 4];
                const float vv[8] = {v0.x, v0.y, v0.z, v0.w, v1.x, v1.y, v1.z, v1.w};
                #pragma unroll
                for (int e = 0; e < 8; ++e) {
                    hx[e] = f2bf(vv[e]);
                    lx[e] = f2bf(vv[e] - bf2f(hx[e]));
                }
            } else {
                #pragma unroll
                for (int e = 0; e < 8; ++e) { hx[e] = 0; lx[e] = 0; }
            }
            *(uint4*)&As_hi[row][ko] = *(const uint4*)hx;
            *(uint4*)&As_lo[row][ko] = *(const uint4*)lx;
        }
    }
    __syncthreads();

    for (int nt = 0; nt < NT; ++nt) {
        const int colBase = (blockIdx.x * NT + nt) * 64;

        s16x8 bh[2][4], bl[2][4];
        #pragma unroll
        for (int ns = 0; ns < 2; ++ns) {
            int gn = colBase + nw * 32 + ns * 16 + l15;
            #pragma unroll
            for (int kq = 0; kq < 4; ++kq) {
                bh[ns][kq] = *(const s16x8*)&Bhi[(size_t)gn * 128 + kq * 32 + quad * 8];
                bl[ns][kq] = *(const s16x8*)&Blo[(size_t)gn * 128 + kq * 32 + quad * 8];
            }
        }

        f32x4 acc[4][2] = {};
        #pragma unroll
        for (int kq = 0; kq < 4; ++kq) {
            int kof = kq * 32 + quad * 8;
            s16x8 ah[4], al[4];
            #pragma unroll
            for (int ms = 0; ms < 4; ++ms) {
                int r = mw * 64 + ms * 16 + l15;
                ah[ms] = *(const s16x8*)&As_hi[r][kof];
                al[ms] = *(const s16x8*)&As_lo[r][kof];
            }
            #pragma unroll
            for (int ms = 0; ms < 4; ++ms)
                #pragma unroll
                for (int ns = 0; ns < 2; ++ns)
                    acc[ms][ns] = __builtin_amdgcn_mfma_f32_16x16x32_bf16(ah[ms], bh[ns][kq], acc[ms][ns], 0, 0, 0);
            #pragma unroll
            for (int ms = 0; ms < 4; ++ms)
                #pragma unroll
                for (int ns = 0; ns < 2; ++ns)
                    acc[ms][ns] = __builtin_amdgcn_mfma_f32_16x16x32_bf16(al[ms], bh[ns][kq], acc[ms][ns], 0, 0, 0);
            #pragma unroll
            for (int ms = 0; ms < 4; ++ms)
                #pragma unroll
                for (int ns = 0; ns < 2; ++ns)
                    acc[ms][ns] = __builtin_amdgcn_mfma_f32_16x16x32_bf16(ah[ms], bl[ns][kq], acc[ms][ns], 0, 0, 0);
        }

        #pragma unroll
        for (int ns = 0; ns < 2; ++ns) {
            int col = colBase + nw * 32 + ns * 16 + l15;
            float bv = bias ? bias[col] : 0.f;
            #pragma unroll
            for (int ms = 0; ms < 4; ++ms) {
                int row0 = rowBase + mw * 64 + ms * 16 + quad * 4;
                #pragma unroll
                for (int r = 0; r < 4; ++r) {
                    int row = row0 + r;
                    if (row < M) C[(size_t)row * Nc + col] = acc[ms][ns][r] + bv;
                }
            }
        }
    }
}

// ---------------------------------------------------------------- gate GEMM
// 2-term swapped-operand gate GEMM (R7 layout, R10 permuted rows, R12 bf16 G):
// A = plain bf16 activations, W split hi/lo. Used for BOTH LSTM layers now
// (R12: gate pre-activations tolerate bf16-level noise at zero absmax cost).
// LDS 17.4 KB -> 8 blocks/CU.
__global__ __launch_bounds__(256) void k_gemm_gT_h(
    const unsigned short* __restrict__ Ahi,
    const unsigned short* __restrict__ Whi, const unsigned short* __restrict__ Wlo,
    const float* __restrict__ bp, unsigned short* __restrict__ G,
    int M)
{
    __shared__ unsigned short As_hi[64][136];

    const int tid  = threadIdx.x;
    const int lane = tid & 63, wave = tid >> 6;
    const int l15 = lane & 15, quad = lane >> 4;
    const int rowBase = blockIdx.x * 64;

    {
        int r0 = tid >> 4;
        int ko = (tid & 15) * 8;
        #pragma unroll
        for (int i = 0; i < 4; ++i) {
            int row = r0 + i * 16;
            int g = rowBase + row;
            uint4 vh = make_uint4(0, 0, 0, 0);
            if (g < M) vh = *(const uint4*)&Ahi[(size_t)g * 128 + ko];
            *(uint4*)&As_hi[row][ko] = vh;
        }
    }
    __syncthreads();

    const int pb = wave * 128;

    #pragma unroll
    for (int tp = 0; tp < 4; ++tp) {
        const int p0 = pb + tp * 32;

        s16x8 wh[2][4], wl[2][4];
        #pragma unroll
        for (int t = 0; t < 2; ++t)
            #pragma unroll
            for (int kq = 0; kq < 4; ++kq) {
                const size_t wrow = (size_t)(p0 + t * 16 + l15) * 128 + kq * 32 + quad * 8;
                wh[t][kq] = *(const s16x8*)&Whi[wrow];
                wl[t][kq] = *(const s16x8*)&Wlo[wrow];
            }
        float4 bv[2];
        #pragma unroll
        for (int t = 0; t < 2; ++t)
            bv[t] = *(const float4*)&bp[p0 + t * 16 + quad * 4];

        #pragma unroll
        for (int rg = 0; rg < 4; ++rg) {
            s16x8 xh[4];
            #pragma unroll
            for (int kq = 0; kq < 4; ++kq)
                xh[kq] = *(const s16x8*)&As_hi[rg * 16 + l15][kq * 32 + quad * 8];
            f32x4 acc[2] = {};
            #pragma unroll
            for (int kq = 0; kq < 4; ++kq)
                #pragma unroll
                for (int t = 0; t < 2; ++t) {
                    acc[t] = __builtin_amdgcn_mfma_f32_16x16x32_bf16(wh[t][kq], xh[kq], acc[t], 0, 0, 0);
                    acc[t] = __builtin_amdgcn_mfma_f32_16x16x32_bf16(wl[t][kq], xh[kq], acc[t], 0, 0, 0);
                }
            const int row = rowBase + rg * 16 + l15;
            if (row < M) {
                const size_t prow = (size_t)grow_perm(row);
                #pragma unroll
                for (int t = 0; t < 2; ++t) {
                    ushort4 o;
                    o.x = f2bf(acc[t][0] + bv[t].x);
                    o.y = f2bf(acc[t][1] + bv[t].y);
                    o.z = f2bf(acc[t][2] + bv[t].z);
                    o.w = f2bf(acc[t][3] + bv[t].w);
                    *(ushort4*)&G[prow * 512 + p0 + t * 16 + quad * 4] = o;
                }
            }
        }
    }
}

// ---------------------------------------------------------------- GCN gather
// Edge loop unrolled x4; accumulation order preserved. lo output optional
// (nullptr -> hi-only consumer downstream; saves 12.8 MB write).
__global__ __launch_bounds__(256) void k_gather(
    const int* __restrict__ rowstart, const int* __restrict__ adj,
    const float* __restrict__ h, const float* __restrict__ dinv,
    const float* __restrict__ bias,
    unsigned short* __restrict__ hi, unsigned short* __restrict__ lo)
{
    const int n    = blockIdx.x * 4 + (threadIdx.x >> 6);   // grid exactly NND/4
    const int lane = threadIdx.x & 63;
    const int r0 = rowstart[n], r1 = rowstart[n + 1];
    const float dn = dinv[n];

    float2 hv = *(const float2*)&h[(size_t)n * 128 + 2 * lane];
    float2 acc;
    acc.x = hv.x * dn;
    acc.y = hv.y * dn;

    int i = r0;
    for (; i + 4 <= r1; i += 4) {
        int s0 = adj[i], s1 = adj[i + 1], s2 = adj[i + 2], s3 = adj[i + 3];
        float d0 = dinv[s0], d1 = dinv[s1], d2 = dinv[s2], d3 = dinv[s3];
        float2 v0 = *(const float2*)&h[(size_t)s0 * 128 + 2 * lane];
        float2 v1 = *(const float2*)&h[(size_t)s1 * 128 + 2 * lane];
        float2 v2 = *(const float2*)&h[(size_t)s2 * 128 + 2 * lane];
        float2 v3 = *(const float2*)&h[(size_t)s3 * 128 + 2 * lane];
        acc.x += v0.x * d0; acc.y += v0.y * d0;
        acc.x += v1.x * d1; acc.y += v1.y * d1;
        acc.x += v2.x * d2; acc.y += v2.y * d2;
        acc.x += v3.x * d3; acc.y += v3.y * d3;
    }
    for (; i < r1; ++i) {
        int s = adj[i];
        float ds = dinv[s];
        float2 v = *(const float2*)&h[(size_t)s * 128 + 2 * lane];
        acc.x += v.x * ds;
        acc.y += v.y * ds;
    }

    float2 bb = *(const float2*)&bias[2 * lane];
    float vx = fmaxf(acc.x * dn + bb.x, 0.f);
    float vy = fmaxf(acc.y * dn + bb.y, 0.f);
    ushort2 ho;
    ho.x = f2bf(vx);
    ho.y = f2bf(vy);
    *(ushort2*)&hi[(size_t)n * 128 + 2 * lane] = ho;
    if (lo) {
        ushort2 lo2;
        lo2.x = f2bf(vx - bf2f(ho.x));
        lo2.y = f2bf(vy - bf2f(ho.y));
        *(ushort2*)&lo[(size_t)n * 128 + 2 * lane] = lo2;
    }
}

// ---------------------------------------------------------------- prep kernels
__global__ void k_prep_gcnw2(const float* __restrict__ W1, const float* __restrict__ W2,
                             unsigned short* __restrict__ hi1, unsigned short* __restrict__ lo1,
                             unsigned short* __restrict__ hi2, unsigned short* __restrict__ lo2) {
    int t = blockIdx.x * 256 + threadIdx.x;   // grid 128 -> 32768 threads
    const float* W = (t < 16384) ? W1 : W2;
    unsigned short* hi = (t < 16384) ? hi1 : hi2;
    unsigned short* lo = (t < 16384) ? lo1 : lo2;
    int tt = t & 16383;
    int k = tt >> 7, n = tt & 127;
    float v = W[tt];
    unsigned short h = f2bf(v);
    hi[n * 128 + k] = h;
    lo[n * 128 + k] = f2bf(v - bf2f(h));
}

// LSTM prep: w_ih and w_hh [512(r=g*128+j)][128(k)] -> packed-transposed
// split-bf16 wT[p=j*4+g][k]; bias -> bp[p] = b_ih + b_hh.
__global__ void k_prep_lstm(const float* __restrict__ w_ih, const float* __restrict__ w_hh,
                            const float* __restrict__ b_ih, const float* __restrict__ b_hh,
                            unsigned short* __restrict__ ih_hi, unsigned short* __restrict__ ih_lo,
                            unsigned short* __restrict__ hh_hi, unsigned short* __restrict__ hh_lo,
                            float* __restrict__ bp)
{
    int t = blockIdx.x * 256 + threadIdx.x;
    if (t < 65536) {
        int r = t >> 7, k = t & 127;
        int g = r >> 7, j = r & 127;
        int p = (j << 2) + g;
        float v = w_ih[t];
        unsigned short h = f2bf(v);
        ih_hi[p * 128 + k] = h;
        ih_lo[p * 128 + k] = f2bf(v - bf2f(h));
    } else if (t < 131072) {
        int t2 = t - 65536;
        int r = t2 >> 7, k = t2 & 127;
        int g = r >> 7, j = r & 127;
        int p = (j << 2) + g;
        float v = w_hh[t2];
        unsigned short h = f2bf(v);
        hh_hi[p * 128 + k] = h;
        hh_lo[p * 128 + k] = f2bf(v - bf2f(h));
    } else if (t < 131584) {
        int r = t - 131072;   // 0..511
        int g = r >> 7, j = r & 127;
        bp[(j << 2) + g] = b_ih[r] + b_hh[r];
    }
}

// ---------------------------------------------------------------- LSTM recurrence
// v14 (verified R12): 1-term recurrence + bf16 G input + permuted-G streaming
// + one-step register prefetch.
__global__ __launch_bounds__(512, 2) void k_lstm(
    const unsigned short* __restrict__ G,   // bf16, permuted: [blk][step][4 seq][512]
    const unsigned short* __restrict__ Whi, // 512 x 128, packed-transposed hi
    unsigned short* __restrict__ Hhi,       // (NB*TSEQ) x 128 bf16-hi, or nullptr
    const float* __restrict__ fcw,          // fused FC weight (layer 1) or nullptr
    const float* __restrict__ fcb,
    float* __restrict__ outp)               // NB x 1 output (layer 1) or nullptr
{
    const int tid  = threadIdx.x;
    const int lane = tid & 63, wave = tid >> 6;   // 8 waves
    const int l15  = lane & 15, quad = lane >> 4;
    const int b0   = blockIdx.x * SB;

    __shared__ __align__(16) unsigned short Ah[16 * AHS];  // h bf16 (rows SB..15 zero)
    __shared__ float partw[8][4][72];        // per-wave P patch [wave][b][col in wave]

    // weight fragments: wave owns n-tiles nt0..nt0+3 (n = p = j*4+gate)
    const int nt0 = wave * 4;
    s16x8 bh[4][4];   // [nt][ks]
    #pragma unroll
    for (int nt = 0; nt < 4; ++nt) {
        int p = (nt0 + nt) * 16 + l15;
        #pragma unroll
        for (int ks = 0; ks < 4; ++ks)
            bh[nt][ks] = *(const s16x8*)&Whi[(size_t)p * 128 + ks * 32 + quad * 8];
    }

    for (int i = tid; i < 16 * AHS; i += 512) Ah[i] = 0;

    // phase-2 mapping: lane l of wave w -> (b2, j) with j owned by wave w
    const int b2 = lane >> 4;              // 0..3
    const int jj = wave * 16 + l15;        // hidden unit this lane updates
    const int bg = b0 + b2;                // sequence index (NB % SB == 0)
    float c = 0.f;
    float hn_last = 0.f;

    // permuted-G base: row' = blk*200 + step*4 + b2; step stride = 2048 ushorts
    const unsigned short* gb = &G[((size_t)blockIdx.x * 200 + b2) * 512 + (jj << 2)];
    ushort4 gr_cur = *(const ushort4*)&gb[0];

    __syncthreads();

    for (int step = 0; step < TSEQ; ++step) {
        // prefetch NEXT step's gate input (full step of latency cover)
        const int nstep = (step + 1 < TSEQ) ? step + 1 : step;
        const ushort4 gr_nxt = *(const ushort4*)&gb[(size_t)nstep * 2048];

        // phase 1: MFMA  P = bf16(h) @ bf16(Whh)  (1-term)
        f32x4 acc[4] = {};
        #pragma unroll
        for (int ks = 0; ks < 4; ++ks) {
            s16x8 ah = *(const s16x8*)&Ah[l15 * AHS + ks * 32 + quad * 8];
            #pragma unroll
            for (int nt = 0; nt < 4; ++nt)
                acc[nt] = __builtin_amdgcn_mfma_f32_16x16x32_bf16(ah, bh[nt][ks], acc[nt], 0, 0, 0);
        }

        // intra-wave exchange: quad-0 lanes hold rows 0..3 (the real seqs)
        if (quad == 0) {
            #pragma unroll
            for (int nt = 0; nt < 4; ++nt)
                #pragma unroll
                for (int r = 0; r < 4; ++r)
                    partw[wave][r][nt * 16 + l15] = acc[nt][r];
        }
        // same-wave producer/consumer: compiler inserts lgkmcnt wait, no barrier

        // phase 2: LSTM cell for (b2, jj); reads this wave's own patch
        {
            float4 pa = *(const float4*)&partw[wave][b2][l15 * 4];
            float xi = pa.x + bf2f(gr_cur.x);
            float xf = pa.y + bf2f(gr_cur.y);
            float xg = pa.z + bf2f(gr_cur.z);
            float xo = pa.w + bf2f(gr_cur.w);
            float ii = sigf(xi), ff = sigf(xf), gg = tanhfast(xg), oo = sigf(xo);
            float cn = ff * c + ii * gg;
            c = cn;
            float hn = oo * tanhfast(cn);
            hn_last = hn;
            unsigned short hh = f2bf(hn);
            Ah[b2 * AHS + jj] = hh;
            if (Hhi)
                Hhi[((size_t)bg * TSEQ + step) * 128 + jj] = hh;
        }
        gr_cur = gr_nxt;
        // single barrier: Ah writes must be visible to all waves' phase-1
        __syncthreads();
    }

    // fused FC head (layer 1): out[bg] = dot(h_last[bg], fcw) + fcb
    if (outp) {
        float* red = (float*)Ah;   // 2 KiB scratch, Ah is dead now
        red[b2 * 128 + jj] = hn_last * fcw[jj];
        __syncthreads();
        if (wave < 4) {            // wave w reduces sequence b0+w
            float v = red[wave * 128 + lane] + red[wave * 128 + lane + 64];
            #pragma unroll
            for (int off = 32; off > 0; off >>= 1)
                v += __shfl_down(v, off);
            if (lane == 0) outp[b0 + wave] = v + fcb[0];
        }
    }
}

// ---------------------------------------------------------------- launch
extern "C" void kernel_launch(void* const* d_in, const int* in_sizes, int n_in,
                              void* d_out, int out_size, void* d_ws, size_t ws_size,
                              hipStream_t stream)
{
    const float* x    = (const float*)d_in[0];
    const int*   ei   = (const int*)d_in[1];
    const float* W1   = (const float*)d_in[3];
    const float* b1   = (const float*)d_in[4];
    const float* W2   = (const float*)d_in[5];
    const float* b2   = (const float*)d_in[6];
    const float* fcw  = (const float*)d_in[7];
    const float* fcb  = (const float*)d_in[8];
    const float* wih0 = (const float*)d_in[9];
    const float* whh0 = (const float*)d_in[10];
    const float* bih0 = (const float*)d_in[11];
    const float* bhh0 = (const float*)d_in[12];
    const float* wih1 = (const float*)d_in[13];
    const float* whh1 = (const float*)d_in[14];
    const float* bih1 = (const float*)d_in[15];
    const float* bhh1 = (const float*)d_in[16];
    float* out = (float*)d_out;

    char* ws = (char*)d_ws;
    // ---- persistent regions
    unsigned short* shi = (unsigned short*)(ws + 0);          // 12.8 MB
    unsigned short* bufG = (unsigned short*)(ws + 51200000);  // 51.2 MB bf16 (ends 102.4M)

    // ---- GCN-phase regions (overlap bufG region; dead before gate GEMM writes)
    unsigned short* xhi = (unsigned short*)(ws + 51200000);   // 12.8 MB
    float* bufHg  = (float*)(ws + 76800000);                  // 25.6 MB (ends 102.4M)
    int* cnt      = (int*)(ws + 102400000);                   // 200000 B (pad 204800)
    int* cursor   = (int*)(ws + 102604800);                   // contiguous with cnt
    int* rowstart = (int*)(ws + 102809600);
    int* adj      = (int*)(ws + 103014400);                   // 2.4 MB (ends 105.42M)
    int* bsum     = (int*)(ws + 105420800);                   // NSCB ints

    float* dinv = (float*)(ws + 153600000);
    float* bp0  = (float*)(ws + 153800192);
    float* bp1  = (float*)(ws + 153802240);
    unsigned short* w1t_hi   = (unsigned short*)(ws + 153804288);
    unsigned short* w1t_lo   = (unsigned short*)(ws + 153837056);
    unsigned short* w2t_hi   = (unsigned short*)(ws + 153869824);
    unsigned short* w2t_lo   = (unsigned short*)(ws + 153902592);
    unsigned short* wpih0_hi = (unsigned short*)(ws + 153935360);
    unsigned short* wpih0_lo = (unsigned short*)(ws + 154066432);
    unsigned short* wpih1_hi = (unsigned short*)(ws + 154197504);
    unsigned short* wpih1_lo = (unsigned short*)(ws + 154328576);
    unsigned short* wphh0_hi = (unsigned short*)(ws + 154459648);
    unsigned short* wphh0_lo = (unsigned short*)(ws + 154590720);
    unsigned short* wphh1_hi = (unsigned short*)(ws + 154721792);
    unsigned short* wphh1_lo = (unsigned short*)(ws + 154852864);

    // ---- CSR build + dinv (multi-block scan); cnt+cursor zeroed in ONE memset
    hipMemsetAsync(cnt, 0, 409600, stream);
    k_count<<<(NE + 255) / 256, 256, 0, stream>>>(ei, cnt);
    k_bsum<<<NSCB, 256, 0, stream>>>(cnt, bsum);
    k_bscan<<<1, 256, 0, stream>>>(bsum);
    k_bout<<<NSCB, 256, 0, stream>>>(cnt, bsum, rowstart, dinv);
    k_fill<<<(NE + 255) / 256, 256, 0, stream>>>(ei, rowstart, cursor, adj);

    // ---- weight prep
    k_prep_gcnw2<<<128, 256, 0, stream>>>(W1, W2, w1t_hi, w1t_lo, w2t_hi, w2t_lo);
    k_prep_lstm<<<514, 256, 0, stream>>>(wih0, whh0, bih0, bhh0,
                                         wpih0_hi, wpih0_lo, wphh0_hi, wphh0_lo, bp0);
    k_prep_lstm<<<514, 256, 0, stream>>>(wih1, whh1, bih1, bhh1,
                                         wpih1_hi, wpih1_lo, wphh1_hi, wphh1_lo, bp1);

    dim3 gH(1, 391);     // GCN GEMMs: 128-row panel, NT=2 (128 cols)

    // ---- GCN layer 1 (fp32 A, convert-on-stage, split precision)
    k_gemm_mfma_xa<<<gH, 256, 0, stream>>>(x, w1t_hi, w1t_lo, nullptr, bufHg, NND, 128, 2);
    k_gather<<<NND / 4, 256, 0, stream>>>(rowstart, adj, bufHg, dinv, b1, xhi, nullptr);

    // ---- GCN layer 2 (2-term: A = bf16 hi only)
    k_gemm_mfma_h2<<<gH, 256, 0, stream>>>(xhi, w2t_hi, w2t_lo, nullptr, bufHg, NND, 128, 2);
    k_gather<<<NND / 4, 256, 0, stream>>>(rowstart, adj, bufHg, dinv, b2, shi, nullptr);

    // ---- LSTM layer 0: 2-term gate GEMM (bf16 G) + recurrence (H -> shi in-place)
    k_gemm_gT_h<<<782, 256, 0, stream>>>(shi, wpih0_hi, wpih0_lo, bp0, bufG, NND);
    k_lstm<<<NB / SB, 512, 0, stream>>>(bufG, wphh0_hi, shi,
                                        nullptr, nullptr, nullptr);

    // ---- LSTM layer 1: 2-term gate GEMM (bf16 G) + recurrence + fused FC
    k_gemm_gT_h<<<782, 256, 0, stream>>>(shi, wpih1_hi, wpih1_lo, bp1, bufG, NND);
    k_lstm<<<NB / SB, 512, 0, stream>>>(bufG, wphh1_hi, nullptr,
                                        fcw, fcb, out);
}

// Round 14
// 477.137 us; speedup vs baseline: 1.1143x; 1.0042x over previous
//
#include <hip/hip_runtime.h>

// Problem constants (fixed by the reference file)
#define NND 50000   // nodes
#define NE  600000  // edges
#define TSEQ 50     // sequence length
#define NB  1000    // batch = NND/TSEQ
#define SB  4       // sequences per LSTM workgroup
#define AHS 136     // LDS h-row stride in shorts (128 + 8 pad, 16B-aligned)
#define NSCB 196    // scan blocks: ceil(NND/256)

typedef __attribute__((ext_vector_type(4))) float f32x4;
typedef __attribute__((ext_vector_type(8))) short s16x8;

// ---------------------------------------------------------------- helpers
__device__ __forceinline__ float sigf(float x) {
    return 1.0f / (1.0f + __expf(-x));
}
__device__ __forceinline__ float tanhfast(float x) {
    x = fminf(fmaxf(x, -15.f), 15.f);
    float e = __expf(2.f * x);
    return (e - 1.f) / (e + 1.f);
}
// bf16 bit helpers (round-to-nearest-even)
__device__ __forceinline__ unsigned short f2bf(float f) {
    unsigned int u = __float_as_uint(f);
    u = u + 0x7FFFu + ((u >> 16) & 1u);
    return (unsigned short)(u >> 16);
}
__device__ __forceinline__ float bf2f(unsigned short h) {
    return __uint_as_float(((unsigned int)h) << 16);
}
// LDS-only barrier: waits DS ops (lgkmcnt) but leaves GLOBAL ops in flight
// (no vmcnt drain). Safe when cross-wave data lives only in LDS — the
// __syncthreads() vmcnt(0) drain put the Hhi store + G prefetch completion
// on the serial critical path every step (m97-class stall).
__device__ __forceinline__ void barrier_lds_only() {
    asm volatile("s_waitcnt lgkmcnt(0)\n\ts_barrier" ::: "memory");
}
// G row permutation: node n -> block-local row (blk*200 + step*4 + seq_in_blk).
// Pure bijection on [0, NND): LSTM block b reads contiguous 4KB per step.
__device__ __forceinline__ int grow_perm(int n) {
    int grp = n / 200;
    int rem = n % 200;
    return grp * 200 + (n % 50) * 4 + rem / 50;
}

// ---------------------------------------------------------------- CSR build
__global__ void k_count(const int* __restrict__ ei, int* __restrict__ cnt) {
    int e = blockIdx.x * 256 + threadIdx.x;
    if (e < NE) atomicAdd(&cnt[ei[NE + e]], 1);
}

// ---- 3-stage multi-block exclusive scan of cnt -> rowstart (+ fused dinv)
__global__ __launch_bounds__(256) void k_bsum(const int* __restrict__ cnt,
                                              int* __restrict__ bsum) {
    __shared__ int red[256];
    int t = threadIdx.x;
    int idx = blockIdx.x * 256 + t;
    red[t] = (idx < NND) ? cnt[idx] : 0;
    __syncthreads();
    for (int off = 128; off > 0; off >>= 1) {
        if (t < off) red[t] += red[t + off];
        __syncthreads();
    }
    if (t == 0) bsum[blockIdx.x] = red[0];
}

__global__ __launch_bounds__(256) void k_bscan(int* __restrict__ bsum) {
    __shared__ int ps[256];
    int t = threadIdx.x;
    int v = (t < NSCB) ? bsum[t] : 0;
    ps[t] = v;
    __syncthreads();
    for (int off = 1; off < 256; off <<= 1) {
        int u = 0;
        if (t >= off) u = ps[t - off];
        __syncthreads();
        if (t >= off) ps[t] += u;
        __syncthreads();
    }
    if (t < NSCB) bsum[t] = ps[t] - v;   // exclusive
}

__global__ __launch_bounds__(256) void k_bout(const int* __restrict__ cnt,
                                              const int* __restrict__ bsum,
                                              int* __restrict__ rowstart,
                                              float* __restrict__ dinv) {
    __shared__ int ps[256];
    int t = threadIdx.x;
    int idx = blockIdx.x * 256 + t;
    int v = (idx < NND) ? cnt[idx] : 0;
    ps[t] = v;
    __syncthreads();
    for (int off = 1; off < 256; off <<= 1) {
        int u = 0;
        if (t >= off) u = ps[t - off];
        __syncthreads();
        if (t >= off) ps[t] += u;
        __syncthreads();
    }
    int boff = bsum[blockIdx.x];
    if (idx < NND) {
        rowstart[idx] = boff + ps[t] - v;   // exclusive
        dinv[idx] = 1.0f / sqrtf((float)v + 1.0f);   // fused (was k_dinv)
    }
    if (idx == NND - 1) rowstart[NND] = boff + ps[t];  // == NE
}

__global__ void k_fill(const int* __restrict__ ei, const int* __restrict__ rowstart,
                       int* __restrict__ cursor, int* __restrict__ adj) {
    int e = blockIdx.x * 256 + threadIdx.x;
    if (e >= NE) return;
    int s = ei[e], d = ei[NE + e];
    int pos = atomicAdd(&cursor[d], 1);
    adj[rowstart[d] + pos] = s;
}

// ---------------------------------------------------------------- MFMA GEMM
// 2-term GCN GEMM: A plain bf16 (hi only), B split hi/lo. 128x128 A panel
// staged once (34.8 KB LDS -> 4 blocks/CU), NT col-tiles per block.
__global__ __launch_bounds__(256) void k_gemm_mfma_h2(
    const unsigned short* __restrict__ Ahi,
    const unsigned short* __restrict__ Bhi, const unsigned short* __restrict__ Blo,
    const float* __restrict__ bias, float* __restrict__ C,
    int M, int Nc, int NT)
{
    __shared__ unsigned short As_hi[128][136];

    const int tid  = threadIdx.x;
    const int lane = tid & 63, wave = tid >> 6;
    const int mw = wave & 1, nw = wave >> 1;
    const int l15 = lane & 15, quad = lane >> 4;
    const int rowBase = blockIdx.y * 128;

    {
        int r0 = tid >> 4;            // 0..15
        int ko = (tid & 15) * 8;      // 0..120
        #pragma unroll
        for (int i = 0; i < 8; ++i) {
            int row = r0 + i * 16;
            int g = rowBase + row;
            uint4 vh = make_uint4(0, 0, 0, 0);
            if (g < M) vh = *(const uint4*)&Ahi[(size_t)g * 128 + ko];
            *(uint4*)&As_hi[row][ko] = vh;
        }
    }
    __syncthreads();

    for (int nt = 0; nt < NT; ++nt) {
        const int colBase = (blockIdx.x * NT + nt) * 64;

        s16x8 bh[2][4], bl[2][4];   // [ns][kq]
        #pragma unroll
        for (int ns = 0; ns < 2; ++ns) {
            int gn = colBase + nw * 32 + ns * 16 + l15;
            #pragma unroll
            for (int kq = 0; kq < 4; ++kq) {
                bh[ns][kq] = *(const s16x8*)&Bhi[(size_t)gn * 128 + kq * 32 + quad * 8];
                bl[ns][kq] = *(const s16x8*)&Blo[(size_t)gn * 128 + kq * 32 + quad * 8];
            }
        }

        f32x4 acc[4][2] = {};
        #pragma unroll
        for (int kq = 0; kq < 4; ++kq) {
            int kof = kq * 32 + quad * 8;
            s16x8 ah[4];
            #pragma unroll
            for (int ms = 0; ms < 4; ++ms) {
                int r = mw * 64 + ms * 16 + l15;
                ah[ms] = *(const s16x8*)&As_hi[r][kof];
            }
            #pragma unroll
            for (int ms = 0; ms < 4; ++ms)
                #pragma unroll
                for (int ns = 0; ns < 2; ++ns)
                    acc[ms][ns] = __builtin_amdgcn_mfma_f32_16x16x32_bf16(ah[ms], bh[ns][kq], acc[ms][ns], 0, 0, 0);
            #pragma unroll
            for (int ms = 0; ms < 4; ++ms)
                #pragma unroll
                for (int ns = 0; ns < 2; ++ns)
                    acc[ms][ns] = __builtin_amdgcn_mfma_f32_16x16x32_bf16(ah[ms], bl[ns][kq], acc[ms][ns], 0, 0, 0);
        }

        #pragma unroll
        for (int ns = 0; ns < 2; ++ns) {
            int col = colBase + nw * 32 + ns * 16 + l15;
            float bv = bias ? bias[col] : 0.f;
            #pragma unroll
            for (int ms = 0; ms < 4; ++ms) {
                int row0 = rowBase + mw * 64 + ms * 16 + quad * 4;
                #pragma unroll
                for (int r = 0; r < 4; ++r) {
                    int row = row0 + r;
                    if (row < M) C[(size_t)row * Nc + col] = acc[ms][ns][r] + bv;
                }
            }
        }
    }
}

// Variant: A is raw fp32 (input x); split-bf16 conversion fused into staging.
// (GCN layer 1 keeps full split precision — input is fp32.)
__global__ __launch_bounds__(256) void k_gemm_mfma_xa(
    const float* __restrict__ X,
    const unsigned short* __restrict__ Bhi, const unsigned short* __restrict__ Blo,
    const float* __restrict__ bias, float* __restrict__ C,
    int M, int Nc, int NT)
{
    __shared__ unsigned short As_hi[128][136];
    __shared__ unsigned short As_lo[128][136];

    const int tid  = threadIdx.x;
    const int lane = tid & 63, wave = tid >> 6;
    const int mw = wave & 1, nw = wave >> 1;
    const int l15 = lane & 15, quad = lane >> 4;
    const int rowBase = blockIdx.y * 128;

    {
        int r0 = tid >> 4;
        int ko = (tid & 15) * 8;
        #pragma unroll
        for (int i = 0; i < 8; ++i) {
            int row = r0 + i * 16;
            int g = rowBase + row;
            unsigned short hx[8], lx[8];
            if (g < M) {
                float4 v0 = *(const float4*)&X[(size_t)g * 128 + ko];
                float4 v1 = *(const float4*)&X[(size_t)g * 128 + ko + 4];
                const float vv[8] = {v0.x, v0.y, v0.z, v0.w, v1.x, v1.y, v1.z, v1.w};
                #pragma unroll
                for (int e = 0; e < 8; ++e) {
                    hx[e] = f2bf(vv[e]);
                    lx[e] = f2bf(vv[e] - bf2f(hx[e]));
                }
            } else {
                #pragma unroll
                for (int e = 0; e < 8; ++e) { hx[e] = 0; lx[e] = 0; }
            }
            *(uint4*)&As_hi[row][ko] = *(const uint4*)hx;
            *(uint4*)&As_lo[row][ko] = *(const uint4*)lx;
        }
    }
    __syncthreads();

    for (int nt = 0; nt < NT; ++nt) {
        const int colBase = (blockIdx.x * NT + nt) * 64;

        s16x8 bh[2][4], bl[2][4];
        #pragma unroll
        for (int ns = 0; ns < 2; ++ns) {
            int gn = colBase + nw * 32 + ns * 16 + l15;
            #pragma unroll
            for (int kq = 0; kq < 4; ++kq) {
                bh[ns][kq] = *(const s16x8*)&Bhi[(size_t)gn * 128 + kq * 32 + quad * 8];
                bl[ns][kq] = *(const s16x8*)&Blo[(size_t)gn * 128 + kq * 32 + quad * 8];
            }
        }

        f32x4 acc[4][2] = {};
        #pragma unroll
        for (int kq = 0; kq < 4; ++kq) {
            int kof = kq * 32 + quad * 8;
            s16x8 ah[4], al[4];
            #pragma unroll
            for (int ms = 0; ms < 4; ++ms) {
                int r = mw * 64 + ms * 16 + l15;
                ah[ms] = *(const s16x8*)&As_hi[r][kof];
                al[ms] = *(const s16x8*)&As_lo[r][kof];
            }
            #pragma unroll
            for (int ms = 0; ms < 4; ++ms)
                #pragma unroll
                for (int ns = 0; ns < 2; ++ns)
                    acc[ms][ns] = __builtin_amdgcn_mfma_f32_16x16x32_bf16(ah[ms], bh[ns][kq], acc[ms][ns], 0, 0, 0);
            #pragma unroll
            for (int ms = 0; ms < 4; ++ms)
                #pragma unroll
                for (int ns = 0; ns < 2; ++ns)
                    acc[ms][ns] = __builtin_amdgcn_mfma_f32_16x16x32_bf16(al[ms], bh[ns][kq], acc[ms][ns], 0, 0, 0);
            #pragma unroll
            for (int ms = 0; ms < 4; ++ms)
                #pragma unroll
                for (int ns = 0; ns < 2; ++ns)
                    acc[ms][ns] = __builtin_amdgcn_mfma_f32_16x16x32_bf16(ah[ms], bl[ns][kq], acc[ms][ns], 0, 0, 0);
        }

        #pragma unroll
        for (int ns = 0; ns < 2; ++ns) {
            int col = colBase + nw * 32 + ns * 16 + l15;
            float bv = bias ? bias[col] : 0.f;
            #pragma unroll
            for (int ms = 0; ms < 4; ++ms) {
                int row0 = rowBase + mw * 64 + ms * 16 + quad * 4;
                #pragma unroll
                for (int r = 0; r < 4; ++r) {
                    int row = row0 + r;
                    if (row < M) C[(size_t)row * Nc + col] = acc[ms][ns][r] + bv;
                }
            }
        }
    }
}

// ---------------------------------------------------------------- gate GEMM
// 2-term swapped-operand gate GEMM (R7 layout, R10 permuted rows, R12 bf16 G):
// A = plain bf16 activations, W split hi/lo. Both LSTM layers. LDS 17.4 KB.
__global__ __launch_bounds__(256) void k_gemm_gT_h(
    const unsigned short* __restrict__ Ahi,
    const unsigned short* __restrict__ Whi, const unsigned short* __restrict__ Wlo,
    const float* __restrict__ bp, unsigned short* __restrict__ G,
    int M)
{
    __shared__ unsigned short As_hi[64][136];

    const int tid  = threadIdx.x;
    const int lane = tid & 63, wave = tid >> 6;
    const int l15 = lane & 15, quad = lane >> 4;
    const int rowBase = blockIdx.x * 64;

    {
        int r0 = tid >> 4;
        int ko = (tid & 15) * 8;
        #pragma unroll
        for (int i = 0; i < 4; ++i) {
            int row = r0 + i * 16;
            int g = rowBase + row;
            uint4 vh = make_uint4(0, 0, 0, 0);
            if (g < M) vh = *(const uint4*)&Ahi[(size_t)g * 128 + ko];
            *(uint4*)&As_hi[row][ko] = vh;
        }
    }
    __syncthreads();

    const int pb = wave * 128;

    #pragma unroll
    for (int tp = 0; tp < 4; ++tp) {
        const int p0 = pb + tp * 32;

        s16x8 wh[2][4], wl[2][4];
        #pragma unroll
        for (int t = 0; t < 2; ++t)
            #pragma unroll
            for (int kq = 0; kq < 4; ++kq) {
                const size_t wrow = (size_t)(p0 + t * 16 + l15) * 128 + kq * 32 + quad * 8;
                wh[t][kq] = *(const s16x8*)&Whi[wrow];
                wl[t][kq] = *(const s16x8*)&Wlo[wrow];
            }
        float4 bv[2];
        #pragma unroll
        for (int t = 0; t < 2; ++t)
            bv[t] = *(const float4*)&bp[p0 + t * 16 + quad * 4];

        #pragma unroll
        for (int rg = 0; rg < 4; ++rg) {
            s16x8 xh[4];
            #pragma unroll
            for (int kq = 0; kq < 4; ++kq)
                xh[kq] = *(const s16x8*)&As_hi[rg * 16 + l15][kq * 32 + quad * 8];
            f32x4 acc[2] = {};
            #pragma unroll
            for (int kq = 0; kq < 4; ++kq)
                #pragma unroll
                for (int t = 0; t < 2; ++t) {
                    acc[t] = __builtin_amdgcn_mfma_f32_16x16x32_bf16(wh[t][kq], xh[kq], acc[t], 0, 0, 0);
                    acc[t] = __builtin_amdgcn_mfma_f32_16x16x32_bf16(wl[t][kq], xh[kq], acc[t], 0, 0, 0);
                }
            const int row = rowBase + rg * 16 + l15;
            if (row < M) {
                const size_t prow = (size_t)grow_perm(row);
                #pragma unroll
                for (int t = 0; t < 2; ++t) {
                    ushort4 o;
                    o.x = f2bf(acc[t][0] + bv[t].x);
                    o.y = f2bf(acc[t][1] + bv[t].y);
                    o.z = f2bf(acc[t][2] + bv[t].z);
                    o.w = f2bf(acc[t][3] + bv[t].w);
                    *(ushort4*)&G[prow * 512 + p0 + t * 16 + quad * 4] = o;
                }
            }
        }
    }
}

// ---------------------------------------------------------------- GCN gather
// Edge loop unrolled x4; accumulation order preserved. lo output optional.
__global__ __launch_bounds__(256) void k_gather(
    const int* __restrict__ rowstart, const int* __restrict__ adj,
    const float* __restrict__ h, const float* __restrict__ dinv,
    const float* __restrict__ bias,
    unsigned short* __restrict__ hi, unsigned short* __restrict__ lo)
{
    const int n    = blockIdx.x * 4 + (threadIdx.x >> 6);   // grid exactly NND/4
    const int lane = threadIdx.x & 63;
    const int r0 = rowstart[n], r1 = rowstart[n + 1];
    const float dn = dinv[n];

    float2 hv = *(const float2*)&h[(size_t)n * 128 + 2 * lane];
    float2 acc;
    acc.x = hv.x * dn;
    acc.y = hv.y * dn;

    int i = r0;
    for (; i + 4 <= r1; i += 4) {
        int s0 = adj[i], s1 = adj[i + 1], s2 = adj[i + 2], s3 = adj[i + 3];
        float d0 = dinv[s0], d1 = dinv[s1], d2 = dinv[s2], d3 = dinv[s3];
        float2 v0 = *(const float2*)&h[(size_t)s0 * 128 + 2 * lane];
        float2 v1 = *(const float2*)&h[(size_t)s1 * 128 + 2 * lane];
        float2 v2 = *(const float2*)&h[(size_t)s2 * 128 + 2 * lane];
        float2 v3 = *(const float2*)&h[(size_t)s3 * 128 + 2 * lane];
        acc.x += v0.x * d0; acc.y += v0.y * d0;
        acc.x += v1.x * d1; acc.y += v1.y * d1;
        acc.x += v2.x * d2; acc.y += v2.y * d2;
        acc.x += v3.x * d3; acc.y += v3.y * d3;
    }
    for (; i < r1; ++i) {
        int s = adj[i];
        float ds = dinv[s];
        float2 v = *(const float2*)&h[(size_t)s * 128 + 2 * lane];
        acc.x += v.x * ds;
        acc.y += v.y * ds;
    }

    float2 bb = *(const float2*)&bias[2 * lane];
    float vx = fmaxf(acc.x * dn + bb.x, 0.f);
    float vy = fmaxf(acc.y * dn + bb.y, 0.f);
    ushort2 ho;
    ho.x = f2bf(vx);
    ho.y = f2bf(vy);
    *(ushort2*)&hi[(size_t)n * 128 + 2 * lane] = ho;
    if (lo) {
        ushort2 lo2;
        lo2.x = f2bf(vx - bf2f(ho.x));
        lo2.y = f2bf(vy - bf2f(ho.y));
        *(ushort2*)&lo[(size_t)n * 128 + 2 * lane] = lo2;
    }
}

// ---------------------------------------------------------------- prep kernels
__global__ void k_prep_gcnw2(const float* __restrict__ W1, const float* __restrict__ W2,
                             unsigned short* __restrict__ hi1, unsigned short* __restrict__ lo1,
                             unsigned short* __restrict__ hi2, unsigned short* __restrict__ lo2) {
    int t = blockIdx.x * 256 + threadIdx.x;   // grid 128 -> 32768 threads
    const float* W = (t < 16384) ? W1 : W2;
    unsigned short* hi = (t < 16384) ? hi1 : hi2;
    unsigned short* lo = (t < 16384) ? lo1 : lo2;
    int tt = t & 16383;
    int k = tt >> 7, n = tt & 127;
    float v = W[tt];
    unsigned short h = f2bf(v);
    hi[n * 128 + k] = h;
    lo[n * 128 + k] = f2bf(v - bf2f(h));
}

// LSTM prep: w_ih and w_hh [512(r=g*128+j)][128(k)] -> packed-transposed
// split-bf16 wT[p=j*4+g][k]; bias -> bp[p] = b_ih + b_hh.
__global__ void k_prep_lstm(const float* __restrict__ w_ih, const float* __restrict__ w_hh,
                            const float* __restrict__ b_ih, const float* __restrict__ b_hh,
                            unsigned short* __restrict__ ih_hi, unsigned short* __restrict__ ih_lo,
                            unsigned short* __restrict__ hh_hi, unsigned short* __restrict__ hh_lo,
                            float* __restrict__ bp)
{
    int t = blockIdx.x * 256 + threadIdx.x;
    if (t < 65536) {
        int r = t >> 7, k = t & 127;
        int g = r >> 7, j = r & 127;
        int p = (j << 2) + g;
        float v = w_ih[t];
        unsigned short h = f2bf(v);
        ih_hi[p * 128 + k] = h;
        ih_lo[p * 128 + k] = f2bf(v - bf2f(h));
    } else if (t < 131072) {
        int t2 = t - 65536;
        int r = t2 >> 7, k = t2 & 127;
        int g = r >> 7, j = r & 127;
        int p = (j << 2) + g;
        float v = w_hh[t2];
        unsigned short h = f2bf(v);
        hh_hi[p * 128 + k] = h;
        hh_lo[p * 128 + k] = f2bf(v - bf2f(h));
    } else if (t < 131584) {
        int r = t - 131072;   // 0..511
        int g = r >> 7, j = r & 127;
        bp[(j << 2) + g] = b_ih[r] + b_hh[r];
    }
}

// ---------------------------------------------------------------- LSTM recurrence
// v15: v14 + LDS-ONLY per-step barrier. R13 counters: MFMA floor 620 cyc,
// VALU ~870, and ~800 unexplained — __syncthreads' vmcnt(0) drain was putting
// the Hhi store completion (and part of the G prefetch) on the serial path
// every step. Cross-wave data is ONLY the LDS Ah array -> lgkmcnt-only
// barrier is sufficient; globals stay in flight. Hhi addressing hoisted to
// a bumped pointer. Numerics identical.
__global__ __launch_bounds__(512, 2) void k_lstm(
    const unsigned short* __restrict__ G,   // bf16, permuted: [blk][step][4 seq][512]
    const unsigned short* __restrict__ Whi, // 512 x 128, packed-transposed hi
    unsigned short* __restrict__ Hhi,       // (NB*TSEQ) x 128 bf16-hi, or nullptr
    const float* __restrict__ fcw,          // fused FC weight (layer 1) or nullptr
    const float* __restrict__ fcb,
    float* __restrict__ outp)               // NB x 1 output (layer 1) or nullptr
{
    const int tid  = threadIdx.x;
    const int lane = tid & 63, wave = tid >> 6;   // 8 waves
    const int l15  = lane & 15, quad = lane >> 4;
    const int b0   = blockIdx.x * SB;

    __shared__ __align__(16) unsigned short Ah[16 * AHS];  // h bf16 (rows SB..15 zero)
    __shared__ float partw[8][4][72];        // per-wave P patch [wave][b][col in wave]

    // weight fragments: wave owns n-tiles nt0..nt0+3 (n = p = j*4+gate)
    const int nt0 = wave * 4;
    s16x8 bh[4][4];   // [nt][ks]
    #pragma unroll
    for (int nt = 0; nt < 4; ++nt) {
        int p = (nt0 + nt) * 16 + l15;
        #pragma unroll
        for (int ks = 0; ks < 4; ++ks)
            bh[nt][ks] = *(const s16x8*)&Whi[(size_t)p * 128 + ks * 32 + quad * 8];
    }

    for (int i = tid; i < 16 * AHS; i += 512) Ah[i] = 0;

    // phase-2 mapping: lane l of wave w -> (b2, j) with j owned by wave w
    const int b2 = lane >> 4;              // 0..3
    const int jj = wave * 16 + l15;        // hidden unit this lane updates
    const int bg = b0 + b2;                // sequence index (NB % SB == 0)
    float c = 0.f;
    float hn_last = 0.f;

    // permuted-G base: row' = blk*200 + step*4 + b2; step stride = 2048 ushorts
    const unsigned short* gb = &G[((size_t)blockIdx.x * 200 + b2) * 512 + (jj << 2)];
    ushort4 gr_cur = *(const ushort4*)&gb[0];
    // hoisted Hhi pointer (bumped by 128 shorts per step)
    unsigned short* hptr = Hhi ? &Hhi[(size_t)bg * TSEQ * 128 + jj] : nullptr;

    __syncthreads();

    for (int step = 0; step < TSEQ; ++step) {
        // prefetch NEXT step's gate input (full step of latency cover;
        // NOT drained by the lds-only barrier below)
        const int nstep = (step + 1 < TSEQ) ? step + 1 : step;
        const ushort4 gr_nxt = *(const ushort4*)&gb[(size_t)nstep * 2048];

        // phase 1: MFMA  P = bf16(h) @ bf16(Whh)  (1-term)
        f32x4 acc[4] = {};
        #pragma unroll
        for (int ks = 0; ks < 4; ++ks) {
            s16x8 ah = *(const s16x8*)&Ah[l15 * AHS + ks * 32 + quad * 8];
            #pragma unroll
            for (int nt = 0; nt < 4; ++nt)
                acc[nt] = __builtin_amdgcn_mfma_f32_16x16x32_bf16(ah, bh[nt][ks], acc[nt], 0, 0, 0);
        }

        // intra-wave exchange: quad-0 lanes hold rows 0..3 (the real seqs)
        if (quad == 0) {
            #pragma unroll
            for (int nt = 0; nt < 4; ++nt)
                #pragma unroll
                for (int r = 0; r < 4; ++r)
                    partw[wave][r][nt * 16 + l15] = acc[nt][r];
        }
        // same-wave producer/consumer: compiler inserts lgkmcnt wait, no barrier

        // phase 2: LSTM cell for (b2, jj); reads this wave's own patch
        {
            float4 pa = *(const float4*)&partw[wave][b2][l15 * 4];
            float xi = pa.x + bf2f(gr_cur.x);
            float xf = pa.y + bf2f(gr_cur.y);
            float xg = pa.z + bf2f(gr_cur.z);
            float xo = pa.w + bf2f(gr_cur.w);
            float ii = sigf(xi), ff = sigf(xf), gg = tanhfast(xg), oo = sigf(xo);
            float cn = ff * c + ii * gg;
            c = cn;
            float hn = oo * tanhfast(cn);
            hn_last = hn;
            unsigned short hh = f2bf(hn);
            Ah[b2 * AHS + jj] = hh;
            if (hptr) {
                *hptr = hh;
                hptr += 128;
            }
        }
        gr_cur = gr_nxt;
        // LDS-only barrier: Ah writes visible to all waves; globals in flight
        barrier_lds_only();
    }

    // fused FC head (layer 1): out[bg] = dot(h_last[bg], fcw) + fcb
    if (outp) {
        float* red = (float*)Ah;   // 2 KiB scratch, Ah is dead now
        red[b2 * 128 + jj] = hn_last * fcw[jj];
        __syncthreads();
        if (wave < 4) {            // wave w reduces sequence b0+w
            float v = red[wave * 128 + lane] + red[wave * 128 + lane + 64];
            #pragma unroll
            for (int off = 32; off > 0; off >>= 1)
                v += __shfl_down(v, off);
            if (lane == 0) outp[b0 + wave] = v + fcb[0];
        }
    }
}

// ---------------------------------------------------------------- launch
extern "C" void kernel_launch(void* const* d_in, const int* in_sizes, int n_in,
                              void* d_out, int out_size, void* d_ws, size_t ws_size,
                              hipStream_t stream)
{
    const float* x    = (const float*)d_in[0];
    const int*   ei   = (const int*)d_in[1];
    const float* W1   = (const float*)d_in[3];
    const float* b1   = (const float*)d_in[4];
    const float* W2   = (const float*)d_in[5];
    const float* b2   = (const float*)d_in[6];
    const float* fcw  = (const float*)d_in[7];
    const float* fcb  = (const float*)d_in[8];
    const float* wih0 = (const float*)d_in[9];
    const float* whh0 = (const float*)d_in[10];
    const float* bih0 = (const float*)d_in[11];
    const float* bhh0 = (const float*)d_in[12];
    const float* wih1 = (const float*)d_in[13];
    const float* whh1 = (const float*)d_in[14];
    const float* bih1 = (const float*)d_in[15];
    const float* bhh1 = (const float*)d_in[16];
    float* out = (float*)d_out;

    char* ws = (char*)d_ws;
    // ---- persistent regions
    unsigned short* shi = (unsigned short*)(ws + 0);          // 12.8 MB
    unsigned short* bufG = (unsigned short*)(ws + 51200000);  // 51.2 MB bf16 (ends 102.4M)

    // ---- GCN-phase regions (overlap bufG region; dead before gate GEMM writes)
    unsigned short* xhi = (unsigned short*)(ws + 51200000);   // 12.8 MB
    float* bufHg  = (float*)(ws + 76800000);                  // 25.6 MB (ends 102.4M)
    int* cnt      = (int*)(ws + 102400000);                   // 200000 B (pad 204800)
    int* cursor   = (int*)(ws + 102604800);                   // contiguous with cnt
    int* rowstart = (int*)(ws + 102809600);
    int* adj      = (int*)(ws + 103014400);                   // 2.4 MB (ends 105.42M)
    int* bsum     = (int*)(ws + 105420800);                   // NSCB ints

    float* dinv = (float*)(ws + 153600000);
    float* bp0  = (float*)(ws + 153800192);
    float* bp1  = (float*)(ws + 153802240);
    unsigned short* w1t_hi   = (unsigned short*)(ws + 153804288);
    unsigned short* w1t_lo   = (unsigned short*)(ws + 153837056);
    unsigned short* w2t_hi   = (unsigned short*)(ws + 153869824);
    unsigned short* w2t_lo   = (unsigned short*)(ws + 153902592);
    unsigned short* wpih0_hi = (unsigned short*)(ws + 153935360);
    unsigned short* wpih0_lo = (unsigned short*)(ws + 154066432);
    unsigned short* wpih1_hi = (unsigned short*)(ws + 154197504);
    unsigned short* wpih1_lo = (unsigned short*)(ws + 154328576);
    unsigned short* wphh0_hi = (unsigned short*)(ws + 154459648);
    unsigned short* wphh0_lo = (unsigned short*)(ws + 154590720);
    unsigned short* wphh1_hi = (unsigned short*)(ws + 154721792);
    unsigned short* wphh1_lo = (unsigned short*)(ws + 154852864);

    // ---- CSR build + dinv (multi-block scan); cnt+cursor zeroed in ONE memset
    hipMemsetAsync(cnt, 0, 409600, stream);
    k_count<<<(NE + 255) / 256, 256, 0, stream>>>(ei, cnt);
    k_bsum<<<NSCB, 256, 0, stream>>>(cnt, bsum);
    k_bscan<<<1, 256, 0, stream>>>(bsum);
    k_bout<<<NSCB, 256, 0, stream>>>(cnt, bsum, rowstart, dinv);
    k_fill<<<(NE + 255) / 256, 256, 0, stream>>>(ei, rowstart, cursor, adj);

    // ---- weight prep
    k_prep_gcnw2<<<128, 256, 0, stream>>>(W1, W2, w1t_hi, w1t_lo, w2t_hi, w2t_lo);
    k_prep_lstm<<<514, 256, 0, stream>>>(wih0, whh0, bih0, bhh0,
                                         wpih0_hi, wpih0_lo, wphh0_hi, wphh0_lo, bp0);
    k_prep_lstm<<<514, 256, 0, stream>>>(wih1, whh1, bih1, bhh1,
                                         wpih1_hi, wpih1_lo, wphh1_hi, wphh1_lo, bp1);

    dim3 gH(1, 391);     // GCN GEMMs: 128-row panel, NT=2 (128 cols)

    // ---- GCN layer 1 (fp32 A, convert-on-stage, split precision)
    k_gemm_mfma_xa<<<gH, 256, 0, stream>>>(x, w1t_hi, w1t_lo, nullptr, bufHg, NND, 128, 2);
    k_gather<<<NND / 4, 256, 0, stream>>>(rowstart, adj, bufHg, dinv, b1, xhi, nullptr);

    // ---- GCN layer 2 (2-term: A = bf16 hi only)
    k_gemm_mfma_h2<<<gH, 256, 0, stream>>>(xhi, w2t_hi, w2t_lo, nullptr, bufHg, NND, 128, 2);
    k_gather<<<NND / 4, 256, 0, stream>>>(rowstart, adj, bufHg, dinv, b2, shi, nullptr);

    // ---- LSTM layer 0: 2-term gate GEMM (bf16 G) + recurrence (H -> shi in-place)
    k_gemm_gT_h<<<782, 256, 0, stream>>>(shi, wpih0_hi, wpih0_lo, bp0, bufG, NND);
    k_lstm<<<NB / SB, 512, 0, stream>>>(bufG, wphh0_hi, shi,
                                        nullptr, nullptr, nullptr);

    // ---- LSTM layer 1: 2-term gate GEMM (bf16 G) + recurrence + fused FC
    k_gemm_gT_h<<<782, 256, 0, stream>>>(shi, wpih1_hi, wpih1_lo, bp1, bufG, NND);
    k_lstm<<<NB / SB, 512, 0, stream>>>(bufG, wphh1_hi, nullptr,
                                        fcw, fcb, out);
}